// Round 7
// baseline (563.386 us; speedup 1.0000x reference)
//
#include <hip/hip_runtime.h>
#include <hip/hip_bf16.h>
#include <math.h>

typedef short bf16x8 __attribute__((ext_vector_type(8)));
typedef short bf16x4 __attribute__((ext_vector_type(4)));
typedef float f32x4 __attribute__((ext_vector_type(4)));

__device__ inline unsigned short f2bf(float f) {
  unsigned u = __float_as_uint(f);
  u += 0x7FFF + ((u >> 16) & 1);           // RNE
  return (unsigned short)(u >> 16);
}
__device__ inline float bf2f(unsigned short h) {
  return __uint_as_float(((unsigned)h) << 16);
}

// ---------------- CSR build ----------------

__global__ __launch_bounds__(256) void zero_i32(int* __restrict__ p, int n) {
  int i = blockIdx.x * 256 + threadIdx.x;
  if (i < n) p[i] = 0;
}

__global__ __launch_bounds__(256) void count_k(const int* __restrict__ dst, int* __restrict__ cnt, int e) {
  int i = blockIdx.x * 256 + threadIdx.x;
  if (i < e) atomicAdd(&cnt[dst[i]], 1);
}

__global__ __launch_bounds__(256) void dis_k(const int* __restrict__ cnt, float* __restrict__ dis, int n) {
  int i = blockIdx.x * 256 + threadIdx.x;
  if (i < n) dis[i] = rsqrtf((float)cnt[i] + 1.0f);
}

// hierarchical scan
__global__ __launch_bounds__(256) void scan_a(const int* __restrict__ cnt, int* __restrict__ bsum, int n) {
  int i = blockIdx.x * 256 + threadIdx.x;
  int v = (i < n) ? cnt[i] : 0;
#pragma unroll
  for (int o = 32; o > 0; o >>= 1) v += __shfl_xor(v, o);
  __shared__ int ws[4];
  if ((threadIdx.x & 63) == 0) ws[threadIdx.x >> 6] = v;
  __syncthreads();
  if (threadIdx.x == 0) bsum[blockIdx.x] = ws[0] + ws[1] + ws[2] + ws[3];
}

__global__ __launch_bounds__(256) void scan_b(const int* __restrict__ bsum, int* __restrict__ bpre,
                                              int* __restrict__ off_n, int nb) {
  __shared__ int s[256];
  int t = threadIdx.x;
  int v = (t < nb) ? bsum[t] : 0;
  s[t] = v;
  __syncthreads();
  for (int o = 1; o < 256; o <<= 1) {
    int u = (t >= o) ? s[t - o] : 0;
    __syncthreads();
    s[t] += u;
    __syncthreads();
  }
  if (t < nb) bpre[t] = s[t] - v;
  if (t == 255) off_n[0] = s[255];
}

__global__ __launch_bounds__(256) void scan_c(const int* __restrict__ cnt, const int* __restrict__ bpre,
                                              int* __restrict__ off, int* __restrict__ cursor, int n) {
  __shared__ int s[256];
  int i = blockIdx.x * 256 + threadIdx.x;
  int t = threadIdx.x;
  int v = (i < n) ? cnt[i] : 0;
  s[t] = v;
  __syncthreads();
  for (int o = 1; o < 256; o <<= 1) {
    int u = (t >= o) ? s[t - o] : 0;
    __syncthreads();
    s[t] += u;
    __syncthreads();
  }
  if (i < n) {
    int ov = bpre[blockIdx.x] + s[t] - v;
    off[i] = ov;
    cursor[i] = ov;
  }
}

__global__ __launch_bounds__(256) void scatter_k(const int* __restrict__ src, const int* __restrict__ dst,
                                                 int* __restrict__ cursor, int* __restrict__ csr, int e) {
  int i = blockIdx.x * 256 + threadIdx.x;
  if (i < e) {
    int p = atomicAdd(&cursor[dst[i]], 1);
    csr[p] = src[i];
  }
}

// ------- weight convert: W[K][N] fp32 -> Wc[N][K] bf16 -------

__global__ __launch_bounds__(256) void wconv_k(const float* __restrict__ W1, const float* __restrict__ Wr,
                                               const float* __restrict__ W2, const float* __restrict__ W3,
                                               const float* __restrict__ W4,
                                               short* __restrict__ o1, short* __restrict__ oR,
                                               short* __restrict__ o2, short* __restrict__ o3,
                                               short* __restrict__ o4) {
  int b = blockIdx.x;  // 960 rows total
  const float* W; short* O; int K, N, nr;
  if (b < 64)       { W = W1; O = o1; K = 128; N = 64;  nr = b; }
  else if (b < 128) { W = Wr; O = oR; K = 128; N = 64;  nr = b - 64; }
  else if (b < 384) { W = W2; O = o2; K = 64;  N = 256; nr = b - 128; }
  else if (b < 896) { W = W3; O = o3; K = 256; N = 512; nr = b - 384; }
  else              { W = W4; O = o4; K = 512; N = 64;  nr = b - 896; }
  for (int k = threadIdx.x; k < K; k += 256)
    O[(size_t)nr * K + k] = (short)f2bf(W[(size_t)k * N + nr]);
}

// ------- MFMA GEMM: C[M,NTOT] = A[M,KT] @ Wc[NTOT,KT](bf16) -------
// ABF=0: A fp32, hi/lo split, 2 products. ABF=1: A bf16, 1 product.
// OBF: emit bf16 output. Block = 4 waves, wave tile 64x64, WMxWN wave grid.

template<int KT, int NTOT, int WM, int WN, int BIAS, int RELU, int ABF, int OBF, int BLK>
__global__ __launch_bounds__(256, BLK) void mgemm(const void* __restrict__ Av,
                                                  const short* __restrict__ Wc,
                                                  const float* __restrict__ bias, void* __restrict__ Cv, int M) {
  __shared__ short As[64 * WM][ABF ? 40 : 72];  // [m][hi | lo | pad] or [m][k | pad]
  __shared__ short Bs[64 * WN][40];             // [n][k | pad]
  const int tid = threadIdx.x;
  const int row0 = blockIdx.x * (64 * WM);
  const int col0 = blockIdx.y * (64 * WN);
  const int w = tid >> 6, lane = tid & 63;
  const int wm = w / WN, wn = w % WN;
  const int rm = wm * 64, cn = wn * 64;
  const int lm = lane & 15, lk = (lane >> 4) * 8;

  f32x4 acc[4][4];
#pragma unroll
  for (int i = 0; i < 4; i++)
#pragma unroll
    for (int j = 0; j < 4; j++)
#pragma unroll
      for (int r = 0; r < 4; r++) acc[i][j][r] = 0.f;

  for (int k0 = 0; k0 < KT; k0 += 32) {
    // stage A
#pragma unroll
    for (int p = 0; p < WM; p++) {
      int r = (tid >> 2) + p * 64;
      int kseg = (tid & 3) * 8;
      int gr = row0 + r;
      if (ABF) {
        bf16x8 v = {0, 0, 0, 0, 0, 0, 0, 0};
        if (gr < M) v = *(const bf16x8*)((const short*)Av + (size_t)gr * KT + k0 + kseg);
        *(bf16x8*)&As[r][kseg] = v;
      } else {
        float4 v0 = {0.f, 0.f, 0.f, 0.f}, v1 = {0.f, 0.f, 0.f, 0.f};
        if (gr < M) {
          const float* ap = (const float*)Av + (size_t)gr * KT + k0 + kseg;
          v0 = *(const float4*)ap;
          v1 = *(const float4*)(ap + 4);
        }
        float vv[8] = {v0.x, v0.y, v0.z, v0.w, v1.x, v1.y, v1.z, v1.w};
        bf16x8 hv, lv;
#pragma unroll
        for (int j = 0; j < 8; j++) {
          unsigned short h = f2bf(vv[j]);
          hv[j] = (short)h;
          lv[j] = (short)f2bf(vv[j] - bf2f(h));
        }
        *(bf16x8*)&As[r][kseg] = hv;
        *(bf16x8*)&As[r][32 + kseg] = lv;
      }
    }
    // stage B: bf16 [N][K] direct copy
#pragma unroll
    for (int p = 0; p < WN; p++) {
      int nr = (tid >> 2) + p * 64;
      int seg = (tid & 3) * 8;
      *(bf16x8*)&Bs[nr][seg] = *(const bf16x8*)(Wc + (size_t)(col0 + nr) * KT + k0 + seg);
    }
    __syncthreads();

    bf16x8 ah[4], al[4], bb[4];
#pragma unroll
    for (int mt = 0; mt < 4; mt++) {
      ah[mt] = *(const bf16x8*)&As[rm + mt * 16 + lm][lk];
      if (!ABF) al[mt] = *(const bf16x8*)&As[rm + mt * 16 + lm][32 + lk];
    }
#pragma unroll
    for (int nt = 0; nt < 4; nt++) bb[nt] = *(const bf16x8*)&Bs[cn + nt * 16 + lm][lk];
#pragma unroll
    for (int mt = 0; mt < 4; mt++)
#pragma unroll
      for (int nt = 0; nt < 4; nt++) {
        acc[mt][nt] = __builtin_amdgcn_mfma_f32_16x16x32_bf16(ah[mt], bb[nt], acc[mt][nt], 0, 0, 0);
        if (!ABF)
          acc[mt][nt] = __builtin_amdgcn_mfma_f32_16x16x32_bf16(al[mt], bb[nt], acc[mt][nt], 0, 0, 0);
      }
    __syncthreads();
  }

  // epilogue: C row = (lane>>4)*4 + reg, col = lane&15
#pragma unroll
  for (int mt = 0; mt < 4; mt++) {
    int grb = row0 + rm + mt * 16 + (lane >> 4) * 4;
#pragma unroll
    for (int nt = 0; nt < 4; nt++) {
      int gc = col0 + cn + nt * 16 + lm;
      float bv = BIAS ? bias[gc] : 0.f;
#pragma unroll
      for (int r = 0; r < 4; r++) {
        int gr = grb + r;
        if (gr < M) {
          float v = acc[mt][nt][r] + bv;
          if (RELU) v = (v >= 0.f) ? v : 0.01f * v;
          if (OBF) ((short*)Cv)[(size_t)gr * NTOT + gc] = (short)f2bf(v);
          else     ((float*)Cv)[(size_t)gr * NTOT + gc] = v;
        }
      }
    }
  }
}

// ---------------- Aggregation (CSR gather), one wave per node ----------------

template<bool BR>
__global__ __launch_bounds__(256) void agg64_k(const float* __restrict__ T, const float* __restrict__ dis,
                                               const int* __restrict__ off, const int* __restrict__ csr,
                                               const float* __restrict__ bias, float* __restrict__ Out, int n) {
  int wid = (blockIdx.x * 256 + threadIdx.x) >> 6;
  int lane = threadIdx.x & 63;
  if (wid >= n) return;
  float di = dis[wid];
  int e0 = off[wid], e1 = off[wid + 1];
  float acc = 0.f;
  for (int e = e0; e < e1; e++) {
    int j = csr[e];
    acc = fmaf(dis[j], T[(size_t)j * 64 + lane], acc);
  }
  float v = di * acc + di * di * T[(size_t)wid * 64 + lane];
  if (BR) {
    v += bias[lane];
    v = (v >= 0.f) ? v : 0.01f * v;
  }
  Out[(size_t)wid * 64 + lane] = v;
}

// bf16 in, bf16 out variant for the 256-dim layer
__global__ __launch_bounds__(256) void agg256b_k(const short* __restrict__ T, const float* __restrict__ dis,
                                                 const int* __restrict__ off, const int* __restrict__ csr,
                                                 short* __restrict__ Out, int n) {
  int wid = (blockIdx.x * 256 + threadIdx.x) >> 6;
  int lane = threadIdx.x & 63;
  if (wid >= n) return;
  float di = dis[wid];
  int e0 = off[wid], e1 = off[wid + 1];
  float a0 = 0.f, a1 = 0.f, a2 = 0.f, a3 = 0.f;
  for (int e = e0; e < e1; e++) {
    int j = csr[e];
    float dj = dis[j];
    bf16x4 t = *(const bf16x4*)&T[(size_t)j * 256 + lane * 4];
    a0 = fmaf(dj, bf2f((unsigned short)t[0]), a0);
    a1 = fmaf(dj, bf2f((unsigned short)t[1]), a1);
    a2 = fmaf(dj, bf2f((unsigned short)t[2]), a2);
    a3 = fmaf(dj, bf2f((unsigned short)t[3]), a3);
  }
  bf16x4 s = *(const bf16x4*)&T[(size_t)wid * 256 + lane * 4];
  float dii = di * di;
  bf16x4 o;
  o[0] = (short)f2bf(di * a0 + dii * bf2f((unsigned short)s[0]));
  o[1] = (short)f2bf(di * a1 + dii * bf2f((unsigned short)s[1]));
  o[2] = (short)f2bf(di * a2 + dii * bf2f((unsigned short)s[2]));
  o[3] = (short)f2bf(di * a3 + dii * bf2f((unsigned short)s[3]));
  *(bf16x4*)&Out[(size_t)wid * 256 + lane * 4] = o;
}

// ---------------- LN(h4 + resid) ----------------

__global__ __launch_bounds__(256) void ln_k(const float* __restrict__ h4, const float* __restrict__ resid,
                                            const float* __restrict__ g, const float* __restrict__ b,
                                            float* __restrict__ outh, int n) {
  int wid = (blockIdx.x * 256 + threadIdx.x) >> 6;
  int lane = threadIdx.x & 63;
  if (wid >= n) return;
  float v = h4[(size_t)wid * 64 + lane] + resid[(size_t)wid * 64 + lane];
  float s = v, ss = v * v;
#pragma unroll
  for (int o = 32; o > 0; o >>= 1) {
    s += __shfl_xor(s, o);
    ss += __shfl_xor(ss, o);
  }
  float m = s * (1.f / 64.f);
  float var = ss * (1.f / 64.f) - m * m;
  float y = (v - m) * rsqrtf(var + 1e-5f) * g[lane] + b[lane];
  outh[(size_t)wid * 64 + lane] = y;
}

// ---------------- per-graph max pool ----------------

__global__ __launch_bounds__(256) void pool_k(const float* __restrict__ hn, float* __restrict__ p, int n) {
  const int G = 64;
  int g = blockIdx.x;
  int f = threadIdx.x & 63, c = threadIdx.x >> 6;
  long long s = ((long long)g * n + G - 1) / G;
  long long e = ((long long)(g + 1) * n + G - 1) / G;
  float m = -INFINITY;
  for (long long i = s + c; i < e; i += 4) m = fmaxf(m, hn[(size_t)i * 64 + f]);
  __shared__ float red[4][64];
  red[c][f] = m;
  __syncthreads();
  if (c == 0) {
    m = fmaxf(fmaxf(red[0][f], red[1][f]), fmaxf(red[2][f], red[3][f]));
    p[g * 64 + f] = m;
  }
}

// ---------------- final MLP ----------------

__global__ __launch_bounds__(64) void mlp_k(const float* __restrict__ p, const float* __restrict__ fc1W,
                                            const float* __restrict__ fc1b, const float* __restrict__ fng,
                                            const float* __restrict__ fnb, const float* __restrict__ fc2W,
                                            const float* __restrict__ fc2b, float* __restrict__ out) {
  int g = blockIdx.x;
  int lane = threadIdx.x;
  __shared__ float ps[64], qs[64];
  ps[lane] = p[g * 64 + lane];
  __syncthreads();
  float q = fc1b[lane];
#pragma unroll 8
  for (int k = 0; k < 64; k++) q = fmaf(ps[k], fc1W[k * 64 + lane], q);
  float s = q, ss = q * q;
#pragma unroll
  for (int o = 32; o > 0; o >>= 1) {
    s += __shfl_xor(s, o);
    ss += __shfl_xor(ss, o);
  }
  float m = s * (1.f / 64.f);
  float var = ss * (1.f / 64.f) - m * m;
  float y = (q - m) * rsqrtf(var + 1e-5f) * fng[lane] + fnb[lane];
  y = (y >= 0.f) ? y : 0.01f * y;
  qs[lane] = y;
  __syncthreads();
  if (lane < 16) {
    float o = fc2b[lane];
#pragma unroll 8
    for (int k = 0; k < 64; k++) o = fmaf(qs[k], fc2W[k * 16 + lane], o);
    out[g * 16 + lane] = o;
  }
}

// ---------------- launch ----------------

extern "C" void kernel_launch(void* const* d_in, const int* in_sizes, int n_in,
                              void* d_out, int out_size, void* d_ws, size_t ws_size,
                              hipStream_t stream) {
  const float* x   = (const float*)d_in[0];
  const int*   ei  = (const int*)d_in[1];
  const float* W1  = (const float*)d_in[3];
  const float* b1  = (const float*)d_in[4];
  const float* W2  = (const float*)d_in[5];
  const float* b2  = (const float*)d_in[6];
  const float* W3  = (const float*)d_in[7];
  const float* b3  = (const float*)d_in[8];
  const float* W4  = (const float*)d_in[9];
  const float* b4  = (const float*)d_in[10];
  const float* Wr  = (const float*)d_in[11];
  const float* br  = (const float*)d_in[12];
  const float* lng = (const float*)d_in[13];
  const float* lnb = (const float*)d_in[14];
  const float* f1W = (const float*)d_in[15];
  const float* f1b = (const float*)d_in[16];
  const float* fng = (const float*)d_in[17];
  const float* fnb = (const float*)d_in[18];
  const float* f2W = (const float*)d_in[19];
  const float* f2b = (const float*)d_in[20];

  int n = in_sizes[0] / 128;   // 50000
  int e = in_sizes[1] / 2;     // 400000
  const int* src = ei;
  const int* dst = ei + e;

  // Arena layout, float units; bf16 buffers count at n*dim/2 floats.
  // Sizes: t1/h1/z2/t4/h4/resid/hn = 64n each; h2b = 128n; z3b = 128n; h3b = 256n.
  // Timeline / liveness:
  //   h2b  [0,128n)      live: L2 gemm -> agg256b
  //   t4   [0,64n)       live: L4 gemm -> agg64   (h2b dead)
  //   h4   [64n,128n)    live: agg64 -> ln        (h2b dead)
  //   z3b  [128n,256n)   live: agg256b -> L3 gemm
  //   resid[128n,192n)   live: resid gemm -> ln   (z3b dead)
  //   hn   [192n,256n)   live: ln -> pool         (z3b dead)
  //   z2   [256n,320n)   h1 [320n,384n)   t1 [384n,448n)
  //   h3b  [448n,704n)   live: L3 gemm -> L4 gemm
  //   meta from 704n
  float* arena = (float*)d_ws;
  short* h2b   = (short*)arena;
  float* t4    = arena;
  float* h4    = arena + (size_t)64 * n;
  short* z3b   = (short*)(arena + (size_t)128 * n);
  float* resid = arena + (size_t)128 * n;
  float* hn    = arena + (size_t)192 * n;
  float* z2    = arena + (size_t)256 * n;
  float* h1    = arena + (size_t)320 * n;
  float* t1    = arena + (size_t)384 * n;
  short* h3b   = (short*)(arena + (size_t)448 * n);
  float* dis   = arena + (size_t)704 * n;  // n
  int* cnt    = (int*)(dis + n);           // n
  int* off    = cnt + n;                   // n+1
  int* cursor = off + n + 1;               // n
  int* csr    = cursor + n;                // e
  int* bsum   = csr + e;                   // 256
  int* bpre   = bsum + 256;                // 256
  float* pool = (float*)(bpre + 256);      // 64*64
  size_t wq = (((size_t)(pool + 4096)) + 15) & ~(size_t)15;
  short* wc1 = (short*)wq;                 // 64 x 128
  short* wcR = wc1 + 8192;                 // 64 x 128
  short* wc2 = wcR + 8192;                 // 256 x 64
  short* wc3 = wc2 + 16384;                // 512 x 256
  short* wc4 = wc3 + 131072;               // 64 x 512
  size_t need = ((char*)(wc4 + 32768) - (char*)d_ws) + 64;
  if (ws_size < need) return;

  int nb_n = (n + 255) / 256;     // 196
  int nb_e = (e + 255) / 256;
  int nb_w = (n + 3) / 4;         // one wave per node
  int g_wide = (n + 63) / 64;     // 782
  int g_narrow = (n + 255) / 256; // 196

  // weights -> bf16 [N][K]
  wconv_k<<<960, 256, 0, stream>>>(W1, Wr, W2, W3, W4, wc1, wcR, wc2, wc3, wc4);

  // degree + CSR (hierarchical scan)
  zero_i32<<<nb_n, 256, 0, stream>>>(cnt, n);
  count_k<<<nb_e, 256, 0, stream>>>(dst, cnt, e);
  dis_k<<<nb_n, 256, 0, stream>>>(cnt, dis, n);
  scan_a<<<nb_n, 256, 0, stream>>>(cnt, bsum, n);
  scan_b<<<1, 256, 0, stream>>>(bsum, bpre, off + n, nb_n);
  scan_c<<<nb_n, 256, 0, stream>>>(cnt, bpre, off, cursor, n);
  scatter_k<<<nb_e, 256, 0, stream>>>(src, dst, cursor, csr, e);

  // layer 1: transform-first (A fp32 split)
  mgemm<128, 64, 4, 1, 0, 0, 0, 0, 3><<<dim3(g_narrow, 1), 256, 0, stream>>>(x, wc1, nullptr, t1, n);
  agg64_k<true><<<nb_w, 256, 0, stream>>>(t1, dis, off, csr, b1, h1, n);
  // layer 2: aggregate-first; h2 stored bf16
  agg64_k<false><<<nb_w, 256, 0, stream>>>(h1, dis, off, csr, nullptr, z2, n);
  mgemm<64, 256, 1, 4, 1, 1, 0, 1, 5><<<dim3(g_wide, 1), 256, 0, stream>>>(z2, wc2, b2, h2b, n);
  // layer 3: aggregate-first; z3, h3 bf16 (A bf16 -> single product)
  agg256b_k<<<nb_w, 256, 0, stream>>>(h2b, dis, off, csr, z3b, n);
  mgemm<256, 512, 1, 4, 1, 1, 1, 1, 5><<<dim3(g_wide, 2), 256, 0, stream>>>(z3b, wc3, b3, h3b, n);
  // layer 4: transform-first (A bf16); t4 overwrites h2b region (dead)
  mgemm<512, 64, 4, 1, 0, 0, 1, 0, 5><<<dim3(g_narrow, 1), 256, 0, stream>>>(h3b, wc4, nullptr, t4, n);
  agg64_k<true><<<nb_w, 256, 0, stream>>>(t4, dis, off, csr, b4, h4, n);
  // residual = x @ Wr + br  (z3b dead -> resid region free)
  mgemm<128, 64, 4, 1, 1, 0, 0, 0, 3><<<dim3(g_narrow, 1), 256, 0, stream>>>(x, wcR, br, resid, n);
  // residual + LN
  ln_k<<<nb_w, 256, 0, stream>>>(h4, resid, lng, lnb, hn, n);
  // pool + MLP
  pool_k<<<64, 256, 0, stream>>>(hn, pool, n);
  mlp_k<<<64, 64, 0, stream>>>(pool, f1W, f1b, fng, fnb, f2W, f2b, (float*)d_out);
}

// Round 8
// 535.980 us; speedup vs baseline: 1.0511x; 1.0511x over previous
//
#include <hip/hip_runtime.h>
#include <hip/hip_bf16.h>
#include <math.h>

typedef short bf16x8 __attribute__((ext_vector_type(8)));
typedef short bf16x4 __attribute__((ext_vector_type(4)));
typedef float f32x4 __attribute__((ext_vector_type(4)));

__device__ inline unsigned short f2bf(float f) {
  unsigned u = __float_as_uint(f);
  u += 0x7FFF + ((u >> 16) & 1);           // RNE
  return (unsigned short)(u >> 16);
}
__device__ inline float bf2f(unsigned short h) {
  return __uint_as_float(((unsigned)h) << 16);
}

// ---------------- CSR build ----------------

__global__ __launch_bounds__(256) void zero_i32(int* __restrict__ p, int n) {
  int i = blockIdx.x * 256 + threadIdx.x;
  if (i < n) p[i] = 0;
}

__global__ __launch_bounds__(256) void count_k(const int* __restrict__ dst, int* __restrict__ cnt, int e) {
  int i = blockIdx.x * 256 + threadIdx.x;
  if (i < e) atomicAdd(&cnt[dst[i]], 1);
}

__global__ __launch_bounds__(256) void dis_k(const int* __restrict__ cnt, float* __restrict__ dis, int n) {
  int i = blockIdx.x * 256 + threadIdx.x;
  if (i < n) dis[i] = rsqrtf((float)cnt[i] + 1.0f);
}

// hierarchical scan
__global__ __launch_bounds__(256) void scan_a(const int* __restrict__ cnt, int* __restrict__ bsum, int n) {
  int i = blockIdx.x * 256 + threadIdx.x;
  int v = (i < n) ? cnt[i] : 0;
#pragma unroll
  for (int o = 32; o > 0; o >>= 1) v += __shfl_xor(v, o);
  __shared__ int ws[4];
  if ((threadIdx.x & 63) == 0) ws[threadIdx.x >> 6] = v;
  __syncthreads();
  if (threadIdx.x == 0) bsum[blockIdx.x] = ws[0] + ws[1] + ws[2] + ws[3];
}

__global__ __launch_bounds__(256) void scan_b(const int* __restrict__ bsum, int* __restrict__ bpre,
                                              int* __restrict__ off_n, int nb) {
  __shared__ int s[256];
  int t = threadIdx.x;
  int v = (t < nb) ? bsum[t] : 0;
  s[t] = v;
  __syncthreads();
  for (int o = 1; o < 256; o <<= 1) {
    int u = (t >= o) ? s[t - o] : 0;
    __syncthreads();
    s[t] += u;
    __syncthreads();
  }
  if (t < nb) bpre[t] = s[t] - v;
  if (t == 255) off_n[0] = s[255];
}

__global__ __launch_bounds__(256) void scan_c(const int* __restrict__ cnt, const int* __restrict__ bpre,
                                              int* __restrict__ off, int* __restrict__ cursor, int n) {
  __shared__ int s[256];
  int i = blockIdx.x * 256 + threadIdx.x;
  int t = threadIdx.x;
  int v = (i < n) ? cnt[i] : 0;
  s[t] = v;
  __syncthreads();
  for (int o = 1; o < 256; o <<= 1) {
    int u = (t >= o) ? s[t - o] : 0;
    __syncthreads();
    s[t] += u;
    __syncthreads();
  }
  if (i < n) {
    int ov = bpre[blockIdx.x] + s[t] - v;
    off[i] = ov;
    cursor[i] = ov;
  }
}

__global__ __launch_bounds__(256) void scatter_k(const int* __restrict__ src, const int* __restrict__ dst,
                                                 int* __restrict__ cursor, int* __restrict__ csr, int e) {
  int i = blockIdx.x * 256 + threadIdx.x;
  if (i < e) {
    int p = atomicAdd(&cursor[dst[i]], 1);
    csr[p] = src[i];
  }
}

// ------- weight convert: W[K][N] fp32 -> Wc[N][K] bf16 -------

__global__ __launch_bounds__(256) void wconv_k(const float* __restrict__ W1, const float* __restrict__ Wr,
                                               const float* __restrict__ W2, const float* __restrict__ W3,
                                               const float* __restrict__ W4,
                                               short* __restrict__ o1, short* __restrict__ oR,
                                               short* __restrict__ o2, short* __restrict__ o3,
                                               short* __restrict__ o4) {
  int b = blockIdx.x;  // 960 rows total
  const float* W; short* O; int K, N, nr;
  if (b < 64)       { W = W1; O = o1; K = 128; N = 64;  nr = b; }
  else if (b < 128) { W = Wr; O = oR; K = 128; N = 64;  nr = b - 64; }
  else if (b < 384) { W = W2; O = o2; K = 64;  N = 256; nr = b - 128; }
  else if (b < 896) { W = W3; O = o3; K = 256; N = 512; nr = b - 384; }
  else              { W = W4; O = o4; K = 512; N = 64;  nr = b - 896; }
  for (int k = threadIdx.x; k < K; k += 256)
    O[(size_t)nr * K + k] = (short)f2bf(W[(size_t)k * N + nr]);
}

// ------- MFMA GEMM: C[M,NTOT] = A[M,KT] @ Wc[NTOT,KT](bf16) -------
// ABF=0: A fp32 hi/lo split (2 products). ABF=1: A bf16 (1 product).
// OBF=1 (WM==1 only): bf16 output via LDS-staged coalesced epilogue (full-line writes).
// SPLIT=1: NTOT=128, WM=2,WN=2; wn==0 waves -> Cv (no bias), wn==1 -> Cv2 (+bias). fp32 out.

template<int KT, int NTOT, int WM, int WN, int BIAS, int RELU, int ABF, int OBF, int SPLIT, int BLK>
__global__ __launch_bounds__(256, BLK) void mgemm(const void* __restrict__ Av,
                                                  const short* __restrict__ Wc,
                                                  const float* __restrict__ bias,
                                                  void* __restrict__ Cv, void* __restrict__ Cv2, int M) {
  __shared__ short As[64 * WM][ABF ? 40 : 72];  // [m][hi | lo | pad] or [m][k | pad]
  __shared__ short Bs[64 * WN][40];             // [n][k | pad]
  const int tid = threadIdx.x;
  const int row0 = blockIdx.x * (64 * WM);
  const int col0 = blockIdx.y * (64 * WN);
  const int w = tid >> 6, lane = tid & 63;
  const int wm = w / WN, wn = w % WN;
  const int rm = wm * 64, cn = wn * 64;
  const int lm = lane & 15, lk = (lane >> 4) * 8;

  f32x4 acc[4][4];
#pragma unroll
  for (int i = 0; i < 4; i++)
#pragma unroll
    for (int j = 0; j < 4; j++)
#pragma unroll
      for (int r = 0; r < 4; r++) acc[i][j][r] = 0.f;

  for (int k0 = 0; k0 < KT; k0 += 32) {
    // stage A
#pragma unroll
    for (int p = 0; p < WM; p++) {
      int r = (tid >> 2) + p * 64;
      int kseg = (tid & 3) * 8;
      int gr = row0 + r;
      if (ABF) {
        bf16x8 v = {0, 0, 0, 0, 0, 0, 0, 0};
        if (gr < M) v = *(const bf16x8*)((const short*)Av + (size_t)gr * KT + k0 + kseg);
        *(bf16x8*)&As[r][kseg] = v;
      } else {
        float4 v0 = {0.f, 0.f, 0.f, 0.f}, v1 = {0.f, 0.f, 0.f, 0.f};
        if (gr < M) {
          const float* ap = (const float*)Av + (size_t)gr * KT + k0 + kseg;
          v0 = *(const float4*)ap;
          v1 = *(const float4*)(ap + 4);
        }
        float vv[8] = {v0.x, v0.y, v0.z, v0.w, v1.x, v1.y, v1.z, v1.w};
        bf16x8 hv, lv;
#pragma unroll
        for (int j = 0; j < 8; j++) {
          unsigned short h = f2bf(vv[j]);
          hv[j] = (short)h;
          lv[j] = (short)f2bf(vv[j] - bf2f(h));
        }
        *(bf16x8*)&As[r][kseg] = hv;
        *(bf16x8*)&As[r][32 + kseg] = lv;
      }
    }
    // stage B
#pragma unroll
    for (int p = 0; p < WN; p++) {
      int nr = (tid >> 2) + p * 64;
      int seg = (tid & 3) * 8;
      *(bf16x8*)&Bs[nr][seg] = *(const bf16x8*)(Wc + (size_t)(col0 + nr) * KT + k0 + seg);
    }
    __syncthreads();

    bf16x8 ah[4], al[4], bb[4];
#pragma unroll
    for (int mt = 0; mt < 4; mt++) {
      ah[mt] = *(const bf16x8*)&As[rm + mt * 16 + lm][lk];
      if (!ABF) al[mt] = *(const bf16x8*)&As[rm + mt * 16 + lm][32 + lk];
    }
#pragma unroll
    for (int nt = 0; nt < 4; nt++) bb[nt] = *(const bf16x8*)&Bs[cn + nt * 16 + lm][lk];
#pragma unroll
    for (int mt = 0; mt < 4; mt++)
#pragma unroll
      for (int nt = 0; nt < 4; nt++) {
        acc[mt][nt] = __builtin_amdgcn_mfma_f32_16x16x32_bf16(ah[mt], bb[nt], acc[mt][nt], 0, 0, 0);
        if (!ABF)
          acc[mt][nt] = __builtin_amdgcn_mfma_f32_16x16x32_bf16(al[mt], bb[nt], acc[mt][nt], 0, 0, 0);
      }
    __syncthreads();
  }

  if (SPLIT) {
    // dual 64-wide fp32 outputs; wave-uniform target
    float* O = (wn == 0) ? (float*)Cv : (float*)Cv2;
#pragma unroll
    for (int mt = 0; mt < 4; mt++) {
      int grb = row0 + rm + mt * 16 + (lane >> 4) * 4;
#pragma unroll
      for (int nt = 0; nt < 4; nt++) {
        int gc = nt * 16 + lm;
        float bv = (wn == 1) ? bias[gc] : 0.f;
#pragma unroll
        for (int r = 0; r < 4; r++) {
          int gr = grb + r;
          if (gr < M) O[(size_t)gr * 64 + gc] = acc[mt][nt][r] + bv;
        }
      }
    }
  } else if (OBF && WM == 1) {
    // LDS-staged coalesced bf16 epilogue (Bs is dead -> reuse as staging)
    short* epi = &Bs[0][0];                 // 16 x NCOL shorts needed; Bs has 64*WN*40 >= that
    const int NCOL = 64 * WN;
    float bvv[4];
#pragma unroll
    for (int nt = 0; nt < 4; nt++) bvv[nt] = BIAS ? bias[col0 + cn + nt * 16 + lm] : 0.f;
#pragma unroll
    for (int mt = 0; mt < 4; mt++) {
      __syncthreads();                      // protect epi from previous iter's readers
#pragma unroll
      for (int nt = 0; nt < 4; nt++)
#pragma unroll
        for (int r = 0; r < 4; r++) {
          float v = acc[mt][nt][r] + bvv[nt];
          if (RELU) v = (v >= 0.f) ? v : 0.01f * v;
          epi[((lane >> 4) * 4 + r) * NCOL + cn + nt * 16 + lm] = (short)f2bf(v);
        }
      __syncthreads();
      const int per = (16 * NCOL) / 256;    // shorts per thread (16 for WN=4, 8 for WN=2)
      int base = tid * per;
      int lr = base / NCOL, lc = base % NCOL;
      int gr = row0 + mt * 16 + lr;
      if (gr < M) {
#pragma unroll
        for (int q = 0; q < per / 8; q++)
          *(bf16x8*)((short*)Cv + (size_t)gr * NTOT + col0 + lc + q * 8) = *(bf16x8*)&epi[base + q * 8];
      }
    }
  } else {
    // general path: fp32 (full-line 64B chunks) or unstaged bf16
#pragma unroll
    for (int mt = 0; mt < 4; mt++) {
      int grb = row0 + rm + mt * 16 + (lane >> 4) * 4;
#pragma unroll
      for (int nt = 0; nt < 4; nt++) {
        int gc = col0 + cn + nt * 16 + lm;
        float bv = BIAS ? bias[gc] : 0.f;
#pragma unroll
        for (int r = 0; r < 4; r++) {
          int gr = grb + r;
          if (gr < M) {
            float v = acc[mt][nt][r] + bv;
            if (RELU) v = (v >= 0.f) ? v : 0.01f * v;
            if (OBF) ((short*)Cv)[(size_t)gr * NTOT + gc] = (short)f2bf(v);
            else     ((float*)Cv)[(size_t)gr * NTOT + gc] = v;
          }
        }
      }
    }
  }
}

// ---------------- Aggregation (CSR gather), one wave per node ----------------

template<bool BR>
__global__ __launch_bounds__(256) void agg64_k(const float* __restrict__ T, const float* __restrict__ dis,
                                               const int* __restrict__ off, const int* __restrict__ csr,
                                               const float* __restrict__ bias, float* __restrict__ Out, int n) {
  int wid = (blockIdx.x * 256 + threadIdx.x) >> 6;
  int lane = threadIdx.x & 63;
  if (wid >= n) return;
  float di = dis[wid];
  int e0 = off[wid], e1 = off[wid + 1];
  float acc = 0.f;
  for (int e = e0; e < e1; e++) {
    int j = csr[e];
    acc = fmaf(dis[j], T[(size_t)j * 64 + lane], acc);
  }
  float v = di * acc + di * di * T[(size_t)wid * 64 + lane];
  if (BR) {
    v += bias[lane];
    v = (v >= 0.f) ? v : 0.01f * v;
  }
  Out[(size_t)wid * 64 + lane] = v;
}

// bf16 in, bf16 out variant for the 256-dim layer
__global__ __launch_bounds__(256) void agg256b_k(const short* __restrict__ T, const float* __restrict__ dis,
                                                 const int* __restrict__ off, const int* __restrict__ csr,
                                                 short* __restrict__ Out, int n) {
  int wid = (blockIdx.x * 256 + threadIdx.x) >> 6;
  int lane = threadIdx.x & 63;
  if (wid >= n) return;
  float di = dis[wid];
  int e0 = off[wid], e1 = off[wid + 1];
  float a0 = 0.f, a1 = 0.f, a2 = 0.f, a3 = 0.f;
  for (int e = e0; e < e1; e++) {
    int j = csr[e];
    float dj = dis[j];
    bf16x4 t = *(const bf16x4*)&T[(size_t)j * 256 + lane * 4];
    a0 = fmaf(dj, bf2f((unsigned short)t[0]), a0);
    a1 = fmaf(dj, bf2f((unsigned short)t[1]), a1);
    a2 = fmaf(dj, bf2f((unsigned short)t[2]), a2);
    a3 = fmaf(dj, bf2f((unsigned short)t[3]), a3);
  }
  bf16x4 s = *(const bf16x4*)&T[(size_t)wid * 256 + lane * 4];
  float dii = di * di;
  bf16x4 o;
  o[0] = (short)f2bf(di * a0 + dii * bf2f((unsigned short)s[0]));
  o[1] = (short)f2bf(di * a1 + dii * bf2f((unsigned short)s[1]));
  o[2] = (short)f2bf(di * a2 + dii * bf2f((unsigned short)s[2]));
  o[3] = (short)f2bf(di * a3 + dii * bf2f((unsigned short)s[3]));
  *(bf16x4*)&Out[(size_t)wid * 256 + lane * 4] = o;
}

// ---------------- LN(h4 + resid) ----------------

__global__ __launch_bounds__(256) void ln_k(const float* __restrict__ h4, const float* __restrict__ resid,
                                            const float* __restrict__ g, const float* __restrict__ b,
                                            float* __restrict__ outh, int n) {
  int wid = (blockIdx.x * 256 + threadIdx.x) >> 6;
  int lane = threadIdx.x & 63;
  if (wid >= n) return;
  float v = h4[(size_t)wid * 64 + lane] + resid[(size_t)wid * 64 + lane];
  float s = v, ss = v * v;
#pragma unroll
  for (int o = 32; o > 0; o >>= 1) {
    s += __shfl_xor(s, o);
    ss += __shfl_xor(ss, o);
  }
  float m = s * (1.f / 64.f);
  float var = ss * (1.f / 64.f) - m * m;
  float y = (v - m) * rsqrtf(var + 1e-5f) * g[lane] + b[lane];
  outh[(size_t)wid * 64 + lane] = y;
}

// ---------------- per-graph max pool ----------------

__global__ __launch_bounds__(256) void pool_k(const float* __restrict__ hn, float* __restrict__ p, int n) {
  const int G = 64;
  int g = blockIdx.x;
  int f = threadIdx.x & 63, c = threadIdx.x >> 6;
  long long s = ((long long)g * n + G - 1) / G;
  long long e = ((long long)(g + 1) * n + G - 1) / G;
  float m = -INFINITY;
  for (long long i = s + c; i < e; i += 4) m = fmaxf(m, hn[(size_t)i * 64 + f]);
  __shared__ float red[4][64];
  red[c][f] = m;
  __syncthreads();
  if (c == 0) {
    m = fmaxf(fmaxf(red[0][f], red[1][f]), fmaxf(red[2][f], red[3][f]));
    p[g * 64 + f] = m;
  }
}

// ---------------- final MLP ----------------

__global__ __launch_bounds__(64) void mlp_k(const float* __restrict__ p, const float* __restrict__ fc1W,
                                            const float* __restrict__ fc1b, const float* __restrict__ fng,
                                            const float* __restrict__ fnb, const float* __restrict__ fc2W,
                                            const float* __restrict__ fc2b, float* __restrict__ out) {
  int g = blockIdx.x;
  int lane = threadIdx.x;
  __shared__ float ps[64], qs[64];
  ps[lane] = p[g * 64 + lane];
  __syncthreads();
  float q = fc1b[lane];
#pragma unroll 8
  for (int k = 0; k < 64; k++) q = fmaf(ps[k], fc1W[k * 64 + lane], q);
  float s = q, ss = q * q;
#pragma unroll
  for (int o = 32; o > 0; o >>= 1) {
    s += __shfl_xor(s, o);
    ss += __shfl_xor(ss, o);
  }
  float m = s * (1.f / 64.f);
  float var = ss * (1.f / 64.f) - m * m;
  float y = (q - m) * rsqrtf(var + 1e-5f) * fng[lane] + fnb[lane];
  y = (y >= 0.f) ? y : 0.01f * y;
  qs[lane] = y;
  __syncthreads();
  if (lane < 16) {
    float o = fc2b[lane];
#pragma unroll 8
    for (int k = 0; k < 64; k++) o = fmaf(qs[k], fc2W[k * 16 + lane], o);
    out[g * 16 + lane] = o;
  }
}

// ---------------- launch ----------------

extern "C" void kernel_launch(void* const* d_in, const int* in_sizes, int n_in,
                              void* d_out, int out_size, void* d_ws, size_t ws_size,
                              hipStream_t stream) {
  const float* x   = (const float*)d_in[0];
  const int*   ei  = (const int*)d_in[1];
  const float* W1  = (const float*)d_in[3];
  const float* b1  = (const float*)d_in[4];
  const float* W2  = (const float*)d_in[5];
  const float* b2  = (const float*)d_in[6];
  const float* W3  = (const float*)d_in[7];
  const float* b3  = (const float*)d_in[8];
  const float* W4  = (const float*)d_in[9];
  const float* b4  = (const float*)d_in[10];
  const float* Wr  = (const float*)d_in[11];
  const float* br  = (const float*)d_in[12];
  const float* lng = (const float*)d_in[13];
  const float* lnb = (const float*)d_in[14];
  const float* f1W = (const float*)d_in[15];
  const float* f1b = (const float*)d_in[16];
  const float* fng = (const float*)d_in[17];
  const float* fnb = (const float*)d_in[18];
  const float* f2W = (const float*)d_in[19];
  const float* f2b = (const float*)d_in[20];

  int n = in_sizes[0] / 128;   // 50000
  int e = in_sizes[1] / 2;     // 400000
  const int* src = ei;
  const int* dst = ei + e;

  // Arena (float units; bf16 buffers count n*dim/2):
  //   resid [0,64n)      live: fused L1 -> ln (whole pipeline)
  //   h2b   [64n,192n)   bf16 n x 256; live L2 -> agg256b
  //   t4    [64n,128n)   live L4 -> agg64(3)   (h2b dead)
  //   h4    [128n,192n)  live agg64(3) -> ln   (h2b dead)
  //   z3b   [192n,320n)  bf16 n x 256; live agg256b -> L3 (z2 dead before written)
  //   hn    [192n,256n)  live ln -> pool       (z3b dead)
  //   z2    [256n,320n)  live agg64(2) -> L2
  //   h1    [320n,384n)  t1 [384n,448n)
  //   h3b   [448n,704n)  bf16 n x 512; live L3 -> L4
  //   meta from 704n
  float* arena = (float*)d_ws;
  float* resid = arena;
  short* h2b   = (short*)(arena + (size_t)64 * n);
  float* t4    = arena + (size_t)64 * n;
  float* h4    = arena + (size_t)128 * n;
  short* z3b   = (short*)(arena + (size_t)192 * n);
  float* hn    = arena + (size_t)192 * n;
  float* z2    = arena + (size_t)256 * n;
  float* h1    = arena + (size_t)320 * n;
  float* t1    = arena + (size_t)384 * n;
  short* h3b   = (short*)(arena + (size_t)448 * n);
  float* dis   = arena + (size_t)704 * n;  // n
  int* cnt    = (int*)(dis + n);           // n
  int* off    = cnt + n;                   // n+1
  int* cursor = off + n + 1;               // n
  int* csr    = cursor + n;                // e
  int* bsum   = csr + e;                   // 256
  int* bpre   = bsum + 256;                // 256
  float* pool = (float*)(bpre + 256);      // 64*64
  size_t wq = (((size_t)(pool + 4096)) + 15) & ~(size_t)15;
  short* wc1 = (short*)wq;                 // 64 x 128   (wc1||wcR = fused 128 x 128)
  short* wcR = wc1 + 8192;                 // 64 x 128
  short* wc2 = wcR + 8192;                 // 256 x 64
  short* wc3 = wc2 + 16384;                // 512 x 256
  short* wc4 = wc3 + 131072;               // 64 x 512
  size_t need = ((char*)(wc4 + 32768) - (char*)d_ws) + 64;
  if (ws_size < need) return;

  int nb_n = (n + 255) / 256;     // 196
  int nb_e = (e + 255) / 256;
  int nb_w = (n + 3) / 4;         // one wave per node
  int g_wide = (n + 63) / 64;     // 782
  int g_narrow = (n + 255) / 256; // 196
  int g_fused = (n + 127) / 128;  // 391

  // weights -> bf16 [N][K]
  wconv_k<<<960, 256, 0, stream>>>(W1, Wr, W2, W3, W4, wc1, wcR, wc2, wc3, wc4);

  // degree + CSR (hierarchical scan)
  zero_i32<<<nb_n, 256, 0, stream>>>(cnt, n);
  count_k<<<nb_e, 256, 0, stream>>>(dst, cnt, e);
  dis_k<<<nb_n, 256, 0, stream>>>(cnt, dis, n);
  scan_a<<<nb_n, 256, 0, stream>>>(cnt, bsum, n);
  scan_b<<<1, 256, 0, stream>>>(bsum, bpre, off + n, nb_n);
  scan_c<<<nb_n, 256, 0, stream>>>(cnt, bpre, off, cursor, n);
  scatter_k<<<nb_e, 256, 0, stream>>>(src, dst, cursor, csr, e);

  // fused layer-1 transform + residual: [t1 | resid] = x @ [W1 | Wr] (+br on resid half)
  mgemm<128, 128, 2, 2, 1, 0, 0, 0, 1, 4><<<dim3(g_fused, 1), 256, 0, stream>>>(x, wc1, br, t1, resid, n);
  agg64_k<true><<<nb_w, 256, 0, stream>>>(t1, dis, off, csr, b1, h1, n);
  // layer 2: aggregate-first; h2 stored bf16 (coalesced staged epilogue)
  agg64_k<false><<<nb_w, 256, 0, stream>>>(h1, dis, off, csr, nullptr, z2, n);
  mgemm<64, 256, 1, 4, 1, 1, 0, 1, 0, 5><<<dim3(g_wide, 1), 256, 0, stream>>>(z2, wc2, b2, h2b, nullptr, n);
  // layer 3: aggregate-first; z3/h3 bf16 (A bf16 single product; staged epilogue)
  agg256b_k<<<nb_w, 256, 0, stream>>>(h2b, dis, off, csr, z3b, n);
  mgemm<256, 512, 1, 4, 1, 1, 1, 1, 0, 5><<<dim3(g_wide, 2), 256, 0, stream>>>(z3b, wc3, b3, h3b, nullptr, n);
  // layer 4: transform-first (A bf16, fp32 out)
  mgemm<512, 64, 4, 1, 0, 0, 1, 0, 0, 5><<<dim3(g_narrow, 1), 256, 0, stream>>>(h3b, wc4, nullptr, t4, nullptr, n);
  agg64_k<true><<<nb_w, 256, 0, stream>>>(t4, dis, off, csr, b4, h4, n);
  // residual + LN
  ln_k<<<nb_w, 256, 0, stream>>>(h4, resid, lng, lnb, hn, n);
  // pool + MLP
  pool_k<<<64, 256, 0, stream>>>(hn, pool, n);
  mlp_k<<<64, 64, 0, stream>>>(pool, f1W, f1b, fng, fnb, f2W, f2b, (float*)d_out);
}

// Round 9
// 493.637 us; speedup vs baseline: 1.1413x; 1.0858x over previous
//
#include <hip/hip_runtime.h>
#include <hip/hip_bf16.h>
#include <math.h>

typedef short bf16x8 __attribute__((ext_vector_type(8)));
typedef short bf16x4 __attribute__((ext_vector_type(4)));
typedef float f32x4 __attribute__((ext_vector_type(4)));

__device__ inline unsigned short f2bf(float f) {
  unsigned u = __float_as_uint(f);
  u += 0x7FFF + ((u >> 16) & 1);           // RNE
  return (unsigned short)(u >> 16);
}
__device__ inline float bf2f(unsigned short h) {
  return __uint_as_float(((unsigned)h) << 16);
}

// ---------------- CSR build ----------------

__global__ __launch_bounds__(256) void zero_i32(int* __restrict__ p, int n) {
  int i = blockIdx.x * 256 + threadIdx.x;
  if (i < n) p[i] = 0;
}

__global__ __launch_bounds__(256) void count_k(const int* __restrict__ dst, int* __restrict__ cnt, int e) {
  int i = blockIdx.x * 256 + threadIdx.x;
  if (i < e) atomicAdd(&cnt[dst[i]], 1);
}

__global__ __launch_bounds__(256) void dis_k(const int* __restrict__ cnt, float* __restrict__ dis, int n) {
  int i = blockIdx.x * 256 + threadIdx.x;
  if (i < n) dis[i] = rsqrtf((float)cnt[i] + 1.0f);
}

// hierarchical scan
__global__ __launch_bounds__(256) void scan_a(const int* __restrict__ cnt, int* __restrict__ bsum, int n) {
  int i = blockIdx.x * 256 + threadIdx.x;
  int v = (i < n) ? cnt[i] : 0;
#pragma unroll
  for (int o = 32; o > 0; o >>= 1) v += __shfl_xor(v, o);
  __shared__ int ws[4];
  if ((threadIdx.x & 63) == 0) ws[threadIdx.x >> 6] = v;
  __syncthreads();
  if (threadIdx.x == 0) bsum[blockIdx.x] = ws[0] + ws[1] + ws[2] + ws[3];
}

__global__ __launch_bounds__(256) void scan_b(const int* __restrict__ bsum, int* __restrict__ bpre,
                                              int* __restrict__ off_n, int nb) {
  __shared__ int s[256];
  int t = threadIdx.x;
  int v = (t < nb) ? bsum[t] : 0;
  s[t] = v;
  __syncthreads();
  for (int o = 1; o < 256; o <<= 1) {
    int u = (t >= o) ? s[t - o] : 0;
    __syncthreads();
    s[t] += u;
    __syncthreads();
  }
  if (t < nb) bpre[t] = s[t] - v;
  if (t == 255) off_n[0] = s[255];
}

__global__ __launch_bounds__(256) void scan_c(const int* __restrict__ cnt, const int* __restrict__ bpre,
                                              int* __restrict__ off, int* __restrict__ cursor, int n) {
  __shared__ int s[256];
  int i = blockIdx.x * 256 + threadIdx.x;
  int t = threadIdx.x;
  int v = (i < n) ? cnt[i] : 0;
  s[t] = v;
  __syncthreads();
  for (int o = 1; o < 256; o <<= 1) {
    int u = (t >= o) ? s[t - o] : 0;
    __syncthreads();
    s[t] += u;
    __syncthreads();
  }
  if (i < n) {
    int ov = bpre[blockIdx.x] + s[t] - v;
    off[i] = ov;
    cursor[i] = ov;
  }
}

__global__ __launch_bounds__(256) void scatter_k(const int* __restrict__ src, const int* __restrict__ dst,
                                                 int* __restrict__ cursor, int* __restrict__ csr, int e) {
  int i = blockIdx.x * 256 + threadIdx.x;
  if (i < e) {
    int p = atomicAdd(&cursor[dst[i]], 1);
    csr[p] = src[i];
  }
}

// ------- weight convert: W[K][N] fp32 -> Wc[N][K] bf16 -------

__global__ __launch_bounds__(256) void wconv_k(const float* __restrict__ W1, const float* __restrict__ Wr,
                                               const float* __restrict__ W2, const float* __restrict__ W3,
                                               const float* __restrict__ W4,
                                               short* __restrict__ o1, short* __restrict__ oR,
                                               short* __restrict__ o2, short* __restrict__ o3,
                                               short* __restrict__ o4) {
  int b = blockIdx.x;  // 960 rows total
  const float* W; short* O; int K, N, nr;
  if (b < 64)       { W = W1; O = o1; K = 128; N = 64;  nr = b; }
  else if (b < 128) { W = Wr; O = oR; K = 128; N = 64;  nr = b - 64; }
  else if (b < 384) { W = W2; O = o2; K = 64;  N = 256; nr = b - 128; }
  else if (b < 896) { W = W3; O = o3; K = 256; N = 512; nr = b - 384; }
  else              { W = W4; O = o4; K = 512; N = 64;  nr = b - 896; }
  for (int k = threadIdx.x; k < K; k += 256)
    O[(size_t)nr * K + k] = (short)f2bf(W[(size_t)k * N + nr]);
}

// ------- MFMA GEMM (generic): C[M,NTOT] = A[M,KT] @ Wc[NTOT,KT](bf16) -------
// ABF=0: A fp32 hi/lo split (2 products). ABF=1: A bf16 (1 product).
// OBF=1 (WM==1): bf16 out via LDS-staged coalesced epilogue.
// SPLIT=1: NTOT=128, WM=2,WN=2; wn==0 -> Cv (no bias), wn==1 -> Cv2 (+bias). fp32 out.

template<int KT, int NTOT, int WM, int WN, int BIAS, int RELU, int ABF, int OBF, int SPLIT, int BLK>
__global__ __launch_bounds__(256, BLK) void mgemm(const void* __restrict__ Av,
                                                  const short* __restrict__ Wc,
                                                  const float* __restrict__ bias,
                                                  void* __restrict__ Cv, void* __restrict__ Cv2, int M) {
  __shared__ short As[64 * WM][ABF ? 40 : 72];
  __shared__ short Bs[64 * WN][40];
  const int tid = threadIdx.x;
  const int row0 = blockIdx.x * (64 * WM);
  const int col0 = blockIdx.y * (64 * WN);
  const int w = tid >> 6, lane = tid & 63;
  const int wm = w / WN, wn = w % WN;
  const int rm = wm * 64, cn = wn * 64;
  const int lm = lane & 15, lk = (lane >> 4) * 8;

  f32x4 acc[4][4];
#pragma unroll
  for (int i = 0; i < 4; i++)
#pragma unroll
    for (int j = 0; j < 4; j++)
#pragma unroll
      for (int r = 0; r < 4; r++) acc[i][j][r] = 0.f;

  for (int k0 = 0; k0 < KT; k0 += 32) {
#pragma unroll
    for (int p = 0; p < WM; p++) {
      int r = (tid >> 2) + p * 64;
      int kseg = (tid & 3) * 8;
      int gr = row0 + r;
      if (ABF) {
        bf16x8 v = {0, 0, 0, 0, 0, 0, 0, 0};
        if (gr < M) v = *(const bf16x8*)((const short*)Av + (size_t)gr * KT + k0 + kseg);
        *(bf16x8*)&As[r][kseg] = v;
      } else {
        float4 v0 = {0.f, 0.f, 0.f, 0.f}, v1 = {0.f, 0.f, 0.f, 0.f};
        if (gr < M) {
          const float* ap = (const float*)Av + (size_t)gr * KT + k0 + kseg;
          v0 = *(const float4*)ap;
          v1 = *(const float4*)(ap + 4);
        }
        float vv[8] = {v0.x, v0.y, v0.z, v0.w, v1.x, v1.y, v1.z, v1.w};
        bf16x8 hv, lv;
#pragma unroll
        for (int j = 0; j < 8; j++) {
          unsigned short h = f2bf(vv[j]);
          hv[j] = (short)h;
          lv[j] = (short)f2bf(vv[j] - bf2f(h));
        }
        *(bf16x8*)&As[r][kseg] = hv;
        *(bf16x8*)&As[r][32 + kseg] = lv;
      }
    }
#pragma unroll
    for (int p = 0; p < WN; p++) {
      int nr = (tid >> 2) + p * 64;
      int seg = (tid & 3) * 8;
      *(bf16x8*)&Bs[nr][seg] = *(const bf16x8*)(Wc + (size_t)(col0 + nr) * KT + k0 + seg);
    }
    __syncthreads();

    bf16x8 ah[4], al[4], bb[4];
#pragma unroll
    for (int mt = 0; mt < 4; mt++) {
      ah[mt] = *(const bf16x8*)&As[rm + mt * 16 + lm][lk];
      if (!ABF) al[mt] = *(const bf16x8*)&As[rm + mt * 16 + lm][32 + lk];
    }
#pragma unroll
    for (int nt = 0; nt < 4; nt++) bb[nt] = *(const bf16x8*)&Bs[cn + nt * 16 + lm][lk];
#pragma unroll
    for (int mt = 0; mt < 4; mt++)
#pragma unroll
      for (int nt = 0; nt < 4; nt++) {
        acc[mt][nt] = __builtin_amdgcn_mfma_f32_16x16x32_bf16(ah[mt], bb[nt], acc[mt][nt], 0, 0, 0);
        if (!ABF)
          acc[mt][nt] = __builtin_amdgcn_mfma_f32_16x16x32_bf16(al[mt], bb[nt], acc[mt][nt], 0, 0, 0);
      }
    __syncthreads();
  }

  if (SPLIT) {
    float* O = (wn == 0) ? (float*)Cv : (float*)Cv2;
#pragma unroll
    for (int mt = 0; mt < 4; mt++) {
      int grb = row0 + rm + mt * 16 + (lane >> 4) * 4;
#pragma unroll
      for (int nt = 0; nt < 4; nt++) {
        int gc = nt * 16 + lm;
        float bv = (wn == 1) ? bias[gc] : 0.f;
#pragma unroll
        for (int r = 0; r < 4; r++) {
          int gr = grb + r;
          if (gr < M) O[(size_t)gr * 64 + gc] = acc[mt][nt][r] + bv;
        }
      }
    }
  } else if (OBF && WM == 1) {
    short* epi = &Bs[0][0];
    const int NCOL = 64 * WN;
    float bvv[4];
#pragma unroll
    for (int nt = 0; nt < 4; nt++) bvv[nt] = BIAS ? bias[col0 + cn + nt * 16 + lm] : 0.f;
#pragma unroll
    for (int mt = 0; mt < 4; mt++) {
      __syncthreads();
#pragma unroll
      for (int nt = 0; nt < 4; nt++)
#pragma unroll
        for (int r = 0; r < 4; r++) {
          float v = acc[mt][nt][r] + bvv[nt];
          if (RELU) v = (v >= 0.f) ? v : 0.01f * v;
          epi[((lane >> 4) * 4 + r) * NCOL + cn + nt * 16 + lm] = (short)f2bf(v);
        }
      __syncthreads();
      const int per = (16 * NCOL) / 256;
      int base = tid * per;
      int lr = base / NCOL, lc = base % NCOL;
      int gr = row0 + mt * 16 + lr;
      if (gr < M) {
#pragma unroll
        for (int q = 0; q < per / 8; q++)
          *(bf16x8*)((short*)Cv + (size_t)gr * NTOT + col0 + lc + q * 8) = *(bf16x8*)&epi[base + q * 8];
      }
    }
  } else {
#pragma unroll
    for (int mt = 0; mt < 4; mt++) {
      int grb = row0 + rm + mt * 16 + (lane >> 4) * 4;
#pragma unroll
      for (int nt = 0; nt < 4; nt++) {
        int gc = col0 + cn + nt * 16 + lm;
        float bv = BIAS ? bias[gc] : 0.f;
#pragma unroll
        for (int r = 0; r < 4; r++) {
          int gr = grb + r;
          if (gr < M) {
            float v = acc[mt][nt][r] + bv;
            if (RELU) v = (v >= 0.f) ? v : 0.01f * v;
            if (OBF) ((short*)Cv)[(size_t)gr * NTOT + gc] = (short)f2bf(v);
            else     ((float*)Cv)[(size_t)gr * NTOT + gc] = v;
          }
        }
      }
    }
  }
}

// ------- fused layer3+layer4: t4 = leaky(z3 @ W3 + b3) @ W4, h3 never hits HBM -------
// 64-row strip per block, 4 waves (wave w owns rows w*16..w*16+15).
// For each of 8 column-chunks c of h3: stage-1 MFMA (K=256) -> +b3,leaky -> bf16 -> Hs
// (C-layout -> A-layout via LDS) -> stage-2 MFMA with W4 chunk into persistent t4 acc.

__global__ __launch_bounds__(256, 5) void fused34_k(const short* __restrict__ z3,
                                                    const short* __restrict__ W3c,  // [512][256] bf16
                                                    const float* __restrict__ b3,
                                                    const short* __restrict__ W4c,  // [64][512] bf16
                                                    float* __restrict__ T4, int M) {
  __shared__ short As[64][40];   // z3 k-chunk
  __shared__ short Bs[64][40];   // W3 chunk rows, k-chunk
  __shared__ short Hs[64][72];   // h3 chunk (64 rows x 64 cols), A-layout
  __shared__ short Ws4[64][72];  // W4 chunk: 64 n x 64 k
  const int tid = threadIdx.x;
  const int row0 = blockIdx.x * 64;
  const int w = tid >> 6, lane = tid & 63;
  const int lm = lane & 15, lk = (lane >> 4) * 8;
  const int rquad = (lane >> 4) * 4;
  const int srow = tid >> 2, sseg = (tid & 3) * 8;

  f32x4 t4acc[4];
#pragma unroll
  for (int nt = 0; nt < 4; nt++)
#pragma unroll
    for (int r = 0; r < 4; r++) t4acc[nt][r] = 0.f;

  for (int c = 0; c < 8; c++) {
    f32x4 acc1[4];
#pragma unroll
    for (int nt = 0; nt < 4; nt++)
#pragma unroll
      for (int r = 0; r < 4; r++) acc1[nt][r] = 0.f;

    for (int k0 = 0; k0 < 256; k0 += 32) {
      // stage z3 rows (k-chunk) + W3 chunk-c rows (k-chunk)
      {
        int gr = row0 + srow;
        bf16x8 v = {0, 0, 0, 0, 0, 0, 0, 0};
        if (gr < M) v = *(const bf16x8*)(z3 + (size_t)gr * 256 + k0 + sseg);
        *(bf16x8*)&As[srow][sseg] = v;
        *(bf16x8*)&Bs[srow][sseg] = *(const bf16x8*)(W3c + (size_t)(c * 64 + srow) * 256 + k0 + sseg);
      }
      __syncthreads();
      bf16x8 ah = *(const bf16x8*)&As[w * 16 + lm][lk];
      bf16x8 bb[4];
#pragma unroll
      for (int nt = 0; nt < 4; nt++) bb[nt] = *(const bf16x8*)&Bs[nt * 16 + lm][lk];
#pragma unroll
      for (int nt = 0; nt < 4; nt++)
        acc1[nt] = __builtin_amdgcn_mfma_f32_16x16x32_bf16(ah, bb[nt], acc1[nt], 0, 0, 0);
      __syncthreads();
    }
    // h3 chunk: bias + leaky -> bf16 -> Hs (wave-private rows)
#pragma unroll
    for (int nt = 0; nt < 4; nt++) {
      float bv = b3[c * 64 + nt * 16 + lm];
#pragma unroll
      for (int r = 0; r < 4; r++) {
        float v = acc1[nt][r] + bv;
        v = (v >= 0.f) ? v : 0.01f * v;
        Hs[w * 16 + rquad + r][nt * 16 + lm] = (short)f2bf(v);
      }
    }
    // stage W4 chunk (k-range c*64..c*64+63 for all 64 outputs)
    *(bf16x8*)&Ws4[srow][sseg]      = *(const bf16x8*)(W4c + (size_t)srow * 512 + c * 64 + sseg);
    *(bf16x8*)&Ws4[srow][32 + sseg] = *(const bf16x8*)(W4c + (size_t)srow * 512 + c * 64 + 32 + sseg);
    __syncthreads();
    // stage-2: t4 += h3_chunk @ W4_chunk (k=64 -> 2 sub-chunks)
#pragma unroll
    for (int kk = 0; kk < 64; kk += 32) {
      bf16x8 ah2 = *(const bf16x8*)&Hs[w * 16 + lm][kk + lk];
      bf16x8 bb2[4];
#pragma unroll
      for (int nt = 0; nt < 4; nt++) bb2[nt] = *(const bf16x8*)&Ws4[nt * 16 + lm][kk + lk];
#pragma unroll
      for (int nt = 0; nt < 4; nt++)
        t4acc[nt] = __builtin_amdgcn_mfma_f32_16x16x32_bf16(ah2, bb2[nt], t4acc[nt], 0, 0, 0);
    }
    __syncthreads();
  }
  // epilogue: t4 fp32 (64B per quad, full lines)
#pragma unroll
  for (int nt = 0; nt < 4; nt++) {
    int gc = nt * 16 + lm;
#pragma unroll
    for (int r = 0; r < 4; r++) {
      int gr = row0 + w * 16 + rquad + r;
      if (gr < M) T4[(size_t)gr * 64 + gc] = t4acc[nt][r];
    }
  }
}

// ---------------- Aggregation (CSR gather), one wave per node ----------------

template<bool BR>
__global__ __launch_bounds__(256) void agg64_k(const float* __restrict__ T, const float* __restrict__ dis,
                                               const int* __restrict__ off, const int* __restrict__ csr,
                                               const float* __restrict__ bias, float* __restrict__ Out, int n) {
  int wid = (blockIdx.x * 256 + threadIdx.x) >> 6;
  int lane = threadIdx.x & 63;
  if (wid >= n) return;
  float di = dis[wid];
  int e0 = off[wid], e1 = off[wid + 1];
  float acc = 0.f;
  for (int e = e0; e < e1; e++) {
    int j = csr[e];
    acc = fmaf(dis[j], T[(size_t)j * 64 + lane], acc);
  }
  float v = di * acc + di * di * T[(size_t)wid * 64 + lane];
  if (BR) {
    v += bias[lane];
    v = (v >= 0.f) ? v : 0.01f * v;
  }
  Out[(size_t)wid * 64 + lane] = v;
}

// bf16 in, bf16 out variant for the 256-dim layer
__global__ __launch_bounds__(256) void agg256b_k(const short* __restrict__ T, const float* __restrict__ dis,
                                                 const int* __restrict__ off, const int* __restrict__ csr,
                                                 short* __restrict__ Out, int n) {
  int wid = (blockIdx.x * 256 + threadIdx.x) >> 6;
  int lane = threadIdx.x & 63;
  if (wid >= n) return;
  float di = dis[wid];
  int e0 = off[wid], e1 = off[wid + 1];
  float a0 = 0.f, a1 = 0.f, a2 = 0.f, a3 = 0.f;
  for (int e = e0; e < e1; e++) {
    int j = csr[e];
    float dj = dis[j];
    bf16x4 t = *(const bf16x4*)&T[(size_t)j * 256 + lane * 4];
    a0 = fmaf(dj, bf2f((unsigned short)t[0]), a0);
    a1 = fmaf(dj, bf2f((unsigned short)t[1]), a1);
    a2 = fmaf(dj, bf2f((unsigned short)t[2]), a2);
    a3 = fmaf(dj, bf2f((unsigned short)t[3]), a3);
  }
  bf16x4 s = *(const bf16x4*)&T[(size_t)wid * 256 + lane * 4];
  float dii = di * di;
  bf16x4 o;
  o[0] = (short)f2bf(di * a0 + dii * bf2f((unsigned short)s[0]));
  o[1] = (short)f2bf(di * a1 + dii * bf2f((unsigned short)s[1]));
  o[2] = (short)f2bf(di * a2 + dii * bf2f((unsigned short)s[2]));
  o[3] = (short)f2bf(di * a3 + dii * bf2f((unsigned short)s[3]));
  *(bf16x4*)&Out[(size_t)wid * 256 + lane * 4] = o;
}

// ---------------- LN(h4 + resid) ----------------

__global__ __launch_bounds__(256) void ln_k(const float* __restrict__ h4, const float* __restrict__ resid,
                                            const float* __restrict__ g, const float* __restrict__ b,
                                            float* __restrict__ outh, int n) {
  int wid = (blockIdx.x * 256 + threadIdx.x) >> 6;
  int lane = threadIdx.x & 63;
  if (wid >= n) return;
  float v = h4[(size_t)wid * 64 + lane] + resid[(size_t)wid * 64 + lane];
  float s = v, ss = v * v;
#pragma unroll
  for (int o = 32; o > 0; o >>= 1) {
    s += __shfl_xor(s, o);
    ss += __shfl_xor(ss, o);
  }
  float m = s * (1.f / 64.f);
  float var = ss * (1.f / 64.f) - m * m;
  float y = (v - m) * rsqrtf(var + 1e-5f) * g[lane] + b[lane];
  outh[(size_t)wid * 64 + lane] = y;
}

// ---------------- per-graph max pool ----------------

__global__ __launch_bounds__(256) void pool_k(const float* __restrict__ hn, float* __restrict__ p, int n) {
  const int G = 64;
  int g = blockIdx.x;
  int f = threadIdx.x & 63, c = threadIdx.x >> 6;
  long long s = ((long long)g * n + G - 1) / G;
  long long e = ((long long)(g + 1) * n + G - 1) / G;
  float m = -INFINITY;
  for (long long i = s + c; i < e; i += 4) m = fmaxf(m, hn[(size_t)i * 64 + f]);
  __shared__ float red[4][64];
  red[c][f] = m;
  __syncthreads();
  if (c == 0) {
    m = fmaxf(fmaxf(red[0][f], red[1][f]), fmaxf(red[2][f], red[3][f]));
    p[g * 64 + f] = m;
  }
}

// ---------------- final MLP ----------------

__global__ __launch_bounds__(64) void mlp_k(const float* __restrict__ p, const float* __restrict__ fc1W,
                                            const float* __restrict__ fc1b, const float* __restrict__ fng,
                                            const float* __restrict__ fnb, const float* __restrict__ fc2W,
                                            const float* __restrict__ fc2b, float* __restrict__ out) {
  int g = blockIdx.x;
  int lane = threadIdx.x;
  __shared__ float ps[64], qs[64];
  ps[lane] = p[g * 64 + lane];
  __syncthreads();
  float q = fc1b[lane];
#pragma unroll 8
  for (int k = 0; k < 64; k++) q = fmaf(ps[k], fc1W[k * 64 + lane], q);
  float s = q, ss = q * q;
#pragma unroll
  for (int o = 32; o > 0; o >>= 1) {
    s += __shfl_xor(s, o);
    ss += __shfl_xor(ss, o);
  }
  float m = s * (1.f / 64.f);
  float var = ss * (1.f / 64.f) - m * m;
  float y = (q - m) * rsqrtf(var + 1e-5f) * fng[lane] + fnb[lane];
  y = (y >= 0.f) ? y : 0.01f * y;
  qs[lane] = y;
  __syncthreads();
  if (lane < 16) {
    float o = fc2b[lane];
#pragma unroll 8
    for (int k = 0; k < 64; k++) o = fmaf(qs[k], fc2W[k * 16 + lane], o);
    out[g * 16 + lane] = o;
  }
}

// ---------------- launch ----------------

extern "C" void kernel_launch(void* const* d_in, const int* in_sizes, int n_in,
                              void* d_out, int out_size, void* d_ws, size_t ws_size,
                              hipStream_t stream) {
  const float* x   = (const float*)d_in[0];
  const int*   ei  = (const int*)d_in[1];
  const float* W1  = (const float*)d_in[3];
  const float* b1  = (const float*)d_in[4];
  const float* W2  = (const float*)d_in[5];
  const float* b2  = (const float*)d_in[6];
  const float* W3  = (const float*)d_in[7];
  const float* b3  = (const float*)d_in[8];
  const float* W4  = (const float*)d_in[9];
  const float* b4  = (const float*)d_in[10];
  const float* Wr  = (const float*)d_in[11];
  const float* br  = (const float*)d_in[12];
  const float* lng = (const float*)d_in[13];
  const float* lnb = (const float*)d_in[14];
  const float* f1W = (const float*)d_in[15];
  const float* f1b = (const float*)d_in[16];
  const float* fng = (const float*)d_in[17];
  const float* fnb = (const float*)d_in[18];
  const float* f2W = (const float*)d_in[19];
  const float* f2b = (const float*)d_in[20];

  int n = in_sizes[0] / 128;   // 50000
  int e = in_sizes[1] / 2;     // 400000
  const int* src = ei;
  const int* dst = ei + e;

  // Arena (float units; bf16 buffers count n*dim/2):
  //   resid [0,64n)      live: fused L1 -> ln
  //   h2b   [64n,192n)   bf16 n x 256; live L2 -> agg256b
  //   t4    [64n,128n)   live fused34 -> agg64(4)   (h2b dead)
  //   h4    [128n,192n)  live agg64(4) -> ln        (h2b dead)
  //   z3b   [192n,320n)  bf16 n x 256; live agg256b -> fused34 (z2 dead when written)
  //   hn    [192n,256n)  live ln -> pool            (z3b dead)
  //   z2    [256n,320n)  live agg64(2) -> L2
  //   h1    [320n,384n)  t1 [384n,448n)
  //   meta from 448n
  float* arena = (float*)d_ws;
  float* resid = arena;
  short* h2b   = (short*)(arena + (size_t)64 * n);
  float* t4    = arena + (size_t)64 * n;
  float* h4    = arena + (size_t)128 * n;
  short* z3b   = (short*)(arena + (size_t)192 * n);
  float* hn    = arena + (size_t)192 * n;
  float* z2    = arena + (size_t)256 * n;
  float* h1    = arena + (size_t)320 * n;
  float* t1    = arena + (size_t)384 * n;
  float* dis   = arena + (size_t)448 * n;  // n
  int* cnt    = (int*)(dis + n);           // n
  int* off    = cnt + n;                   // n+1
  int* cursor = off + n + 1;               // n
  int* csr    = cursor + n;                // e
  int* bsum   = csr + e;                   // 256
  int* bpre   = bsum + 256;                // 256
  float* pool = (float*)(bpre + 256);      // 64*64
  size_t wq = (((size_t)(pool + 4096)) + 15) & ~(size_t)15;
  short* wc1 = (short*)wq;                 // 64 x 128   (wc1||wcR = fused 128 x 128)
  short* wcR = wc1 + 8192;                 // 64 x 128
  short* wc2 = wcR + 8192;                 // 256 x 64
  short* wc3 = wc2 + 16384;                // 512 x 256
  short* wc4 = wc3 + 131072;               // 64 x 512
  size_t need = ((char*)(wc4 + 32768) - (char*)d_ws) + 64;
  if (ws_size < need) return;

  int nb_n = (n + 255) / 256;     // 196
  int nb_e = (e + 255) / 256;
  int nb_w = (n + 3) / 4;         // one wave per node
  int g_wide = (n + 63) / 64;     // 782
  int g_fused = (n + 127) / 128;  // 391

  // weights -> bf16 [N][K]
  wconv_k<<<960, 256, 0, stream>>>(W1, Wr, W2, W3, W4, wc1, wcR, wc2, wc3, wc4);

  // degree + CSR (hierarchical scan)
  zero_i32<<<nb_n, 256, 0, stream>>>(cnt, n);
  count_k<<<nb_e, 256, 0, stream>>>(dst, cnt, e);
  dis_k<<<nb_n, 256, 0, stream>>>(cnt, dis, n);
  scan_a<<<nb_n, 256, 0, stream>>>(cnt, bsum, n);
  scan_b<<<1, 256, 0, stream>>>(bsum, bpre, off + n, nb_n);
  scan_c<<<nb_n, 256, 0, stream>>>(cnt, bpre, off, cursor, n);
  scatter_k<<<nb_e, 256, 0, stream>>>(src, dst, cursor, csr, e);

  // fused layer-1 transform + residual: [t1 | resid] = x @ [W1 | Wr] (+br on resid half)
  mgemm<128, 128, 2, 2, 1, 0, 0, 0, 1, 4><<<dim3(g_fused, 1), 256, 0, stream>>>(x, wc1, br, t1, resid, n);
  agg64_k<true><<<nb_w, 256, 0, stream>>>(t1, dis, off, csr, b1, h1, n);
  // layer 2: aggregate-first; h2 stored bf16 (coalesced staged epilogue)
  agg64_k<false><<<nb_w, 256, 0, stream>>>(h1, dis, off, csr, nullptr, z2, n);
  mgemm<64, 256, 1, 4, 1, 1, 0, 1, 0, 5><<<dim3(g_wide, 1), 256, 0, stream>>>(z2, wc2, b2, h2b, nullptr, n);
  // layer 3 aggregate, then fused L3-GEMM + L4-GEMM (h3 stays on-chip)
  agg256b_k<<<nb_w, 256, 0, stream>>>(h2b, dis, off, csr, z3b, n);
  fused34_k<<<g_wide, 256, 0, stream>>>(z3b, wc3, b3, wc4, t4, n);
  agg64_k<true><<<nb_w, 256, 0, stream>>>(t4, dis, off, csr, b4, h4, n);
  // residual + LN
  ln_k<<<nb_w, 256, 0, stream>>>(h4, resid, lng, lnb, hn, n);
  // pool + MLP
  pool_k<<<64, 256, 0, stream>>>(hn, pool, n);
  mlp_k<<<64, 64, 0, stream>>>(pool, f1W, f1b, fng, fnb, f2W, f2b, (float*)d_out);
}

// Round 10
// 468.074 us; speedup vs baseline: 1.2036x; 1.0546x over previous
//
#include <hip/hip_runtime.h>
#include <hip/hip_bf16.h>
#include <math.h>

typedef short bf16x8 __attribute__((ext_vector_type(8)));
typedef short bf16x4 __attribute__((ext_vector_type(4)));
typedef float f32x4 __attribute__((ext_vector_type(4)));

__device__ inline unsigned short f2bf(float f) {
  unsigned u = __float_as_uint(f);
  u += 0x7FFF + ((u >> 16) & 1);           // RNE
  return (unsigned short)(u >> 16);
}
__device__ inline float bf2f(unsigned short h) {
  return __uint_as_float(((unsigned)h) << 16);
}

// ---------------- CSR build ----------------

__global__ __launch_bounds__(256) void zero_i32(int* __restrict__ p, int n) {
  int i = blockIdx.x * 256 + threadIdx.x;
  if (i < n) p[i] = 0;
}

__global__ __launch_bounds__(256) void count_k(const int* __restrict__ dst, int* __restrict__ cnt, int e) {
  int i = blockIdx.x * 256 + threadIdx.x;
  if (i < e) atomicAdd(&cnt[dst[i]], 1);
}

__global__ __launch_bounds__(256) void dis_k(const int* __restrict__ cnt, float* __restrict__ dis, int n) {
  int i = blockIdx.x * 256 + threadIdx.x;
  if (i < n) dis[i] = rsqrtf((float)cnt[i] + 1.0f);
}

// hierarchical scan
__global__ __launch_bounds__(256) void scan_a(const int* __restrict__ cnt, int* __restrict__ bsum, int n) {
  int i = blockIdx.x * 256 + threadIdx.x;
  int v = (i < n) ? cnt[i] : 0;
#pragma unroll
  for (int o = 32; o > 0; o >>= 1) v += __shfl_xor(v, o);
  __shared__ int ws[4];
  if ((threadIdx.x & 63) == 0) ws[threadIdx.x >> 6] = v;
  __syncthreads();
  if (threadIdx.x == 0) bsum[blockIdx.x] = ws[0] + ws[1] + ws[2] + ws[3];
}

__global__ __launch_bounds__(256) void scan_b(const int* __restrict__ bsum, int* __restrict__ bpre,
                                              int* __restrict__ off_n, int nb) {
  __shared__ int s[256];
  int t = threadIdx.x;
  int v = (t < nb) ? bsum[t] : 0;
  s[t] = v;
  __syncthreads();
  for (int o = 1; o < 256; o <<= 1) {
    int u = (t >= o) ? s[t - o] : 0;
    __syncthreads();
    s[t] += u;
    __syncthreads();
  }
  if (t < nb) bpre[t] = s[t] - v;
  if (t == 255) off_n[0] = s[255];
}

__global__ __launch_bounds__(256) void scan_c(const int* __restrict__ cnt, const int* __restrict__ bpre,
                                              int* __restrict__ off, int* __restrict__ cursor, int n) {
  __shared__ int s[256];
  int i = blockIdx.x * 256 + threadIdx.x;
  int t = threadIdx.x;
  int v = (i < n) ? cnt[i] : 0;
  s[t] = v;
  __syncthreads();
  for (int o = 1; o < 256; o <<= 1) {
    int u = (t >= o) ? s[t - o] : 0;
    __syncthreads();
    s[t] += u;
    __syncthreads();
  }
  if (i < n) {
    int ov = bpre[blockIdx.x] + s[t] - v;
    off[i] = ov;
    cursor[i] = ov;
  }
}

__global__ __launch_bounds__(256) void scatter_k(const int* __restrict__ src, const int* __restrict__ dst,
                                                 int* __restrict__ cursor, int* __restrict__ csr, int e) {
  int i = blockIdx.x * 256 + threadIdx.x;
  if (i < e) {
    int p = atomicAdd(&cursor[dst[i]], 1);
    csr[p] = src[i];
  }
}

// ------- weight convert: W[K][N] fp32 -> Wc[N][K] bf16 -------

__global__ __launch_bounds__(256) void wconv_k(const float* __restrict__ W1, const float* __restrict__ Wr,
                                               const float* __restrict__ W2, const float* __restrict__ W3,
                                               const float* __restrict__ W4,
                                               short* __restrict__ o1, short* __restrict__ oR,
                                               short* __restrict__ o2, short* __restrict__ o3,
                                               short* __restrict__ o4) {
  int b = blockIdx.x;  // 960 rows total
  const float* W; short* O; int K, N, nr;
  if (b < 64)       { W = W1; O = o1; K = 128; N = 64;  nr = b; }
  else if (b < 128) { W = Wr; O = oR; K = 128; N = 64;  nr = b - 64; }
  else if (b < 384) { W = W2; O = o2; K = 64;  N = 256; nr = b - 128; }
  else if (b < 896) { W = W3; O = o3; K = 256; N = 512; nr = b - 384; }
  else              { W = W4; O = o4; K = 512; N = 64;  nr = b - 896; }
  for (int k = threadIdx.x; k < K; k += 256)
    O[(size_t)nr * K + k] = (short)f2bf(W[(size_t)k * N + nr]);
}

// ------- MFMA GEMM (generic): C[M,NTOT] = A[M,KT] @ Wc[NTOT,KT](bf16) -------

template<int KT, int NTOT, int WM, int WN, int BIAS, int RELU, int ABF, int OBF, int SPLIT, int BLK>
__global__ __launch_bounds__(256, BLK) void mgemm(const void* __restrict__ Av,
                                                  const short* __restrict__ Wc,
                                                  const float* __restrict__ bias,
                                                  void* __restrict__ Cv, void* __restrict__ Cv2, int M) {
  __shared__ short As[64 * WM][ABF ? 40 : 72];
  __shared__ short Bs[64 * WN][40];
  const int tid = threadIdx.x;
  const int row0 = blockIdx.x * (64 * WM);
  const int col0 = blockIdx.y * (64 * WN);
  const int w = tid >> 6, lane = tid & 63;
  const int wm = w / WN, wn = w % WN;
  const int rm = wm * 64, cn = wn * 64;
  const int lm = lane & 15, lk = (lane >> 4) * 8;

  f32x4 acc[4][4];
#pragma unroll
  for (int i = 0; i < 4; i++)
#pragma unroll
    for (int j = 0; j < 4; j++)
#pragma unroll
      for (int r = 0; r < 4; r++) acc[i][j][r] = 0.f;

  for (int k0 = 0; k0 < KT; k0 += 32) {
#pragma unroll
    for (int p = 0; p < WM; p++) {
      int r = (tid >> 2) + p * 64;
      int kseg = (tid & 3) * 8;
      int gr = row0 + r;
      if (ABF) {
        bf16x8 v = {0, 0, 0, 0, 0, 0, 0, 0};
        if (gr < M) v = *(const bf16x8*)((const short*)Av + (size_t)gr * KT + k0 + kseg);
        *(bf16x8*)&As[r][kseg] = v;
      } else {
        float4 v0 = {0.f, 0.f, 0.f, 0.f}, v1 = {0.f, 0.f, 0.f, 0.f};
        if (gr < M) {
          const float* ap = (const float*)Av + (size_t)gr * KT + k0 + kseg;
          v0 = *(const float4*)ap;
          v1 = *(const float4*)(ap + 4);
        }
        float vv[8] = {v0.x, v0.y, v0.z, v0.w, v1.x, v1.y, v1.z, v1.w};
        bf16x8 hv, lv;
#pragma unroll
        for (int j = 0; j < 8; j++) {
          unsigned short h = f2bf(vv[j]);
          hv[j] = (short)h;
          lv[j] = (short)f2bf(vv[j] - bf2f(h));
        }
        *(bf16x8*)&As[r][kseg] = hv;
        *(bf16x8*)&As[r][32 + kseg] = lv;
      }
    }
#pragma unroll
    for (int p = 0; p < WN; p++) {
      int nr = (tid >> 2) + p * 64;
      int seg = (tid & 3) * 8;
      *(bf16x8*)&Bs[nr][seg] = *(const bf16x8*)(Wc + (size_t)(col0 + nr) * KT + k0 + seg);
    }
    __syncthreads();

    bf16x8 ah[4], al[4], bb[4];
#pragma unroll
    for (int mt = 0; mt < 4; mt++) {
      ah[mt] = *(const bf16x8*)&As[rm + mt * 16 + lm][lk];
      if (!ABF) al[mt] = *(const bf16x8*)&As[rm + mt * 16 + lm][32 + lk];
    }
#pragma unroll
    for (int nt = 0; nt < 4; nt++) bb[nt] = *(const bf16x8*)&Bs[cn + nt * 16 + lm][lk];
#pragma unroll
    for (int mt = 0; mt < 4; mt++)
#pragma unroll
      for (int nt = 0; nt < 4; nt++) {
        acc[mt][nt] = __builtin_amdgcn_mfma_f32_16x16x32_bf16(ah[mt], bb[nt], acc[mt][nt], 0, 0, 0);
        if (!ABF)
          acc[mt][nt] = __builtin_amdgcn_mfma_f32_16x16x32_bf16(al[mt], bb[nt], acc[mt][nt], 0, 0, 0);
      }
    __syncthreads();
  }

  if (SPLIT) {
    float* O = (wn == 0) ? (float*)Cv : (float*)Cv2;
#pragma unroll
    for (int mt = 0; mt < 4; mt++) {
      int grb = row0 + rm + mt * 16 + (lane >> 4) * 4;
#pragma unroll
      for (int nt = 0; nt < 4; nt++) {
        int gc = nt * 16 + lm;
        float bv = (wn == 1) ? bias[gc] : 0.f;
#pragma unroll
        for (int r = 0; r < 4; r++) {
          int gr = grb + r;
          if (gr < M) O[(size_t)gr * 64 + gc] = acc[mt][nt][r] + bv;
        }
      }
    }
  } else if (OBF && WM == 1) {
    short* epi = &Bs[0][0];
    const int NCOL = 64 * WN;
    float bvv[4];
#pragma unroll
    for (int nt = 0; nt < 4; nt++) bvv[nt] = BIAS ? bias[col0 + cn + nt * 16 + lm] : 0.f;
#pragma unroll
    for (int mt = 0; mt < 4; mt++) {
      __syncthreads();
#pragma unroll
      for (int nt = 0; nt < 4; nt++)
#pragma unroll
        for (int r = 0; r < 4; r++) {
          float v = acc[mt][nt][r] + bvv[nt];
          if (RELU) v = (v >= 0.f) ? v : 0.01f * v;
          epi[((lane >> 4) * 4 + r) * NCOL + cn + nt * 16 + lm] = (short)f2bf(v);
        }
      __syncthreads();
      const int per = (16 * NCOL) / 256;
      int base = tid * per;
      int lr = base / NCOL, lc = base % NCOL;
      int gr = row0 + mt * 16 + lr;
      if (gr < M) {
#pragma unroll
        for (int q = 0; q < per / 8; q++)
          *(bf16x8*)((short*)Cv + (size_t)gr * NTOT + col0 + lc + q * 8) = *(bf16x8*)&epi[base + q * 8];
      }
    }
  } else {
#pragma unroll
    for (int mt = 0; mt < 4; mt++) {
      int grb = row0 + rm + mt * 16 + (lane >> 4) * 4;
#pragma unroll
      for (int nt = 0; nt < 4; nt++) {
        int gc = col0 + cn + nt * 16 + lm;
        float bv = BIAS ? bias[gc] : 0.f;
#pragma unroll
        for (int r = 0; r < 4; r++) {
          int gr = grb + r;
          if (gr < M) {
            float v = acc[mt][nt][r] + bv;
            if (RELU) v = (v >= 0.f) ? v : 0.01f * v;
            if (OBF) ((short*)Cv)[(size_t)gr * NTOT + gc] = (short)f2bf(v);
            else     ((float*)Cv)[(size_t)gr * NTOT + gc] = v;
          }
        }
      }
    }
  }
}

// ------- fused layer3+layer4: t4 = leaky(z3 @ W3 + b3) @ W4, h3 never hits HBM -------
// R10 restructure: z3 A-fragments live in registers (loaded once, 32 VGPR);
// whole 64x256 W3 column-chunk staged in LDS per c (coalesced, conflict-free);
// 2 barriers per chunk, 40 MFMA per chunk.

__global__ __launch_bounds__(256, 3) void fused34_k(const short* __restrict__ z3,
                                                    const short* __restrict__ W3c,  // [512][256] bf16
                                                    const float* __restrict__ b3,
                                                    const short* __restrict__ W4c,  // [64][512] bf16
                                                    float* __restrict__ T4, int M) {
  __shared__ short Bs[64][264];  // W3 chunk: 64 n-rows x 256 k  (33 KB)
  __shared__ short Hs[64][72];   // h3 chunk in A-layout (wave-private rows)
  __shared__ short Ws4[64][72];  // W4 chunk: 64 n x 64 k
  const int tid = threadIdx.x;
  const int row0 = blockIdx.x * 64;
  const int w = tid >> 6, lane = tid & 63;
  const int lm = lane & 15, lk = (lane >> 4) * 8;
  const int rquad = (lane >> 4) * 4;
  const int srow = tid >> 2, sseg = (tid & 3) * 8;

  // A fragments for this wave's 16 rows, full K=256, in registers
  bf16x8 afr[8];
  {
    int gr = row0 + w * 16 + lm;
    bool ok = gr < M;
    const short* zp = z3 + (size_t)gr * 256 + lk;
#pragma unroll
    for (int kc = 0; kc < 8; kc++) {
      bf16x8 v = {0, 0, 0, 0, 0, 0, 0, 0};
      if (ok) v = *(const bf16x8*)(zp + kc * 32);
      afr[kc] = v;
    }
  }

  f32x4 t4acc[4];
#pragma unroll
  for (int nt = 0; nt < 4; nt++)
#pragma unroll
    for (int r = 0; r < 4; r++) t4acc[nt][r] = 0.f;

  for (int c = 0; c < 8; c++) {
    // stage W3 chunk-c (64 rows x 256 k) — fully coalesced: per q, 256 threads read 4 KB contiguous
#pragma unroll
    for (int q = 0; q < 8; q++) {
      int flat = q * 2048 + tid * 8;            // shorts
      int rr = flat >> 8, cc = flat & 255;
      *(bf16x8*)&Bs[rr][cc] = *(const bf16x8*)(W3c + (size_t)c * 64 * 256 + flat);
    }
    // stage W4 chunk (k-range c*64..c*64+63 for all 64 outputs)
    *(bf16x8*)&Ws4[srow][sseg]      = *(const bf16x8*)(W4c + (size_t)srow * 512 + c * 64 + sseg);
    *(bf16x8*)&Ws4[srow][32 + sseg] = *(const bf16x8*)(W4c + (size_t)srow * 512 + c * 64 + 32 + sseg);
    __syncthreads();

    // stage-1: h3 chunk = z3 @ W3_c  (8 K-steps, barrier-free)
    f32x4 acc1[4];
#pragma unroll
    for (int nt = 0; nt < 4; nt++)
#pragma unroll
      for (int r = 0; r < 4; r++) acc1[nt][r] = 0.f;
#pragma unroll
    for (int k0 = 0; k0 < 8; k0++) {
      bf16x8 bb[4];
#pragma unroll
      for (int nt = 0; nt < 4; nt++) bb[nt] = *(const bf16x8*)&Bs[nt * 16 + lm][k0 * 32 + lk];
#pragma unroll
      for (int nt = 0; nt < 4; nt++)
        acc1[nt] = __builtin_amdgcn_mfma_f32_16x16x32_bf16(afr[k0], bb[nt], acc1[nt], 0, 0, 0);
    }
    // bias + leaky -> bf16 -> Hs (C-layout -> A-layout; rows wave-private)
#pragma unroll
    for (int nt = 0; nt < 4; nt++) {
      float bv = b3[c * 64 + nt * 16 + lm];
#pragma unroll
      for (int r = 0; r < 4; r++) {
        float v = acc1[nt][r] + bv;
        v = (v >= 0.f) ? v : 0.01f * v;
        Hs[w * 16 + rquad + r][nt * 16 + lm] = (short)f2bf(v);
      }
    }
    // stage-2: t4 += h3_chunk @ W4_chunk (k=64 -> 2 sub-chunks)
#pragma unroll
    for (int kk = 0; kk < 64; kk += 32) {
      bf16x8 ah2 = *(const bf16x8*)&Hs[w * 16 + lm][kk + lk];
      bf16x8 bb2[4];
#pragma unroll
      for (int nt = 0; nt < 4; nt++) bb2[nt] = *(const bf16x8*)&Ws4[nt * 16 + lm][kk + lk];
#pragma unroll
      for (int nt = 0; nt < 4; nt++)
        t4acc[nt] = __builtin_amdgcn_mfma_f32_16x16x32_bf16(ah2, bb2[nt], t4acc[nt], 0, 0, 0);
    }
    __syncthreads();  // Bs/Ws4 reads done before next c overwrites
  }
  // epilogue: t4 fp32
#pragma unroll
  for (int nt = 0; nt < 4; nt++) {
    int gc = nt * 16 + lm;
#pragma unroll
    for (int r = 0; r < 4; r++) {
      int gr = row0 + w * 16 + rquad + r;
      if (gr < M) T4[(size_t)gr * 64 + gc] = t4acc[nt][r];
    }
  }
}

// ---------------- Aggregation (CSR gather), one wave per node ----------------

template<bool BR>
__global__ __launch_bounds__(256) void agg64_k(const float* __restrict__ T, const float* __restrict__ dis,
                                               const int* __restrict__ off, const int* __restrict__ csr,
                                               const float* __restrict__ bias, float* __restrict__ Out, int n) {
  int wid = (blockIdx.x * 256 + threadIdx.x) >> 6;
  int lane = threadIdx.x & 63;
  if (wid >= n) return;
  float di = dis[wid];
  int e0 = off[wid], e1 = off[wid + 1];
  float acc = 0.f;
  for (int e = e0; e < e1; e++) {
    int j = csr[e];
    acc = fmaf(dis[j], T[(size_t)j * 64 + lane], acc);
  }
  float v = di * acc + di * di * T[(size_t)wid * 64 + lane];
  if (BR) {
    v += bias[lane];
    v = (v >= 0.f) ? v : 0.01f * v;
  }
  Out[(size_t)wid * 64 + lane] = v;
}

// layer-4 tail fused: hn = LN( leaky(agg(t4)+b4) + resid )
__global__ __launch_bounds__(256) void agg64_ln_k(const float* __restrict__ T, const float* __restrict__ dis,
                                                  const int* __restrict__ off, const int* __restrict__ csr,
                                                  const float* __restrict__ bias, const float* __restrict__ resid,
                                                  const float* __restrict__ g, const float* __restrict__ b,
                                                  float* __restrict__ outh, int n) {
  int wid = (blockIdx.x * 256 + threadIdx.x) >> 6;
  int lane = threadIdx.x & 63;
  if (wid >= n) return;
  float di = dis[wid];
  int e0 = off[wid], e1 = off[wid + 1];
  float acc = 0.f;
  for (int e = e0; e < e1; e++) {
    int j = csr[e];
    acc = fmaf(dis[j], T[(size_t)j * 64 + lane], acc);
  }
  float v = di * acc + di * di * T[(size_t)wid * 64 + lane] + bias[lane];
  v = (v >= 0.f) ? v : 0.01f * v;
  v += resid[(size_t)wid * 64 + lane];
  float s = v, ss = v * v;
#pragma unroll
  for (int o = 32; o > 0; o >>= 1) {
    s += __shfl_xor(s, o);
    ss += __shfl_xor(ss, o);
  }
  float m = s * (1.f / 64.f);
  float var = ss * (1.f / 64.f) - m * m;
  float y = (v - m) * rsqrtf(var + 1e-5f) * g[lane] + b[lane];
  outh[(size_t)wid * 64 + lane] = y;
}

// bf16 in, bf16 out variant for the 256-dim layer
__global__ __launch_bounds__(256) void agg256b_k(const short* __restrict__ T, const float* __restrict__ dis,
                                                 const int* __restrict__ off, const int* __restrict__ csr,
                                                 short* __restrict__ Out, int n) {
  int wid = (blockIdx.x * 256 + threadIdx.x) >> 6;
  int lane = threadIdx.x & 63;
  if (wid >= n) return;
  float di = dis[wid];
  int e0 = off[wid], e1 = off[wid + 1];
  float a0 = 0.f, a1 = 0.f, a2 = 0.f, a3 = 0.f;
  for (int e = e0; e < e1; e++) {
    int j = csr[e];
    float dj = dis[j];
    bf16x4 t = *(const bf16x4*)&T[(size_t)j * 256 + lane * 4];
    a0 = fmaf(dj, bf2f((unsigned short)t[0]), a0);
    a1 = fmaf(dj, bf2f((unsigned short)t[1]), a1);
    a2 = fmaf(dj, bf2f((unsigned short)t[2]), a2);
    a3 = fmaf(dj, bf2f((unsigned short)t[3]), a3);
  }
  bf16x4 s = *(const bf16x4*)&T[(size_t)wid * 256 + lane * 4];
  float dii = di * di;
  bf16x4 o;
  o[0] = (short)f2bf(di * a0 + dii * bf2f((unsigned short)s[0]));
  o[1] = (short)f2bf(di * a1 + dii * bf2f((unsigned short)s[1]));
  o[2] = (short)f2bf(di * a2 + dii * bf2f((unsigned short)s[2]));
  o[3] = (short)f2bf(di * a3 + dii * bf2f((unsigned short)s[3]));
  *(bf16x4*)&Out[(size_t)wid * 256 + lane * 4] = o;
}

// ---------------- per-graph max pool ----------------

__global__ __launch_bounds__(256) void pool_k(const float* __restrict__ hn, float* __restrict__ p, int n) {
  const int G = 64;
  int g = blockIdx.x;
  int f = threadIdx.x & 63, c = threadIdx.x >> 6;
  long long s = ((long long)g * n + G - 1) / G;
  long long e = ((long long)(g + 1) * n + G - 1) / G;
  float m = -INFINITY;
  for (long long i = s + c; i < e; i += 4) m = fmaxf(m, hn[(size_t)i * 64 + f]);
  __shared__ float red[4][64];
  red[c][f] = m;
  __syncthreads();
  if (c == 0) {
    m = fmaxf(fmaxf(red[0][f], red[1][f]), fmaxf(red[2][f], red[3][f]));
    p[g * 64 + f] = m;
  }
}

// ---------------- final MLP ----------------

__global__ __launch_bounds__(64) void mlp_k(const float* __restrict__ p, const float* __restrict__ fc1W,
                                            const float* __restrict__ fc1b, const float* __restrict__ fng,
                                            const float* __restrict__ fnb, const float* __restrict__ fc2W,
                                            const float* __restrict__ fc2b, float* __restrict__ out) {
  int g = blockIdx.x;
  int lane = threadIdx.x;
  __shared__ float ps[64], qs[64];
  ps[lane] = p[g * 64 + lane];
  __syncthreads();
  float q = fc1b[lane];
#pragma unroll 8
  for (int k = 0; k < 64; k++) q = fmaf(ps[k], fc1W[k * 64 + lane], q);
  float s = q, ss = q * q;
#pragma unroll
  for (int o = 32; o > 0; o >>= 1) {
    s += __shfl_xor(s, o);
    ss += __shfl_xor(ss, o);
  }
  float m = s * (1.f / 64.f);
  float var = ss * (1.f / 64.f) - m * m;
  float y = (q - m) * rsqrtf(var + 1e-5f) * fng[lane] + fnb[lane];
  y = (y >= 0.f) ? y : 0.01f * y;
  qs[lane] = y;
  __syncthreads();
  if (lane < 16) {
    float o = fc2b[lane];
#pragma unroll 8
    for (int k = 0; k < 64; k++) o = fmaf(qs[k], fc2W[k * 16 + lane], o);
    out[g * 16 + lane] = o;
  }
}

// ---------------- launch ----------------

extern "C" void kernel_launch(void* const* d_in, const int* in_sizes, int n_in,
                              void* d_out, int out_size, void* d_ws, size_t ws_size,
                              hipStream_t stream) {
  const float* x   = (const float*)d_in[0];
  const int*   ei  = (const int*)d_in[1];
  const float* W1  = (const float*)d_in[3];
  const float* b1  = (const float*)d_in[4];
  const float* W2  = (const float*)d_in[5];
  const float* b2  = (const float*)d_in[6];
  const float* W3  = (const float*)d_in[7];
  const float* b3  = (const float*)d_in[8];
  const float* W4  = (const float*)d_in[9];
  const float* b4  = (const float*)d_in[10];
  const float* Wr  = (const float*)d_in[11];
  const float* br  = (const float*)d_in[12];
  const float* lng = (const float*)d_in[13];
  const float* lnb = (const float*)d_in[14];
  const float* f1W = (const float*)d_in[15];
  const float* f1b = (const float*)d_in[16];
  const float* fng = (const float*)d_in[17];
  const float* fnb = (const float*)d_in[18];
  const float* f2W = (const float*)d_in[19];
  const float* f2b = (const float*)d_in[20];

  int n = in_sizes[0] / 128;   // 50000
  int e = in_sizes[1] / 2;     // 400000
  const int* src = ei;
  const int* dst = ei + e;

  // Arena (float units; bf16 buffers count n*dim/2):
  //   resid [0,64n)      live: fused L1 -> agg64_ln
  //   h2b   [64n,192n)   bf16 n x 256; live L2 -> agg256b
  //   t4    [64n,128n)   live fused34 -> agg64_ln   (h2b dead)
  //   z3b   [192n,320n)  bf16 n x 256; live agg256b -> fused34
  //   hn    [192n,256n)  live agg64_ln -> pool      (z3b dead)
  //   z2    [256n,320n)  live agg64(2) -> L2
  //   h1    [320n,384n)  t1 [384n,448n)
  //   meta from 448n
  float* arena = (float*)d_ws;
  float* resid = arena;
  short* h2b   = (short*)(arena + (size_t)64 * n);
  float* t4    = arena + (size_t)64 * n;
  short* z3b   = (short*)(arena + (size_t)192 * n);
  float* hn    = arena + (size_t)192 * n;
  float* z2    = arena + (size_t)256 * n;
  float* h1    = arena + (size_t)320 * n;
  float* t1    = arena + (size_t)384 * n;
  float* dis   = arena + (size_t)448 * n;  // n
  int* cnt    = (int*)(dis + n);           // n
  int* off    = cnt + n;                   // n+1
  int* cursor = off + n + 1;               // n
  int* csr    = cursor + n;                // e
  int* bsum   = csr + e;                   // 256
  int* bpre   = bsum + 256;                // 256
  float* pool = (float*)(bpre + 256);      // 64*64
  size_t wq = (((size_t)(pool + 4096)) + 15) & ~(size_t)15;
  short* wc1 = (short*)wq;                 // 64 x 128   (wc1||wcR = fused 128 x 128)
  short* wcR = wc1 + 8192;                 // 64 x 128
  short* wc2 = wcR + 8192;                 // 256 x 64
  short* wc3 = wc2 + 16384;                // 512 x 256
  short* wc4 = wc3 + 131072;               // 64 x 512
  size_t need = ((char*)(wc4 + 32768) - (char*)d_ws) + 64;
  if (ws_size < need) return;

  int nb_n = (n + 255) / 256;     // 196
  int nb_e = (e + 255) / 256;
  int nb_w = (n + 3) / 4;         // one wave per node
  int g_wide = (n + 63) / 64;     // 782
  int g_fused = (n + 127) / 128;  // 391

  // weights -> bf16 [N][K]
  wconv_k<<<960, 256, 0, stream>>>(W1, Wr, W2, W3, W4, wc1, wcR, wc2, wc3, wc4);

  // degree + CSR (hierarchical scan)
  zero_i32<<<nb_n, 256, 0, stream>>>(cnt, n);
  count_k<<<nb_e, 256, 0, stream>>>(dst, cnt, e);
  dis_k<<<nb_n, 256, 0, stream>>>(cnt, dis, n);
  scan_a<<<nb_n, 256, 0, stream>>>(cnt, bsum, n);
  scan_b<<<1, 256, 0, stream>>>(bsum, bpre, off + n, nb_n);
  scan_c<<<nb_n, 256, 0, stream>>>(cnt, bpre, off, cursor, n);
  scatter_k<<<nb_e, 256, 0, stream>>>(src, dst, cursor, csr, e);

  // fused layer-1 transform + residual: [t1 | resid] = x @ [W1 | Wr] (+br on resid half)
  mgemm<128, 128, 2, 2, 1, 0, 0, 0, 1, 4><<<dim3(g_fused, 1), 256, 0, stream>>>(x, wc1, br, t1, resid, n);
  agg64_k<true><<<nb_w, 256, 0, stream>>>(t1, dis, off, csr, b1, h1, n);
  // layer 2: aggregate-first; h2 stored bf16 (coalesced staged epilogue)
  agg64_k<false><<<nb_w, 256, 0, stream>>>(h1, dis, off, csr, nullptr, z2, n);
  mgemm<64, 256, 1, 4, 1, 1, 0, 1, 0, 5><<<dim3(g_wide, 1), 256, 0, stream>>>(z2, wc2, b2, h2b, nullptr, n);
  // layer 3 aggregate, then fused L3-GEMM + L4-GEMM (h3 stays on-chip)
  agg256b_k<<<nb_w, 256, 0, stream>>>(h2b, dis, off, csr, z3b, n);
  fused34_k<<<g_wide, 256, 0, stream>>>(z3b, wc3, b3, wc4, t4, n);
  // layer-4 aggregation fused with residual + LN
  agg64_ln_k<<<nb_w, 256, 0, stream>>>(t4, dis, off, csr, b4, resid, lng, lnb, hn, n);
  // pool + MLP
  pool_k<<<64, 256, 0, stream>>>(hn, pool, n);
  mlp_k<<<64, 64, 0, stream>>>(pool, f1W, f1b, fng, fnb, f2W, f2b, (float*)d_out);
}

// Round 11
// 397.675 us; speedup vs baseline: 1.4167x; 1.1770x over previous
//
#include <hip/hip_runtime.h>
#include <hip/hip_bf16.h>
#include <math.h>

typedef short bf16x8 __attribute__((ext_vector_type(8)));
typedef short bf16x4 __attribute__((ext_vector_type(4)));
typedef float f32x4 __attribute__((ext_vector_type(4)));

__device__ inline unsigned short f2bf(float f) {
  unsigned u = __float_as_uint(f);
  u += 0x7FFF + ((u >> 16) & 1);           // RNE
  return (unsigned short)(u >> 16);
}
__device__ inline float bf2f(unsigned short h) {
  return __uint_as_float(((unsigned)h) << 16);
}

// ---------------- CSR build ----------------

__global__ __launch_bounds__(256) void zero_i32(int* __restrict__ p, int n) {
  int i = blockIdx.x * 256 + threadIdx.x;
  if (i < n) p[i] = 0;
}

__global__ __launch_bounds__(256) void count_k(const int* __restrict__ dst, int* __restrict__ cnt, int e) {
  int i = blockIdx.x * 256 + threadIdx.x;
  if (i < e) atomicAdd(&cnt[dst[i]], 1);
}

__global__ __launch_bounds__(256) void dis_k(const int* __restrict__ cnt, float* __restrict__ dis, int n) {
  int i = blockIdx.x * 256 + threadIdx.x;
  if (i < n) dis[i] = rsqrtf((float)cnt[i] + 1.0f);
}

// hierarchical scan
__global__ __launch_bounds__(256) void scan_a(const int* __restrict__ cnt, int* __restrict__ bsum, int n) {
  int i = blockIdx.x * 256 + threadIdx.x;
  int v = (i < n) ? cnt[i] : 0;
#pragma unroll
  for (int o = 32; o > 0; o >>= 1) v += __shfl_xor(v, o);
  __shared__ int ws[4];
  if ((threadIdx.x & 63) == 0) ws[threadIdx.x >> 6] = v;
  __syncthreads();
  if (threadIdx.x == 0) bsum[blockIdx.x] = ws[0] + ws[1] + ws[2] + ws[3];
}

__global__ __launch_bounds__(256) void scan_b(const int* __restrict__ bsum, int* __restrict__ bpre,
                                              int* __restrict__ off_n, int nb) {
  __shared__ int s[256];
  int t = threadIdx.x;
  int v = (t < nb) ? bsum[t] : 0;
  s[t] = v;
  __syncthreads();
  for (int o = 1; o < 256; o <<= 1) {
    int u = (t >= o) ? s[t - o] : 0;
    __syncthreads();
    s[t] += u;
    __syncthreads();
  }
  if (t < nb) bpre[t] = s[t] - v;
  if (t == 255) off_n[0] = s[255];
}

__global__ __launch_bounds__(256) void scan_c(const int* __restrict__ cnt, const int* __restrict__ bpre,
                                              int* __restrict__ off, int* __restrict__ cursor, int n) {
  __shared__ int s[256];
  int i = blockIdx.x * 256 + threadIdx.x;
  int t = threadIdx.x;
  int v = (i < n) ? cnt[i] : 0;
  s[t] = v;
  __syncthreads();
  for (int o = 1; o < 256; o <<= 1) {
    int u = (t >= o) ? s[t - o] : 0;
    __syncthreads();
    s[t] += u;
    __syncthreads();
  }
  if (i < n) {
    int ov = bpre[blockIdx.x] + s[t] - v;
    off[i] = ov;
    cursor[i] = ov;
  }
}

__global__ __launch_bounds__(256) void scatter_k(const int* __restrict__ src, const int* __restrict__ dst,
                                                 int* __restrict__ cursor, int* __restrict__ csr, int e) {
  int i = blockIdx.x * 256 + threadIdx.x;
  if (i < e) {
    int p = atomicAdd(&cursor[dst[i]], 1);
    csr[p] = src[i];
  }
}

// ------- weight convert: W[K][N] fp32 -> Wc[N][K] bf16 -------

__global__ __launch_bounds__(256) void wconv_k(const float* __restrict__ W1, const float* __restrict__ Wr,
                                               const float* __restrict__ W2, const float* __restrict__ W3,
                                               const float* __restrict__ W4,
                                               short* __restrict__ o1, short* __restrict__ oR,
                                               short* __restrict__ o2, short* __restrict__ o3,
                                               short* __restrict__ o4) {
  int b = blockIdx.x;  // 960 rows total
  const float* W; short* O; int K, N, nr;
  if (b < 64)       { W = W1; O = o1; K = 128; N = 64;  nr = b; }
  else if (b < 128) { W = Wr; O = oR; K = 128; N = 64;  nr = b - 64; }
  else if (b < 384) { W = W2; O = o2; K = 64;  N = 256; nr = b - 128; }
  else if (b < 896) { W = W3; O = o3; K = 256; N = 512; nr = b - 384; }
  else              { W = W4; O = o4; K = 512; N = 64;  nr = b - 896; }
  for (int k = threadIdx.x; k < K; k += 256)
    O[(size_t)nr * K + k] = (short)f2bf(W[(size_t)k * N + nr]);
}

// ------- MFMA GEMM (generic): C[M,NTOT] = A[M,KT] @ Wc[NTOT,KT](bf16) -------
// SCL: multiply output rows by scl[row] (pre-scaling for the dis-free aggregation).

template<int KT, int NTOT, int WM, int WN, int BIAS, int RELU, int ABF, int OBF, int SPLIT, int SCL, int BLK>
__global__ __launch_bounds__(256, BLK) void mgemm(const void* __restrict__ Av,
                                                  const short* __restrict__ Wc,
                                                  const float* __restrict__ bias,
                                                  void* __restrict__ Cv, void* __restrict__ Cv2,
                                                  const float* __restrict__ scl, int M) {
  __shared__ short As[64 * WM][ABF ? 40 : 72];
  __shared__ short Bs[64 * WN][40];
  const int tid = threadIdx.x;
  const int row0 = blockIdx.x * (64 * WM);
  const int col0 = blockIdx.y * (64 * WN);
  const int w = tid >> 6, lane = tid & 63;
  const int wm = w / WN, wn = w % WN;
  const int rm = wm * 64, cn = wn * 64;
  const int lm = lane & 15, lk = (lane >> 4) * 8;

  f32x4 acc[4][4];
#pragma unroll
  for (int i = 0; i < 4; i++)
#pragma unroll
    for (int j = 0; j < 4; j++)
#pragma unroll
      for (int r = 0; r < 4; r++) acc[i][j][r] = 0.f;

  for (int k0 = 0; k0 < KT; k0 += 32) {
#pragma unroll
    for (int p = 0; p < WM; p++) {
      int r = (tid >> 2) + p * 64;
      int kseg = (tid & 3) * 8;
      int gr = row0 + r;
      if (ABF) {
        bf16x8 v = {0, 0, 0, 0, 0, 0, 0, 0};
        if (gr < M) v = *(const bf16x8*)((const short*)Av + (size_t)gr * KT + k0 + kseg);
        *(bf16x8*)&As[r][kseg] = v;
      } else {
        float4 v0 = {0.f, 0.f, 0.f, 0.f}, v1 = {0.f, 0.f, 0.f, 0.f};
        if (gr < M) {
          const float* ap = (const float*)Av + (size_t)gr * KT + k0 + kseg;
          v0 = *(const float4*)ap;
          v1 = *(const float4*)(ap + 4);
        }
        float vv[8] = {v0.x, v0.y, v0.z, v0.w, v1.x, v1.y, v1.z, v1.w};
        bf16x8 hv, lv;
#pragma unroll
        for (int j = 0; j < 8; j++) {
          unsigned short h = f2bf(vv[j]);
          hv[j] = (short)h;
          lv[j] = (short)f2bf(vv[j] - bf2f(h));
        }
        *(bf16x8*)&As[r][kseg] = hv;
        *(bf16x8*)&As[r][32 + kseg] = lv;
      }
    }
#pragma unroll
    for (int p = 0; p < WN; p++) {
      int nr = (tid >> 2) + p * 64;
      int seg = (tid & 3) * 8;
      *(bf16x8*)&Bs[nr][seg] = *(const bf16x8*)(Wc + (size_t)(col0 + nr) * KT + k0 + seg);
    }
    __syncthreads();

    bf16x8 ah[4], al[4], bb[4];
#pragma unroll
    for (int mt = 0; mt < 4; mt++) {
      ah[mt] = *(const bf16x8*)&As[rm + mt * 16 + lm][lk];
      if (!ABF) al[mt] = *(const bf16x8*)&As[rm + mt * 16 + lm][32 + lk];
    }
#pragma unroll
    for (int nt = 0; nt < 4; nt++) bb[nt] = *(const bf16x8*)&Bs[cn + nt * 16 + lm][lk];
#pragma unroll
    for (int mt = 0; mt < 4; mt++)
#pragma unroll
      for (int nt = 0; nt < 4; nt++) {
        acc[mt][nt] = __builtin_amdgcn_mfma_f32_16x16x32_bf16(ah[mt], bb[nt], acc[mt][nt], 0, 0, 0);
        if (!ABF)
          acc[mt][nt] = __builtin_amdgcn_mfma_f32_16x16x32_bf16(al[mt], bb[nt], acc[mt][nt], 0, 0, 0);
      }
    __syncthreads();
  }

  if (SPLIT) {
    float* O = (wn == 0) ? (float*)Cv : (float*)Cv2;
#pragma unroll
    for (int mt = 0; mt < 4; mt++) {
      int grb = row0 + rm + mt * 16 + (lane >> 4) * 4;
#pragma unroll
      for (int nt = 0; nt < 4; nt++) {
        int gc = nt * 16 + lm;
        float bv = (wn == 1) ? bias[gc] : 0.f;
#pragma unroll
        for (int r = 0; r < 4; r++) {
          int gr = grb + r;
          if (gr < M) {
            float v = acc[mt][nt][r];
            if (wn == 0 && SCL) v *= scl[gr];   // t1 half pre-scaled by dis
            else v += bv;
            O[(size_t)gr * 64 + gc] = v;
          }
        }
      }
    }
  } else if (OBF && WM == 1) {
    short* epi = &Bs[0][0];
    const int NCOL = 64 * WN;
    float bvv[4];
#pragma unroll
    for (int nt = 0; nt < 4; nt++) bvv[nt] = BIAS ? bias[col0 + cn + nt * 16 + lm] : 0.f;
#pragma unroll
    for (int mt = 0; mt < 4; mt++) {
      __syncthreads();
#pragma unroll
      for (int r = 0; r < 4; r++) {
        int gr = row0 + mt * 16 + (lane >> 4) * 4 + r;
        float sc = (SCL && gr < M) ? scl[gr] : 1.f;
#pragma unroll
        for (int nt = 0; nt < 4; nt++) {
          float v = acc[mt][nt][r] + bvv[nt];
          if (RELU) v = (v >= 0.f) ? v : 0.01f * v;
          if (SCL) v *= sc;
          epi[((lane >> 4) * 4 + r) * NCOL + cn + nt * 16 + lm] = (short)f2bf(v);
        }
      }
      __syncthreads();
      const int per = (16 * NCOL) / 256;
      int base = tid * per;
      int lr = base / NCOL, lc = base % NCOL;
      int gr = row0 + mt * 16 + lr;
      if (gr < M) {
#pragma unroll
        for (int q = 0; q < per / 8; q++)
          *(bf16x8*)((short*)Cv + (size_t)gr * NTOT + col0 + lc + q * 8) = *(bf16x8*)&epi[base + q * 8];
      }
    }
  } else {
#pragma unroll
    for (int mt = 0; mt < 4; mt++) {
      int grb = row0 + rm + mt * 16 + (lane >> 4) * 4;
#pragma unroll
      for (int nt = 0; nt < 4; nt++) {
        int gc = col0 + cn + nt * 16 + lm;
        float bv = BIAS ? bias[gc] : 0.f;
#pragma unroll
        for (int r = 0; r < 4; r++) {
          int gr = grb + r;
          if (gr < M) {
            float v = acc[mt][nt][r] + bv;
            if (RELU) v = (v >= 0.f) ? v : 0.01f * v;
            if (SCL) v *= scl[gr];
            if (OBF) ((short*)Cv)[(size_t)gr * NTOT + gc] = (short)f2bf(v);
            else     ((float*)Cv)[(size_t)gr * NTOT + gc] = v;
          }
        }
      }
    }
  }
}

// ------- fused layer3+layer4: t4 = dis * (leaky(z3 @ W3 + b3) @ W4) -------

__global__ __launch_bounds__(256, 3) void fused34_k(const short* __restrict__ z3,
                                                    const short* __restrict__ W3c,  // [512][256] bf16
                                                    const float* __restrict__ b3,
                                                    const short* __restrict__ W4c,  // [64][512] bf16
                                                    const float* __restrict__ dis,
                                                    float* __restrict__ T4, int M) {
  __shared__ short Bs[64][264];  // W3 chunk: 64 n-rows x 256 k
  __shared__ short Hs[64][72];   // h3 chunk in A-layout
  __shared__ short Ws4[64][72];  // W4 chunk
  const int tid = threadIdx.x;
  const int row0 = blockIdx.x * 64;
  const int w = tid >> 6, lane = tid & 63;
  const int lm = lane & 15, lk = (lane >> 4) * 8;
  const int rquad = (lane >> 4) * 4;
  const int srow = tid >> 2, sseg = (tid & 3) * 8;

  bf16x8 afr[8];
  {
    int gr = row0 + w * 16 + lm;
    bool ok = gr < M;
    const short* zp = z3 + (size_t)gr * 256 + lk;
#pragma unroll
    for (int kc = 0; kc < 8; kc++) {
      bf16x8 v = {0, 0, 0, 0, 0, 0, 0, 0};
      if (ok) v = *(const bf16x8*)(zp + kc * 32);
      afr[kc] = v;
    }
  }

  f32x4 t4acc[4];
#pragma unroll
  for (int nt = 0; nt < 4; nt++)
#pragma unroll
    for (int r = 0; r < 4; r++) t4acc[nt][r] = 0.f;

  for (int c = 0; c < 8; c++) {
#pragma unroll
    for (int q = 0; q < 8; q++) {
      int flat = q * 2048 + tid * 8;
      int rr = flat >> 8, cc = flat & 255;
      *(bf16x8*)&Bs[rr][cc] = *(const bf16x8*)(W3c + (size_t)c * 64 * 256 + flat);
    }
    *(bf16x8*)&Ws4[srow][sseg]      = *(const bf16x8*)(W4c + (size_t)srow * 512 + c * 64 + sseg);
    *(bf16x8*)&Ws4[srow][32 + sseg] = *(const bf16x8*)(W4c + (size_t)srow * 512 + c * 64 + 32 + sseg);
    __syncthreads();

    f32x4 acc1[4];
#pragma unroll
    for (int nt = 0; nt < 4; nt++)
#pragma unroll
      for (int r = 0; r < 4; r++) acc1[nt][r] = 0.f;
#pragma unroll
    for (int k0 = 0; k0 < 8; k0++) {
      bf16x8 bb[4];
#pragma unroll
      for (int nt = 0; nt < 4; nt++) bb[nt] = *(const bf16x8*)&Bs[nt * 16 + lm][k0 * 32 + lk];
#pragma unroll
      for (int nt = 0; nt < 4; nt++)
        acc1[nt] = __builtin_amdgcn_mfma_f32_16x16x32_bf16(afr[k0], bb[nt], acc1[nt], 0, 0, 0);
    }
#pragma unroll
    for (int nt = 0; nt < 4; nt++) {
      float bv = b3[c * 64 + nt * 16 + lm];
#pragma unroll
      for (int r = 0; r < 4; r++) {
        float v = acc1[nt][r] + bv;
        v = (v >= 0.f) ? v : 0.01f * v;
        Hs[w * 16 + rquad + r][nt * 16 + lm] = (short)f2bf(v);
      }
    }
#pragma unroll
    for (int kk = 0; kk < 64; kk += 32) {
      bf16x8 ah2 = *(const bf16x8*)&Hs[w * 16 + lm][kk + lk];
      bf16x8 bb2[4];
#pragma unroll
      for (int nt = 0; nt < 4; nt++) bb2[nt] = *(const bf16x8*)&Ws4[nt * 16 + lm][kk + lk];
#pragma unroll
      for (int nt = 0; nt < 4; nt++)
        t4acc[nt] = __builtin_amdgcn_mfma_f32_16x16x32_bf16(ah2, bb2[nt], t4acc[nt], 0, 0, 0);
    }
    __syncthreads();
  }
  // epilogue: t4 fp32, pre-scaled by dis[row]
#pragma unroll
  for (int r = 0; r < 4; r++) {
    int gr = row0 + w * 16 + rquad + r;
    float sc = (gr < M) ? dis[gr] : 0.f;
#pragma unroll
    for (int nt = 0; nt < 4; nt++) {
      int gc = nt * 16 + lm;
      if (gr < M) T4[(size_t)gr * 64 + gc] = t4acc[nt][r] * sc;
    }
  }
}

// ---------------- Aggregation (dis-free gather; rows pre-scaled by dis) ----------------
// out = di * (sum_j T[j] + T[i]); BR: +bias, leaky; OSCL: *di again (pre-scale own output)

template<int BR, int OSCL>
__global__ __launch_bounds__(256) void agg64_k(const float* __restrict__ T, const float* __restrict__ dis,
                                               const int* __restrict__ off, const int* __restrict__ csr,
                                               const float* __restrict__ bias, float* __restrict__ Out, int n) {
  int wid = (blockIdx.x * 256 + threadIdx.x) >> 6;
  int lane = threadIdx.x & 63;
  if (wid >= n) return;
  float di = dis[wid];
  int e0 = off[wid], e1 = off[wid + 1];
  float acc = T[(size_t)wid * 64 + lane];
  int e = e0;
  for (; e + 4 <= e1; e += 4) {
    int j0 = csr[e], j1 = csr[e + 1], j2 = csr[e + 2], j3 = csr[e + 3];
    float v0 = T[(size_t)j0 * 64 + lane];
    float v1 = T[(size_t)j1 * 64 + lane];
    float v2 = T[(size_t)j2 * 64 + lane];
    float v3 = T[(size_t)j3 * 64 + lane];
    acc += (v0 + v1) + (v2 + v3);
  }
  for (; e < e1; e++) acc += T[(size_t)csr[e] * 64 + lane];
  float v = di * acc;
  if (BR) {
    v += bias[lane];
    v = (v >= 0.f) ? v : 0.01f * v;
  }
  if (OSCL) v *= di;
  Out[(size_t)wid * 64 + lane] = v;
}

// layer-4 tail fused: hn = LN( leaky(di*sum + b4) + resid )
__global__ __launch_bounds__(256) void agg64_ln_k(const float* __restrict__ T, const float* __restrict__ dis,
                                                  const int* __restrict__ off, const int* __restrict__ csr,
                                                  const float* __restrict__ bias, const float* __restrict__ resid,
                                                  const float* __restrict__ g, const float* __restrict__ b,
                                                  float* __restrict__ outh, int n) {
  int wid = (blockIdx.x * 256 + threadIdx.x) >> 6;
  int lane = threadIdx.x & 63;
  if (wid >= n) return;
  float di = dis[wid];
  int e0 = off[wid], e1 = off[wid + 1];
  float acc = T[(size_t)wid * 64 + lane];
  int e = e0;
  for (; e + 4 <= e1; e += 4) {
    int j0 = csr[e], j1 = csr[e + 1], j2 = csr[e + 2], j3 = csr[e + 3];
    float v0 = T[(size_t)j0 * 64 + lane];
    float v1 = T[(size_t)j1 * 64 + lane];
    float v2 = T[(size_t)j2 * 64 + lane];
    float v3 = T[(size_t)j3 * 64 + lane];
    acc += (v0 + v1) + (v2 + v3);
  }
  for (; e < e1; e++) acc += T[(size_t)csr[e] * 64 + lane];
  float v = di * acc + bias[lane];
  v = (v >= 0.f) ? v : 0.01f * v;
  v += resid[(size_t)wid * 64 + lane];
  float s = v, ss = v * v;
#pragma unroll
  for (int o = 32; o > 0; o >>= 1) {
    s += __shfl_xor(s, o);
    ss += __shfl_xor(ss, o);
  }
  float m = s * (1.f / 64.f);
  float var = ss * (1.f / 64.f) - m * m;
  float y = (v - m) * rsqrtf(var + 1e-5f) * g[lane] + b[lane];
  outh[(size_t)wid * 64 + lane] = y;
}

// bf16 gather for the 256-dim layer (rows pre-scaled): z3 = di*(sum + self)
__global__ __launch_bounds__(256) void agg256b_k(const short* __restrict__ T, const float* __restrict__ dis,
                                                 const int* __restrict__ off, const int* __restrict__ csr,
                                                 short* __restrict__ Out, int n) {
  int wid = (blockIdx.x * 256 + threadIdx.x) >> 6;
  int lane = threadIdx.x & 63;
  if (wid >= n) return;
  float di = dis[wid];
  int e0 = off[wid], e1 = off[wid + 1];
  bf16x4 sf = *(const bf16x4*)&T[(size_t)wid * 256 + lane * 4];
  float a0 = bf2f((unsigned short)sf[0]);
  float a1 = bf2f((unsigned short)sf[1]);
  float a2 = bf2f((unsigned short)sf[2]);
  float a3 = bf2f((unsigned short)sf[3]);
  int e = e0;
  for (; e + 4 <= e1; e += 4) {
    int j0 = csr[e], j1 = csr[e + 1], j2 = csr[e + 2], j3 = csr[e + 3];
    bf16x4 t0 = *(const bf16x4*)&T[(size_t)j0 * 256 + lane * 4];
    bf16x4 t1 = *(const bf16x4*)&T[(size_t)j1 * 256 + lane * 4];
    bf16x4 t2 = *(const bf16x4*)&T[(size_t)j2 * 256 + lane * 4];
    bf16x4 t3 = *(const bf16x4*)&T[(size_t)j3 * 256 + lane * 4];
    a0 += (bf2f((unsigned short)t0[0]) + bf2f((unsigned short)t1[0])) +
          (bf2f((unsigned short)t2[0]) + bf2f((unsigned short)t3[0]));
    a1 += (bf2f((unsigned short)t0[1]) + bf2f((unsigned short)t1[1])) +
          (bf2f((unsigned short)t2[1]) + bf2f((unsigned short)t3[1]));
    a2 += (bf2f((unsigned short)t0[2]) + bf2f((unsigned short)t1[2])) +
          (bf2f((unsigned short)t2[2]) + bf2f((unsigned short)t3[2]));
    a3 += (bf2f((unsigned short)t0[3]) + bf2f((unsigned short)t1[3])) +
          (bf2f((unsigned short)t2[3]) + bf2f((unsigned short)t3[3]));
  }
  for (; e < e1; e++) {
    bf16x4 t = *(const bf16x4*)&T[(size_t)csr[e] * 256 + lane * 4];
    a0 += bf2f((unsigned short)t[0]);
    a1 += bf2f((unsigned short)t[1]);
    a2 += bf2f((unsigned short)t[2]);
    a3 += bf2f((unsigned short)t[3]);
  }
  bf16x4 o;
  o[0] = (short)f2bf(di * a0);
  o[1] = (short)f2bf(di * a1);
  o[2] = (short)f2bf(di * a2);
  o[3] = (short)f2bf(di * a3);
  *(bf16x4*)&Out[(size_t)wid * 256 + lane * 4] = o;
}

// ---------------- per-graph max pool ----------------

__global__ __launch_bounds__(256) void pool_k(const float* __restrict__ hn, float* __restrict__ p, int n) {
  const int G = 64;
  int g = blockIdx.x;
  int f = threadIdx.x & 63, c = threadIdx.x >> 6;
  long long s = ((long long)g * n + G - 1) / G;
  long long e = ((long long)(g + 1) * n + G - 1) / G;
  float m = -INFINITY;
  for (long long i = s + c; i < e; i += 4) m = fmaxf(m, hn[(size_t)i * 64 + f]);
  __shared__ float red[4][64];
  red[c][f] = m;
  __syncthreads();
  if (c == 0) {
    m = fmaxf(fmaxf(red[0][f], red[1][f]), fmaxf(red[2][f], red[3][f]));
    p[g * 64 + f] = m;
  }
}

// ---------------- final MLP ----------------

__global__ __launch_bounds__(64) void mlp_k(const float* __restrict__ p, const float* __restrict__ fc1W,
                                            const float* __restrict__ fc1b, const float* __restrict__ fng,
                                            const float* __restrict__ fnb, const float* __restrict__ fc2W,
                                            const float* __restrict__ fc2b, float* __restrict__ out) {
  int g = blockIdx.x;
  int lane = threadIdx.x;
  __shared__ float ps[64], qs[64];
  ps[lane] = p[g * 64 + lane];
  __syncthreads();
  float q = fc1b[lane];
#pragma unroll 8
  for (int k = 0; k < 64; k++) q = fmaf(ps[k], fc1W[k * 64 + lane], q);
  float s = q, ss = q * q;
#pragma unroll
  for (int o = 32; o > 0; o >>= 1) {
    s += __shfl_xor(s, o);
    ss += __shfl_xor(ss, o);
  }
  float m = s * (1.f / 64.f);
  float var = ss * (1.f / 64.f) - m * m;
  float y = (q - m) * rsqrtf(var + 1e-5f) * fng[lane] + fnb[lane];
  y = (y >= 0.f) ? y : 0.01f * y;
  qs[lane] = y;
  __syncthreads();
  if (lane < 16) {
    float o = fc2b[lane];
#pragma unroll 8
    for (int k = 0; k < 64; k++) o = fmaf(qs[k], fc2W[k * 16 + lane], o);
    out[g * 16 + lane] = o;
  }
}

// ---------------- launch ----------------

extern "C" void kernel_launch(void* const* d_in, const int* in_sizes, int n_in,
                              void* d_out, int out_size, void* d_ws, size_t ws_size,
                              hipStream_t stream) {
  const float* x   = (const float*)d_in[0];
  const int*   ei  = (const int*)d_in[1];
  const float* W1  = (const float*)d_in[3];
  const float* b1  = (const float*)d_in[4];
  const float* W2  = (const float*)d_in[5];
  const float* b2  = (const float*)d_in[6];
  const float* W3  = (const float*)d_in[7];
  const float* b3  = (const float*)d_in[8];
  const float* W4  = (const float*)d_in[9];
  const float* b4  = (const float*)d_in[10];
  const float* Wr  = (const float*)d_in[11];
  const float* br  = (const float*)d_in[12];
  const float* lng = (const float*)d_in[13];
  const float* lnb = (const float*)d_in[14];
  const float* f1W = (const float*)d_in[15];
  const float* f1b = (const float*)d_in[16];
  const float* fng = (const float*)d_in[17];
  const float* fnb = (const float*)d_in[18];
  const float* f2W = (const float*)d_in[19];
  const float* f2b = (const float*)d_in[20];

  int n = in_sizes[0] / 128;   // 50000
  int e = in_sizes[1] / 2;     // 400000
  const int* src = ei;
  const int* dst = ei + e;

  // Arena (float units; bf16 buffers count n*dim/2):
  //   resid [0,64n)      live: fused L1 -> agg64_ln
  //   h2b   [64n,192n)   bf16 n x 256; live L2 -> agg256b   (holds dis*h2)
  //   t4    [64n,128n)   live fused34 -> agg64_ln           (h2b dead; holds dis*t4)
  //   z3b   [192n,320n)  bf16 n x 256; live agg256b -> fused34
  //   hn    [192n,256n)  live agg64_ln -> pool              (z3b dead)
  //   z2    [256n,320n)  live agg64(2) -> L2
  //   h1    [320n,384n)  holds dis*h1;  t1 [384n,448n) holds dis*t1
  //   meta from 448n
  float* arena = (float*)d_ws;
  float* resid = arena;
  short* h2b   = (short*)(arena + (size_t)64 * n);
  float* t4    = arena + (size_t)64 * n;
  short* z3b   = (short*)(arena + (size_t)192 * n);
  float* hn    = arena + (size_t)192 * n;
  float* z2    = arena + (size_t)256 * n;
  float* h1    = arena + (size_t)320 * n;
  float* t1    = arena + (size_t)384 * n;
  float* dis   = arena + (size_t)448 * n;  // n
  int* cnt    = (int*)(dis + n);           // n
  int* off    = cnt + n;                   // n+1
  int* cursor = off + n + 1;               // n
  int* csr    = cursor + n;                // e
  int* bsum   = csr + e;                   // 256
  int* bpre   = bsum + 256;                // 256
  float* pool = (float*)(bpre + 256);      // 64*64
  size_t wq = (((size_t)(pool + 4096)) + 15) & ~(size_t)15;
  short* wc1 = (short*)wq;                 // 64 x 128   (wc1||wcR = fused 128 x 128)
  short* wcR = wc1 + 8192;                 // 64 x 128
  short* wc2 = wcR + 8192;                 // 256 x 64
  short* wc3 = wc2 + 16384;                // 512 x 256
  short* wc4 = wc3 + 131072;               // 64 x 512
  size_t need = ((char*)(wc4 + 32768) - (char*)d_ws) + 64;
  if (ws_size < need) return;

  int nb_n = (n + 255) / 256;     // 196
  int nb_e = (e + 255) / 256;
  int nb_w = (n + 3) / 4;         // one wave per node
  int g_wide = (n + 63) / 64;     // 782
  int g_fused = (n + 127) / 128;  // 391

  // weights -> bf16 [N][K]
  wconv_k<<<960, 256, 0, stream>>>(W1, Wr, W2, W3, W4, wc1, wcR, wc2, wc3, wc4);

  // degree + CSR (hierarchical scan)
  zero_i32<<<nb_n, 256, 0, stream>>>(cnt, n);
  count_k<<<nb_e, 256, 0, stream>>>(dst, cnt, e);
  dis_k<<<nb_n, 256, 0, stream>>>(cnt, dis, n);
  scan_a<<<nb_n, 256, 0, stream>>>(cnt, bsum, n);
  scan_b<<<1, 256, 0, stream>>>(bsum, bpre, off + n, nb_n);
  scan_c<<<nb_n, 256, 0, stream>>>(cnt, bpre, off, cursor, n);
  scatter_k<<<nb_e, 256, 0, stream>>>(src, dst, cursor, csr, e);

  // fused L1 + residual: t1 = dis*(x@W1); resid = x@Wr + br
  mgemm<128, 128, 2, 2, 1, 0, 0, 0, 1, 1, 4><<<dim3(g_fused, 1), 256, 0, stream>>>(x, wc1, br, t1, resid, dis, n);
  // h1 = dis * leaky(di*sum(t1) + b1)   [OSCL pre-scales for next agg]
  agg64_k<1, 1><<<nb_w, 256, 0, stream>>>(t1, dis, off, csr, b1, h1, n);
  // z2 = di * sum(h1)
  agg64_k<0, 0><<<nb_w, 256, 0, stream>>>(h1, dis, off, csr, nullptr, z2, n);
  // h2b = dis * leaky(z2@W2 + b2)  (bf16, staged epilogue, SCL)
  mgemm<64, 256, 1, 4, 1, 1, 0, 1, 0, 1, 5><<<dim3(g_wide, 1), 256, 0, stream>>>(z2, wc2, b2, h2b, nullptr, dis, n);
  // z3 = di * sum(h2b)
  agg256b_k<<<nb_w, 256, 0, stream>>>(h2b, dis, off, csr, z3b, n);
  // t4 = dis * (leaky(z3@W3+b3) @ W4)   (h3 on-chip)
  fused34_k<<<g_wide, 256, 0, stream>>>(z3b, wc3, b3, wc4, dis, t4, n);
  // hn = LN( leaky(di*sum(t4) + b4) + resid )
  agg64_ln_k<<<nb_w, 256, 0, stream>>>(t4, dis, off, csr, b4, resid, lng, lnb, hn, n);
  // pool + MLP
  pool_k<<<64, 256, 0, stream>>>(hn, pool, n);
  mlp_k<<<64, 64, 0, stream>>>(pool, f1W, f1b, fng, fnb, f2W, f2b, (float*)d_out);
}

// Round 12
// 387.916 us; speedup vs baseline: 1.4523x; 1.0252x over previous
//
#include <hip/hip_runtime.h>
#include <hip/hip_bf16.h>
#include <math.h>

typedef short bf16x8 __attribute__((ext_vector_type(8)));
typedef short bf16x4 __attribute__((ext_vector_type(4)));
typedef float f32x4 __attribute__((ext_vector_type(4)));

__device__ inline unsigned short f2bf(float f) {
  unsigned u = __float_as_uint(f);
  u += 0x7FFF + ((u >> 16) & 1);           // RNE
  return (unsigned short)(u >> 16);
}
__device__ inline float bf2f(unsigned short h) {
  return __uint_as_float(((unsigned)h) << 16);
}

// ---------------- CSR build ----------------

__global__ __launch_bounds__(256) void zero_i32(int* __restrict__ p, int n) {
  int i = blockIdx.x * 256 + threadIdx.x;
  if (i < n) p[i] = 0;
}

__global__ __launch_bounds__(256) void count_k(const int* __restrict__ dst, int* __restrict__ cnt, int e) {
  int i = blockIdx.x * 256 + threadIdx.x;
  if (i < e) atomicAdd(&cnt[dst[i]], 1);
}

__global__ __launch_bounds__(256) void dis_k(const int* __restrict__ cnt, float* __restrict__ dis, int n) {
  int i = blockIdx.x * 256 + threadIdx.x;
  if (i < n) dis[i] = rsqrtf((float)cnt[i] + 1.0f);
}

__global__ __launch_bounds__(256) void scan_a(const int* __restrict__ cnt, int* __restrict__ bsum, int n) {
  int i = blockIdx.x * 256 + threadIdx.x;
  int v = (i < n) ? cnt[i] : 0;
#pragma unroll
  for (int o = 32; o > 0; o >>= 1) v += __shfl_xor(v, o);
  __shared__ int ws[4];
  if ((threadIdx.x & 63) == 0) ws[threadIdx.x >> 6] = v;
  __syncthreads();
  if (threadIdx.x == 0) bsum[blockIdx.x] = ws[0] + ws[1] + ws[2] + ws[3];
}

__global__ __launch_bounds__(256) void scan_b(const int* __restrict__ bsum, int* __restrict__ bpre,
                                              int* __restrict__ off_n, int nb) {
  __shared__ int s[256];
  int t = threadIdx.x;
  int v = (t < nb) ? bsum[t] : 0;
  s[t] = v;
  __syncthreads();
  for (int o = 1; o < 256; o <<= 1) {
    int u = (t >= o) ? s[t - o] : 0;
    __syncthreads();
    s[t] += u;
    __syncthreads();
  }
  if (t < nb) bpre[t] = s[t] - v;
  if (t == 255) off_n[0] = s[255];
}

__global__ __launch_bounds__(256) void scan_c(const int* __restrict__ cnt, const int* __restrict__ bpre,
                                              int* __restrict__ off, int* __restrict__ cursor, int n) {
  __shared__ int s[256];
  int i = blockIdx.x * 256 + threadIdx.x;
  int t = threadIdx.x;
  int v = (i < n) ? cnt[i] : 0;
  s[t] = v;
  __syncthreads();
  for (int o = 1; o < 256; o <<= 1) {
    int u = (t >= o) ? s[t - o] : 0;
    __syncthreads();
    s[t] += u;
    __syncthreads();
  }
  if (i < n) {
    int ov = bpre[blockIdx.x] + s[t] - v;
    off[i] = ov;
    cursor[i] = ov;
  }
}

__global__ __launch_bounds__(256) void scatter_k(const int* __restrict__ src, const int* __restrict__ dst,
                                                 int* __restrict__ cursor, int* __restrict__ csr, int e) {
  int i = blockIdx.x * 256 + threadIdx.x;
  if (i < e) {
    int p = atomicAdd(&cursor[dst[i]], 1);
    csr[p] = src[i];
  }
}

// ------- weight convert: W[K][N] fp32 -> Wc[N][K] bf16 -------

__global__ __launch_bounds__(256) void wconv_k(const float* __restrict__ W1, const float* __restrict__ Wr,
                                               const float* __restrict__ W2, const float* __restrict__ W3,
                                               const float* __restrict__ W4,
                                               short* __restrict__ o1, short* __restrict__ oR,
                                               short* __restrict__ o2, short* __restrict__ o3,
                                               short* __restrict__ o4) {
  int b = blockIdx.x;  // 960 rows total
  const float* W; short* O; int K, N, nr;
  if (b < 64)       { W = W1; O = o1; K = 128; N = 64;  nr = b; }
  else if (b < 128) { W = Wr; O = oR; K = 128; N = 64;  nr = b - 64; }
  else if (b < 384) { W = W2; O = o2; K = 64;  N = 256; nr = b - 128; }
  else if (b < 896) { W = W3; O = o3; K = 256; N = 512; nr = b - 384; }
  else              { W = W4; O = o4; K = 512; N = 64;  nr = b - 896; }
  for (int k = threadIdx.x; k < K; k += 256)
    O[(size_t)nr * K + k] = (short)f2bf(W[(size_t)k * N + nr]);
}

// ------- MFMA GEMM (generic): C[M,NTOT] = A[M,KT] @ Wc[NTOT,KT](bf16) -------
// ABF=0: A fp32 hi/lo split (2 products). ABF=1: A bf16 (1 product).
// OBF=1 (WM==1): bf16 out via LDS-staged coalesced epilogue.
// SPLIT=1 (WM=2,WN=2,NTOT=128): wn==0 -> Cv = bf16 staged, *scl; wn==1 -> Cv2 fp32 +bias.

template<int KT, int NTOT, int WM, int WN, int BIAS, int RELU, int ABF, int OBF, int SPLIT, int SCL, int BLK>
__global__ __launch_bounds__(256, BLK) void mgemm(const void* __restrict__ Av,
                                                  const short* __restrict__ Wc,
                                                  const float* __restrict__ bias,
                                                  void* __restrict__ Cv, void* __restrict__ Cv2,
                                                  const float* __restrict__ scl, int M) {
  __shared__ short As[64 * WM][ABF ? 40 : 72];
  __shared__ short Bs[64 * WN][40];
  const int tid = threadIdx.x;
  const int row0 = blockIdx.x * (64 * WM);
  const int col0 = blockIdx.y * (64 * WN);
  const int w = tid >> 6, lane = tid & 63;
  const int wm = w / WN, wn = w % WN;
  const int rm = wm * 64, cn = wn * 64;
  const int lm = lane & 15, lk = (lane >> 4) * 8;

  f32x4 acc[4][4];
#pragma unroll
  for (int i = 0; i < 4; i++)
#pragma unroll
    for (int j = 0; j < 4; j++)
#pragma unroll
      for (int r = 0; r < 4; r++) acc[i][j][r] = 0.f;

  for (int k0 = 0; k0 < KT; k0 += 32) {
#pragma unroll
    for (int p = 0; p < WM; p++) {
      int r = (tid >> 2) + p * 64;
      int kseg = (tid & 3) * 8;
      int gr = row0 + r;
      if (ABF) {
        bf16x8 v = {0, 0, 0, 0, 0, 0, 0, 0};
        if (gr < M) v = *(const bf16x8*)((const short*)Av + (size_t)gr * KT + k0 + kseg);
        *(bf16x8*)&As[r][kseg] = v;
      } else {
        float4 v0 = {0.f, 0.f, 0.f, 0.f}, v1 = {0.f, 0.f, 0.f, 0.f};
        if (gr < M) {
          const float* ap = (const float*)Av + (size_t)gr * KT + k0 + kseg;
          v0 = *(const float4*)ap;
          v1 = *(const float4*)(ap + 4);
        }
        float vv[8] = {v0.x, v0.y, v0.z, v0.w, v1.x, v1.y, v1.z, v1.w};
        bf16x8 hv, lv;
#pragma unroll
        for (int j = 0; j < 8; j++) {
          unsigned short h = f2bf(vv[j]);
          hv[j] = (short)h;
          lv[j] = (short)f2bf(vv[j] - bf2f(h));
        }
        *(bf16x8*)&As[r][kseg] = hv;
        *(bf16x8*)&As[r][32 + kseg] = lv;
      }
    }
#pragma unroll
    for (int p = 0; p < WN; p++) {
      int nr = (tid >> 2) + p * 64;
      int seg = (tid & 3) * 8;
      *(bf16x8*)&Bs[nr][seg] = *(const bf16x8*)(Wc + (size_t)(col0 + nr) * KT + k0 + seg);
    }
    __syncthreads();

    bf16x8 ah[4], al[4], bb[4];
#pragma unroll
    for (int mt = 0; mt < 4; mt++) {
      ah[mt] = *(const bf16x8*)&As[rm + mt * 16 + lm][lk];
      if (!ABF) al[mt] = *(const bf16x8*)&As[rm + mt * 16 + lm][32 + lk];
    }
#pragma unroll
    for (int nt = 0; nt < 4; nt++) bb[nt] = *(const bf16x8*)&Bs[cn + nt * 16 + lm][lk];
#pragma unroll
    for (int mt = 0; mt < 4; mt++)
#pragma unroll
      for (int nt = 0; nt < 4; nt++) {
        acc[mt][nt] = __builtin_amdgcn_mfma_f32_16x16x32_bf16(ah[mt], bb[nt], acc[mt][nt], 0, 0, 0);
        if (!ABF)
          acc[mt][nt] = __builtin_amdgcn_mfma_f32_16x16x32_bf16(al[mt], bb[nt], acc[mt][nt], 0, 0, 0);
      }
    __syncthreads();
  }

  if (SPLIT) {
    // wn==0 waves: bf16 t1 = acc*scl, staged through As for full-line writes.
    // wn==1 waves: fp32 resid = acc + bias, direct stores.
    short* epi = (short*)&As[0][0];   // 128*64 shorts = 16 KB <= As(18.4 KB)
    if (wn == 0) {
#pragma unroll
      for (int mt = 0; mt < 4; mt++) {
        int lr = rm + mt * 16 + (lane >> 4) * 4;
#pragma unroll
        for (int r = 0; r < 4; r++) {
          int gr = row0 + lr + r;
          float sc = (SCL && gr < M) ? scl[gr] : 0.f;
#pragma unroll
          for (int nt = 0; nt < 4; nt++)
            epi[(lr + r) * 64 + nt * 16 + lm] = (short)f2bf(acc[mt][nt][r] * sc);
        }
      }
    } else {
#pragma unroll
      for (int mt = 0; mt < 4; mt++) {
        int grb = row0 + rm + mt * 16 + (lane >> 4) * 4;
#pragma unroll
        for (int nt = 0; nt < 4; nt++) {
          int gc = nt * 16 + lm;
          float bv = bias[gc];
#pragma unroll
          for (int r = 0; r < 4; r++) {
            int gr = grb + r;
            if (gr < M) ((float*)Cv2)[(size_t)gr * 64 + gc] = acc[mt][nt][r] + bv;
          }
        }
      }
    }
    __syncthreads();
    int base = tid * 32;               // 8192 shorts / 256 threads
    int row = base >> 6, col = base & 63;
    int gr = row0 + row;
    if (gr < M) {
#pragma unroll
      for (int q = 0; q < 4; q++)
        *(bf16x8*)((short*)Cv + (size_t)gr * 64 + col + q * 8) = *(bf16x8*)&epi[base + q * 8];
    }
  } else if (OBF && WM == 1) {
    short* epi = &Bs[0][0];
    const int NCOL = 64 * WN;
    float bvv[4];
#pragma unroll
    for (int nt = 0; nt < 4; nt++) bvv[nt] = BIAS ? bias[col0 + cn + nt * 16 + lm] : 0.f;
#pragma unroll
    for (int mt = 0; mt < 4; mt++) {
      __syncthreads();
#pragma unroll
      for (int r = 0; r < 4; r++) {
        int gr = row0 + mt * 16 + (lane >> 4) * 4 + r;
        float sc = (SCL && gr < M) ? scl[gr] : 1.f;
#pragma unroll
        for (int nt = 0; nt < 4; nt++) {
          float v = acc[mt][nt][r] + bvv[nt];
          if (RELU) v = (v >= 0.f) ? v : 0.01f * v;
          if (SCL) v *= sc;
          epi[((lane >> 4) * 4 + r) * NCOL + cn + nt * 16 + lm] = (short)f2bf(v);
        }
      }
      __syncthreads();
      const int per = (16 * NCOL) / 256;
      int base = tid * per;
      int lr = base / NCOL, lc = base % NCOL;
      int gr = row0 + mt * 16 + lr;
      if (gr < M) {
#pragma unroll
        for (int q = 0; q < per / 8; q++)
          *(bf16x8*)((short*)Cv + (size_t)gr * NTOT + col0 + lc + q * 8) = *(bf16x8*)&epi[base + q * 8];
      }
    }
  } else {
#pragma unroll
    for (int mt = 0; mt < 4; mt++) {
      int grb = row0 + rm + mt * 16 + (lane >> 4) * 4;
#pragma unroll
      for (int nt = 0; nt < 4; nt++) {
        int gc = col0 + cn + nt * 16 + lm;
        float bv = BIAS ? bias[gc] : 0.f;
#pragma unroll
        for (int r = 0; r < 4; r++) {
          int gr = grb + r;
          if (gr < M) {
            float v = acc[mt][nt][r] + bv;
            if (RELU) v = (v >= 0.f) ? v : 0.01f * v;
            if (SCL) v *= scl[gr];
            if (OBF) ((short*)Cv)[(size_t)gr * NTOT + gc] = (short)f2bf(v);
            else     ((float*)Cv)[(size_t)gr * NTOT + gc] = v;
          }
        }
      }
    }
  }
}

// ------- fused layer3+layer4: t4 = dis * (leaky(z3 @ W3 + b3) @ W4) -------
// R12: 32-col h3 chunks (16 chunks) -> LDS 26.5 KB -> 5 blocks/CU.

__global__ __launch_bounds__(256, 5) void fused34_k(const short* __restrict__ z3,
                                                    const short* __restrict__ W3c,  // [512][256] bf16
                                                    const float* __restrict__ b3,
                                                    const short* __restrict__ W4c,  // [64][512] bf16
                                                    const float* __restrict__ dis,
                                                    float* __restrict__ T4, int M) {
  __shared__ short Bs[32][264];  // W3 chunk: 32 n-rows x 256 k (16.9 KB)
  __shared__ short Hs[64][40];   // h3 chunk (64 rows x 32 cols), A-layout
  __shared__ short Ws4[64][40];  // W4 chunk: 64 out x 32 k
  const int tid = threadIdx.x;
  const int row0 = blockIdx.x * 64;
  const int w = tid >> 6, lane = tid & 63;
  const int lm = lane & 15, lk = (lane >> 4) * 8;
  const int rquad = (lane >> 4) * 4;

  // z3 A-fragments in registers (wave-private 16 rows, full K=256)
  bf16x8 afr[8];
  {
    int gr = row0 + w * 16 + lm;
    bool ok = gr < M;
    const short* zp = z3 + (size_t)gr * 256 + lk;
#pragma unroll
    for (int kc = 0; kc < 8; kc++) {
      bf16x8 v = {0, 0, 0, 0, 0, 0, 0, 0};
      if (ok) v = *(const bf16x8*)(zp + kc * 32);
      afr[kc] = v;
    }
  }

  f32x4 t4acc[4];
#pragma unroll
  for (int nt = 0; nt < 4; nt++)
#pragma unroll
    for (int r = 0; r < 4; r++) t4acc[nt][r] = 0.f;

  for (int c = 0; c < 16; c++) {
    // stage W3 chunk-c (32 rows x 256 k): 4 coalesced bf16x8 per thread
#pragma unroll
    for (int q = 0; q < 4; q++) {
      int flat = q * 2048 + tid * 8;
      int rr = flat >> 8, cc = flat & 255;
      *(bf16x8*)&Bs[rr][cc] = *(const bf16x8*)(W3c + (size_t)c * 32 * 256 + flat);
    }
    // stage W4 chunk (k-range c*32..c*32+31 for all 64 outputs): 1 bf16x8 per thread
    Ws4[tid >> 2][(tid & 3) * 8 + 0] = 0;  // placate compiler about aliasing? no—overwritten below
    *(bf16x8*)&Ws4[tid >> 2][(tid & 3) * 8] =
        *(const bf16x8*)(W4c + (size_t)(tid >> 2) * 512 + c * 32 + (tid & 3) * 8);
    __syncthreads();

    // stage-1: h3 chunk (2 nt tiles), 16 MFMA, barrier-free
    f32x4 acc1[2];
#pragma unroll
    for (int nt = 0; nt < 2; nt++)
#pragma unroll
      for (int r = 0; r < 4; r++) acc1[nt][r] = 0.f;
#pragma unroll
    for (int k0 = 0; k0 < 8; k0++) {
      bf16x8 bb[2];
#pragma unroll
      for (int nt = 0; nt < 2; nt++) bb[nt] = *(const bf16x8*)&Bs[nt * 16 + lm][k0 * 32 + lk];
#pragma unroll
      for (int nt = 0; nt < 2; nt++)
        acc1[nt] = __builtin_amdgcn_mfma_f32_16x16x32_bf16(afr[k0], bb[nt], acc1[nt], 0, 0, 0);
    }
    // bias + leaky -> bf16 -> Hs (C-layout -> A-layout; same-wave rows)
#pragma unroll
    for (int nt = 0; nt < 2; nt++) {
      float bv = b3[c * 32 + nt * 16 + lm];
#pragma unroll
      for (int r = 0; r < 4; r++) {
        float v = acc1[nt][r] + bv;
        v = (v >= 0.f) ? v : 0.01f * v;
        Hs[w * 16 + rquad + r][nt * 16 + lm] = (short)f2bf(v);
      }
    }
    // stage-2: t4 += h3_chunk @ W4_chunk (k=32, 4 MFMA)
    {
      bf16x8 ah2 = *(const bf16x8*)&Hs[w * 16 + lm][lk];
      bf16x8 bb2[4];
#pragma unroll
      for (int nt = 0; nt < 4; nt++) bb2[nt] = *(const bf16x8*)&Ws4[nt * 16 + lm][lk];
#pragma unroll
      for (int nt = 0; nt < 4; nt++)
        t4acc[nt] = __builtin_amdgcn_mfma_f32_16x16x32_bf16(ah2, bb2[nt], t4acc[nt], 0, 0, 0);
    }
    __syncthreads();
  }
  // epilogue: t4 fp32, pre-scaled by dis[row]
#pragma unroll
  for (int r = 0; r < 4; r++) {
    int gr = row0 + w * 16 + rquad + r;
    float sc = (gr < M) ? dis[gr] : 0.f;
#pragma unroll
    for (int nt = 0; nt < 4; nt++) {
      int gc = nt * 16 + lm;
      if (gr < M) T4[(size_t)gr * 64 + gc] = t4acc[nt][r] * sc;
    }
  }
}

// ---------------- Aggregation (dis-free; rows pre-scaled by dis) ----------------
// bf16 in / bf16 out, 64-dim. out = di*(sum + self); BR: +bias,leaky; OSCL: *di again.

template<int BR, int OSCL>
__global__ __launch_bounds__(256) void aggb64_k(const short* __restrict__ T, const float* __restrict__ dis,
                                                const int* __restrict__ off, const int* __restrict__ csr,
                                                const float* __restrict__ bias, short* __restrict__ Out, int n) {
  int wid = (blockIdx.x * 256 + threadIdx.x) >> 6;
  int lane = threadIdx.x & 63;
  if (wid >= n) return;
  float di = dis[wid];
  int e0 = off[wid], e1 = off[wid + 1];
  float acc = bf2f((unsigned short)T[(size_t)wid * 64 + lane]);
  int e = e0;
  for (; e + 4 <= e1; e += 4) {
    int j0 = csr[e], j1 = csr[e + 1], j2 = csr[e + 2], j3 = csr[e + 3];
    float v0 = bf2f((unsigned short)T[(size_t)j0 * 64 + lane]);
    float v1 = bf2f((unsigned short)T[(size_t)j1 * 64 + lane]);
    float v2 = bf2f((unsigned short)T[(size_t)j2 * 64 + lane]);
    float v3 = bf2f((unsigned short)T[(size_t)j3 * 64 + lane]);
    acc += (v0 + v1) + (v2 + v3);
  }
  for (; e < e1; e++) acc += bf2f((unsigned short)T[(size_t)csr[e] * 64 + lane]);
  float v = di * acc;
  if (BR) {
    v += bias[lane];
    v = (v >= 0.f) ? v : 0.01f * v;
  }
  if (OSCL) v *= di;
  Out[(size_t)wid * 64 + lane] = (short)f2bf(v);
}

// layer-4 tail fused: hn = LN( leaky(di*sum(t4) + b4) + resid )   (t4, resid fp32)
__global__ __launch_bounds__(256) void agg64_ln_k(const float* __restrict__ T, const float* __restrict__ dis,
                                                  const int* __restrict__ off, const int* __restrict__ csr,
                                                  const float* __restrict__ bias, const float* __restrict__ resid,
                                                  const float* __restrict__ g, const float* __restrict__ b,
                                                  float* __restrict__ outh, int n) {
  int wid = (blockIdx.x * 256 + threadIdx.x) >> 6;
  int lane = threadIdx.x & 63;
  if (wid >= n) return;
  float di = dis[wid];
  int e0 = off[wid], e1 = off[wid + 1];
  float acc = T[(size_t)wid * 64 + lane];
  int e = e0;
  for (; e + 4 <= e1; e += 4) {
    int j0 = csr[e], j1 = csr[e + 1], j2 = csr[e + 2], j3 = csr[e + 3];
    float v0 = T[(size_t)j0 * 64 + lane];
    float v1 = T[(size_t)j1 * 64 + lane];
    float v2 = T[(size_t)j2 * 64 + lane];
    float v3 = T[(size_t)j3 * 64 + lane];
    acc += (v0 + v1) + (v2 + v3);
  }
  for (; e < e1; e++) acc += T[(size_t)csr[e] * 64 + lane];
  float v = di * acc + bias[lane];
  v = (v >= 0.f) ? v : 0.01f * v;
  v += resid[(size_t)wid * 64 + lane];
  float s = v, ss = v * v;
#pragma unroll
  for (int o = 32; o > 0; o >>= 1) {
    s += __shfl_xor(s, o);
    ss += __shfl_xor(ss, o);
  }
  float m = s * (1.f / 64.f);
  float var = ss * (1.f / 64.f) - m * m;
  float y = (v - m) * rsqrtf(var + 1e-5f) * g[lane] + b[lane];
  outh[(size_t)wid * 64 + lane] = y;
}

// bf16 gather for the 256-dim layer (rows pre-scaled): z3 = di*(sum + self)
__global__ __launch_bounds__(256) void agg256b_k(const short* __restrict__ T, const float* __restrict__ dis,
                                                 const int* __restrict__ off, const int* __restrict__ csr,
                                                 short* __restrict__ Out, int n) {
  int wid = (blockIdx.x * 256 + threadIdx.x) >> 6;
  int lane = threadIdx.x & 63;
  if (wid >= n) return;
  float di = dis[wid];
  int e0 = off[wid], e1 = off[wid + 1];
  bf16x4 sf = *(const bf16x4*)&T[(size_t)wid * 256 + lane * 4];
  float a0 = bf2f((unsigned short)sf[0]);
  float a1 = bf2f((unsigned short)sf[1]);
  float a2 = bf2f((unsigned short)sf[2]);
  float a3 = bf2f((unsigned short)sf[3]);
  int e = e0;
  for (; e + 4 <= e1; e += 4) {
    int j0 = csr[e], j1 = csr[e + 1], j2 = csr[e + 2], j3 = csr[e + 3];
    bf16x4 t0 = *(const bf16x4*)&T[(size_t)j0 * 256 + lane * 4];
    bf16x4 t1 = *(const bf16x4*)&T[(size_t)j1 * 256 + lane * 4];
    bf16x4 t2 = *(const bf16x4*)&T[(size_t)j2 * 256 + lane * 4];
    bf16x4 t3 = *(const bf16x4*)&T[(size_t)j3 * 256 + lane * 4];
    a0 += (bf2f((unsigned short)t0[0]) + bf2f((unsigned short)t1[0])) +
          (bf2f((unsigned short)t2[0]) + bf2f((unsigned short)t3[0]));
    a1 += (bf2f((unsigned short)t0[1]) + bf2f((unsigned short)t1[1])) +
          (bf2f((unsigned short)t2[1]) + bf2f((unsigned short)t3[1]));
    a2 += (bf2f((unsigned short)t0[2]) + bf2f((unsigned short)t1[2])) +
          (bf2f((unsigned short)t2[2]) + bf2f((unsigned short)t3[2]));
    a3 += (bf2f((unsigned short)t0[3]) + bf2f((unsigned short)t1[3])) +
          (bf2f((unsigned short)t2[3]) + bf2f((unsigned short)t3[3]));
  }
  for (; e < e1; e++) {
    bf16x4 t = *(const bf16x4*)&T[(size_t)csr[e] * 256 + lane * 4];
    a0 += bf2f((unsigned short)t[0]);
    a1 += bf2f((unsigned short)t[1]);
    a2 += bf2f((unsigned short)t[2]);
    a3 += bf2f((unsigned short)t[3]);
  }
  bf16x4 o;
  o[0] = (short)f2bf(di * a0);
  o[1] = (short)f2bf(di * a1);
  o[2] = (short)f2bf(di * a2);
  o[3] = (short)f2bf(di * a3);
  *(bf16x4*)&Out[(size_t)wid * 256 + lane * 4] = o;
}

// ---------------- per-graph max pool ----------------

__global__ __launch_bounds__(256) void pool_k(const float* __restrict__ hn, float* __restrict__ p, int n) {
  const int G = 64;
  int g = blockIdx.x;
  int f = threadIdx.x & 63, c = threadIdx.x >> 6;
  long long s = ((long long)g * n + G - 1) / G;
  long long e = ((long long)(g + 1) * n + G - 1) / G;
  float m = -INFINITY;
  for (long long i = s + c; i < e; i += 4) m = fmaxf(m, hn[(size_t)i * 64 + f]);
  __shared__ float red[4][64];
  red[c][f] = m;
  __syncthreads();
  if (c == 0) {
    m = fmaxf(fmaxf(red[0][f], red[1][f]), fmaxf(red[2][f], red[3][f]));
    p[g * 64 + f] = m;
  }
}

// ---------------- final MLP ----------------

__global__ __launch_bounds__(64) void mlp_k(const float* __restrict__ p, const float* __restrict__ fc1W,
                                            const float* __restrict__ fc1b, const float* __restrict__ fng,
                                            const float* __restrict__ fnb, const float* __restrict__ fc2W,
                                            const float* __restrict__ fc2b, float* __restrict__ out) {
  int g = blockIdx.x;
  int lane = threadIdx.x;
  __shared__ float ps[64], qs[64];
  ps[lane] = p[g * 64 + lane];
  __syncthreads();
  float q = fc1b[lane];
#pragma unroll 8
  for (int k = 0; k < 64; k++) q = fmaf(ps[k], fc1W[k * 64 + lane], q);
  float s = q, ss = q * q;
#pragma unroll
  for (int o = 32; o > 0; o >>= 1) {
    s += __shfl_xor(s, o);
    ss += __shfl_xor(ss, o);
  }
  float m = s * (1.f / 64.f);
  float var = ss * (1.f / 64.f) - m * m;
  float y = (q - m) * rsqrtf(var + 1e-5f) * fng[lane] + fnb[lane];
  y = (y >= 0.f) ? y : 0.01f * y;
  qs[lane] = y;
  __syncthreads();
  if (lane < 16) {
    float o = fc2b[lane];
#pragma unroll 8
    for (int k = 0; k < 64; k++) o = fmaf(qs[k], fc2W[k * 16 + lane], o);
    out[g * 16 + lane] = o;
  }
}

// ---------------- launch ----------------

extern "C" void kernel_launch(void* const* d_in, const int* in_sizes, int n_in,
                              void* d_out, int out_size, void* d_ws, size_t ws_size,
                              hipStream_t stream) {
  const float* x   = (const float*)d_in[0];
  const int*   ei  = (const int*)d_in[1];
  const float* W1  = (const float*)d_in[3];
  const float* b1  = (const float*)d_in[4];
  const float* W2  = (const float*)d_in[5];
  const float* b2  = (const float*)d_in[6];
  const float* W3  = (const float*)d_in[7];
  const float* b3  = (const float*)d_in[8];
  const float* W4  = (const float*)d_in[9];
  const float* b4  = (const float*)d_in[10];
  const float* Wr  = (const float*)d_in[11];
  const float* br  = (const float*)d_in[12];
  const float* lng = (const float*)d_in[13];
  const float* lnb = (const float*)d_in[14];
  const float* f1W = (const float*)d_in[15];
  const float* f1b = (const float*)d_in[16];
  const float* fng = (const float*)d_in[17];
  const float* fnb = (const float*)d_in[18];
  const float* f2W = (const float*)d_in[19];
  const float* f2b = (const float*)d_in[20];

  int n = in_sizes[0] / 128;   // 50000
  int e = in_sizes[1] / 2;     // 400000
  const int* src = ei;
  const int* dst = ei + e;

  // Arena (float units; bf16 buffers count n*dim/2):
  //   resid [0,64n)      live: fused L1 -> agg64_ln
  //   h2b   [64n,192n)   bf16 n x 256; live L2 -> agg256b
  //   t4    [64n,128n)   fp32; live fused34 -> agg64_ln   (h2b dead)
  //   z3b   [192n,320n)  bf16 n x 256; live agg256b -> fused34
  //   hn    [192n,256n)  live agg64_ln -> pool            (z3b dead)
  //   t1b   [320n,352n)  bf16 n x 64; live L1 -> aggb64(1)
  //   h1b   [352n,384n)  bf16 n x 64; live aggb64(1) -> aggb64(2)
  //   z2b   [384n,416n)  bf16 n x 64; live aggb64(2) -> L2
  //   meta from 448n
  float* arena = (float*)d_ws;
  float* resid = arena;
  short* h2b   = (short*)(arena + (size_t)64 * n);
  float* t4    = arena + (size_t)64 * n;
  short* z3b   = (short*)(arena + (size_t)192 * n);
  float* hn    = arena + (size_t)192 * n;
  short* t1b   = (short*)(arena + (size_t)320 * n);
  short* h1b   = (short*)(arena + (size_t)352 * n);
  short* z2b   = (short*)(arena + (size_t)384 * n);
  float* dis   = arena + (size_t)448 * n;  // n
  int* cnt    = (int*)(dis + n);           // n
  int* off    = cnt + n;                   // n+1
  int* cursor = off + n + 1;               // n
  int* csr    = cursor + n;                // e
  int* bsum   = csr + e;                   // 256
  int* bpre   = bsum + 256;                // 256
  float* pool = (float*)(bpre + 256);      // 64*64
  size_t wq = (((size_t)(pool + 4096)) + 15) & ~(size_t)15;
  short* wc1 = (short*)wq;                 // 64 x 128   (wc1||wcR = fused 128 x 128)
  short* wcR = wc1 + 8192;                 // 64 x 128
  short* wc2 = wcR + 8192;                 // 256 x 64
  short* wc3 = wc2 + 16384;                // 512 x 256
  short* wc4 = wc3 + 131072;               // 64 x 512
  size_t need = ((char*)(wc4 + 32768) - (char*)d_ws) + 64;
  if (ws_size < need) return;

  int nb_n = (n + 255) / 256;     // 196
  int nb_e = (e + 255) / 256;
  int nb_w = (n + 3) / 4;         // one wave per node
  int g_wide = (n + 63) / 64;     // 782
  int g_fused = (n + 127) / 128;  // 391

  // weights -> bf16 [N][K]
  wconv_k<<<960, 256, 0, stream>>>(W1, Wr, W2, W3, W4, wc1, wcR, wc2, wc3, wc4);

  // degree + CSR (hierarchical scan)
  zero_i32<<<nb_n, 256, 0, stream>>>(cnt, n);
  count_k<<<nb_e, 256, 0, stream>>>(dst, cnt, e);
  dis_k<<<nb_n, 256, 0, stream>>>(cnt, dis, n);
  scan_a<<<nb_n, 256, 0, stream>>>(cnt, bsum, n);
  scan_b<<<1, 256, 0, stream>>>(bsum, bpre, off + n, nb_n);
  scan_c<<<nb_n, 256, 0, stream>>>(cnt, bpre, off, cursor, n);
  scatter_k<<<nb_e, 256, 0, stream>>>(src, dst, cursor, csr, e);

  // fused L1 + residual: t1b = bf16(dis*(x@W1)); resid = x@Wr + br
  mgemm<128, 128, 2, 2, 1, 0, 0, 0, 1, 1, 4><<<dim3(g_fused, 1), 256, 0, stream>>>(x, wc1, br, t1b, resid, dis, n);
  // h1b = bf16( dis * leaky(di*sum(t1) + b1) )
  aggb64_k<1, 1><<<nb_w, 256, 0, stream>>>(t1b, dis, off, csr, b1, h1b, n);
  // z2b = bf16( di * sum(h1) )
  aggb64_k<0, 0><<<nb_w, 256, 0, stream>>>(h1b, dis, off, csr, nullptr, z2b, n);
  // h2b = bf16( dis * leaky(z2@W2 + b2) )   (A bf16 single product)
  mgemm<64, 256, 1, 4, 1, 1, 1, 1, 0, 1, 5><<<dim3(g_wide, 1), 256, 0, stream>>>(z2b, wc2, b2, h2b, nullptr, dis, n);
  // z3b = bf16( di * sum(h2b) )
  agg256b_k<<<nb_w, 256, 0, stream>>>(h2b, dis, off, csr, z3b, n);
  // t4 = dis * (leaky(z3@W3+b3) @ W4)   (h3 on-chip)
  fused34_k<<<g_wide, 256, 0, stream>>>(z3b, wc3, b3, wc4, dis, t4, n);
  // hn = LN( leaky(di*sum(t4) + b4) + resid )
  agg64_ln_k<<<nb_w, 256, 0, stream>>>(t4, dis, off, csr, b4, resid, lng, lnb, hn, n);
  // pool + MLP
  pool_k<<<64, 256, 0, stream>>>(hn, pool, n);
  mlp_k<<<64, 64, 0, stream>>>(pool, f1W, f1b, fng, fnb, f2W, f2b, (float*)d_out);
}

// Round 13
// 378.531 us; speedup vs baseline: 1.4883x; 1.0248x over previous
//
#include <hip/hip_runtime.h>
#include <hip/hip_bf16.h>
#include <math.h>

typedef short bf16x8 __attribute__((ext_vector_type(8)));
typedef short bf16x4 __attribute__((ext_vector_type(4)));
typedef float f32x4 __attribute__((ext_vector_type(4)));

__device__ inline unsigned short f2bf(float f) {
  unsigned u = __float_as_uint(f);
  u += 0x7FFF + ((u >> 16) & 1);           // RNE
  return (unsigned short)(u >> 16);
}
__device__ inline float bf2f(unsigned short h) {
  return __uint_as_float(((unsigned)h) << 16);
}

// ---------------- CSR build ----------------

__global__ __launch_bounds__(256) void zero_i32(int* __restrict__ p, int n) {
  int i = blockIdx.x * 256 + threadIdx.x;
  if (i < n) p[i] = 0;
}

__global__ __launch_bounds__(256) void count_k(const int* __restrict__ dst, int* __restrict__ cnt, int e) {
  int i = blockIdx.x * 256 + threadIdx.x;
  if (i < e) atomicAdd(&cnt[dst[i]], 1);
}

__global__ __launch_bounds__(256) void scan_a(const int* __restrict__ cnt, int* __restrict__ bsum, int n) {
  int i = blockIdx.x * 256 + threadIdx.x;
  int v = (i < n) ? cnt[i] : 0;
#pragma unroll
  for (int o = 32; o > 0; o >>= 1) v += __shfl_xor(v, o);
  __shared__ int ws[4];
  if ((threadIdx.x & 63) == 0) ws[threadIdx.x >> 6] = v;
  __syncthreads();
  if (threadIdx.x == 0) bsum[blockIdx.x] = ws[0] + ws[1] + ws[2] + ws[3];
}

__global__ __launch_bounds__(256) void scan_b(const int* __restrict__ bsum, int* __restrict__ bpre,
                                              int* __restrict__ off_n, int nb) {
  __shared__ int s[256];
  int t = threadIdx.x;
  int v = (t < nb) ? bsum[t] : 0;
  s[t] = v;
  __syncthreads();
  for (int o = 1; o < 256; o <<= 1) {
    int u = (t >= o) ? s[t - o] : 0;
    __syncthreads();
    s[t] += u;
    __syncthreads();
  }
  if (t < nb) bpre[t] = s[t] - v;
  if (t == 255) off_n[0] = s[255];
}

// scan_c also computes dis = rsqrt(cnt+1)
__global__ __launch_bounds__(256) void scan_c(const int* __restrict__ cnt, const int* __restrict__ bpre,
                                              int* __restrict__ off, int* __restrict__ cursor,
                                              float* __restrict__ dis, int n) {
  __shared__ int s[256];
  int i = blockIdx.x * 256 + threadIdx.x;
  int t = threadIdx.x;
  int v = (i < n) ? cnt[i] : 0;
  s[t] = v;
  __syncthreads();
  for (int o = 1; o < 256; o <<= 1) {
    int u = (t >= o) ? s[t - o] : 0;
    __syncthreads();
    s[t] += u;
    __syncthreads();
  }
  if (i < n) {
    int ov = bpre[blockIdx.x] + s[t] - v;
    off[i] = ov;
    cursor[i] = ov;
    dis[i] = rsqrtf((float)v + 1.0f);
  }
}

__global__ __launch_bounds__(256) void scatter_k(const int* __restrict__ src, const int* __restrict__ dst,
                                                 int* __restrict__ cursor, int* __restrict__ csr, int e) {
  int i = blockIdx.x * 256 + threadIdx.x;
  if (i < e) {
    int p = atomicAdd(&cursor[dst[i]], 1);
    csr[p] = src[i];
  }
}

// ------- weight convert: W[K][N] fp32 -> Wc[N][K] bf16 -------

__global__ __launch_bounds__(256) void wconv_k(const float* __restrict__ W1, const float* __restrict__ Wr,
                                               const float* __restrict__ W2, const float* __restrict__ W3,
                                               const float* __restrict__ W4,
                                               short* __restrict__ o1, short* __restrict__ oR,
                                               short* __restrict__ o2, short* __restrict__ o3,
                                               short* __restrict__ o4) {
  int b = blockIdx.x;  // 960 rows total
  const float* W; short* O; int K, N, nr;
  if (b < 64)       { W = W1; O = o1; K = 128; N = 64;  nr = b; }
  else if (b < 128) { W = Wr; O = oR; K = 128; N = 64;  nr = b - 64; }
  else if (b < 384) { W = W2; O = o2; K = 64;  N = 256; nr = b - 128; }
  else if (b < 896) { W = W3; O = o3; K = 256; N = 512; nr = b - 384; }
  else              { W = W4; O = o4; K = 512; N = 64;  nr = b - 896; }
  for (int k = threadIdx.x; k < K; k += 256)
    O[(size_t)nr * K + k] = (short)f2bf(W[(size_t)k * N + nr]);
}

// ------- MFMA GEMM (generic): C[M,NTOT] = A[M,KT] @ Wc[NTOT,KT](bf16) -------

template<int KT, int NTOT, int WM, int WN, int BIAS, int RELU, int ABF, int OBF, int SPLIT, int SCL, int BLK>
__global__ __launch_bounds__(256, BLK) void mgemm(const void* __restrict__ Av,
                                                  const short* __restrict__ Wc,
                                                  const float* __restrict__ bias,
                                                  void* __restrict__ Cv, void* __restrict__ Cv2,
                                                  const float* __restrict__ scl, int M) {
  __shared__ short As[64 * WM][ABF ? 40 : 72];
  __shared__ short Bs[64 * WN][40];
  const int tid = threadIdx.x;
  const int row0 = blockIdx.x * (64 * WM);
  const int col0 = blockIdx.y * (64 * WN);
  const int w = tid >> 6, lane = tid & 63;
  const int wm = w / WN, wn = w % WN;
  const int rm = wm * 64, cn = wn * 64;
  const int lm = lane & 15, lk = (lane >> 4) * 8;

  f32x4 acc[4][4];
#pragma unroll
  for (int i = 0; i < 4; i++)
#pragma unroll
    for (int j = 0; j < 4; j++)
#pragma unroll
      for (int r = 0; r < 4; r++) acc[i][j][r] = 0.f;

  for (int k0 = 0; k0 < KT; k0 += 32) {
#pragma unroll
    for (int p = 0; p < WM; p++) {
      int r = (tid >> 2) + p * 64;
      int kseg = (tid & 3) * 8;
      int gr = row0 + r;
      if (ABF) {
        bf16x8 v = {0, 0, 0, 0, 0, 0, 0, 0};
        if (gr < M) v = *(const bf16x8*)((const short*)Av + (size_t)gr * KT + k0 + kseg);
        *(bf16x8*)&As[r][kseg] = v;
      } else {
        float4 v0 = {0.f, 0.f, 0.f, 0.f}, v1 = {0.f, 0.f, 0.f, 0.f};
        if (gr < M) {
          const float* ap = (const float*)Av + (size_t)gr * KT + k0 + kseg;
          v0 = *(const float4*)ap;
          v1 = *(const float4*)(ap + 4);
        }
        float vv[8] = {v0.x, v0.y, v0.z, v0.w, v1.x, v1.y, v1.z, v1.w};
        bf16x8 hv, lv;
#pragma unroll
        for (int j = 0; j < 8; j++) {
          unsigned short h = f2bf(vv[j]);
          hv[j] = (short)h;
          lv[j] = (short)f2bf(vv[j] - bf2f(h));
        }
        *(bf16x8*)&As[r][kseg] = hv;
        *(bf16x8*)&As[r][32 + kseg] = lv;
      }
    }
#pragma unroll
    for (int p = 0; p < WN; p++) {
      int nr = (tid >> 2) + p * 64;
      int seg = (tid & 3) * 8;
      *(bf16x8*)&Bs[nr][seg] = *(const bf16x8*)(Wc + (size_t)(col0 + nr) * KT + k0 + seg);
    }
    __syncthreads();

    bf16x8 ah[4], al[4], bb[4];
#pragma unroll
    for (int mt = 0; mt < 4; mt++) {
      ah[mt] = *(const bf16x8*)&As[rm + mt * 16 + lm][lk];
      if (!ABF) al[mt] = *(const bf16x8*)&As[rm + mt * 16 + lm][32 + lk];
    }
#pragma unroll
    for (int nt = 0; nt < 4; nt++) bb[nt] = *(const bf16x8*)&Bs[cn + nt * 16 + lm][lk];
#pragma unroll
    for (int mt = 0; mt < 4; mt++)
#pragma unroll
      for (int nt = 0; nt < 4; nt++) {
        acc[mt][nt] = __builtin_amdgcn_mfma_f32_16x16x32_bf16(ah[mt], bb[nt], acc[mt][nt], 0, 0, 0);
        if (!ABF)
          acc[mt][nt] = __builtin_amdgcn_mfma_f32_16x16x32_bf16(al[mt], bb[nt], acc[mt][nt], 0, 0, 0);
      }
    __syncthreads();
  }

  if (SPLIT) {
    short* epi = (short*)&As[0][0];   // 128*64 shorts = 16 KB
    if (wn == 0) {
#pragma unroll
      for (int mt = 0; mt < 4; mt++) {
        int lr = rm + mt * 16 + (lane >> 4) * 4;
#pragma unroll
        for (int r = 0; r < 4; r++) {
          int gr = row0 + lr + r;
          float sc = (SCL && gr < M) ? scl[gr] : 0.f;
#pragma unroll
          for (int nt = 0; nt < 4; nt++)
            epi[(lr + r) * 64 + nt * 16 + lm] = (short)f2bf(acc[mt][nt][r] * sc);
        }
      }
    } else {
#pragma unroll
      for (int mt = 0; mt < 4; mt++) {
        int grb = row0 + rm + mt * 16 + (lane >> 4) * 4;
#pragma unroll
        for (int nt = 0; nt < 4; nt++) {
          int gc = nt * 16 + lm;
          float bv = bias[gc];
#pragma unroll
          for (int r = 0; r < 4; r++) {
            int gr = grb + r;
            if (gr < M) ((float*)Cv2)[(size_t)gr * 64 + gc] = acc[mt][nt][r] + bv;
          }
        }
      }
    }
    __syncthreads();
    int base = tid * 32;
    int row = base >> 6, col = base & 63;
    int gr = row0 + row;
    if (gr < M) {
#pragma unroll
      for (int q = 0; q < 4; q++)
        *(bf16x8*)((short*)Cv + (size_t)gr * 64 + col + q * 8) = *(bf16x8*)&epi[base + q * 8];
    }
  } else if (OBF && WM == 1) {
    short* epi = &Bs[0][0];
    const int NCOL = 64 * WN;
    float bvv[4];
#pragma unroll
    for (int nt = 0; nt < 4; nt++) bvv[nt] = BIAS ? bias[col0 + cn + nt * 16 + lm] : 0.f;
#pragma unroll
    for (int mt = 0; mt < 4; mt++) {
      __syncthreads();
#pragma unroll
      for (int r = 0; r < 4; r++) {
        int gr = row0 + mt * 16 + (lane >> 4) * 4 + r;
        float sc = (SCL && gr < M) ? scl[gr] : 1.f;
#pragma unroll
        for (int nt = 0; nt < 4; nt++) {
          float v = acc[mt][nt][r] + bvv[nt];
          if (RELU) v = (v >= 0.f) ? v : 0.01f * v;
          if (SCL) v *= sc;
          epi[((lane >> 4) * 4 + r) * NCOL + cn + nt * 16 + lm] = (short)f2bf(v);
        }
      }
      __syncthreads();
      const int per = (16 * NCOL) / 256;
      int base = tid * per;
      int lr = base / NCOL, lc = base % NCOL;
      int gr = row0 + mt * 16 + lr;
      if (gr < M) {
#pragma unroll
        for (int q = 0; q < per / 8; q++)
          *(bf16x8*)((short*)Cv + (size_t)gr * NTOT + col0 + lc + q * 8) = *(bf16x8*)&epi[base + q * 8];
      }
    }
  } else {
#pragma unroll
    for (int mt = 0; mt < 4; mt++) {
      int grb = row0 + rm + mt * 16 + (lane >> 4) * 4;
#pragma unroll
      for (int nt = 0; nt < 4; nt++) {
        int gc = col0 + cn + nt * 16 + lm;
        float bv = BIAS ? bias[gc] : 0.f;
#pragma unroll
        for (int r = 0; r < 4; r++) {
          int gr = grb + r;
          if (gr < M) {
            float v = acc[mt][nt][r] + bv;
            if (RELU) v = (v >= 0.f) ? v : 0.01f * v;
            if (SCL) v *= scl[gr];
            if (OBF) ((short*)Cv)[(size_t)gr * NTOT + gc] = (short)f2bf(v);
            else     ((float*)Cv)[(size_t)gr * NTOT + gc] = v;
          }
        }
      }
    }
  }
}

// ------- fused layer3+layer4: t4 = dis * (leaky(z3 @ W3 + b3) @ W4) -------
// R13: ping-pong double-buffered W3/W4 staging; 1 barrier per chunk; load
// latency for chunk c+1 hidden under chunk c's MFMA.

__global__ __launch_bounds__(256, 3) void fused34_k(const short* __restrict__ z3,
                                                    const short* __restrict__ W3c,  // [512][256] bf16
                                                    const float* __restrict__ b3,
                                                    const short* __restrict__ W4c,  // [64][512] bf16
                                                    const float* __restrict__ dis,
                                                    float* __restrict__ T4, int M) {
  __shared__ short Bs[2][32][264];  // W3 chunk ping-pong (2 x 16.9 KB)
  __shared__ short Ws4[2][64][40];  // W4 chunk ping-pong (2 x 5 KB)
  __shared__ short Hs[64][40];      // h3 chunk, A-layout (wave-private rows)
  const int tid = threadIdx.x;
  const int row0 = blockIdx.x * 64;
  const int w = tid >> 6, lane = tid & 63;
  const int lm = lane & 15, lk = (lane >> 4) * 8;
  const int rquad = (lane >> 4) * 4;
  const int w3row = tid >> 5, w3seg = (tid & 31) * 8;   // 32 rows x 256: 8 rows/wave? (256 thr -> 8/row)
  const int w4row = tid >> 2, w4seg = (tid & 3) * 8;

  // z3 A-fragments in registers (wave-private 16 rows, full K=256)
  bf16x8 afr[8];
  {
    int gr = row0 + w * 16 + lm;
    bool ok = gr < M;
    const short* zp = z3 + (size_t)gr * 256 + lk;
#pragma unroll
    for (int kc = 0; kc < 8; kc++) {
      bf16x8 v = {0, 0, 0, 0, 0, 0, 0, 0};
      if (ok) v = *(const bf16x8*)(zp + kc * 32);
      afr[kc] = v;
    }
  }

  f32x4 t4acc[4];
#pragma unroll
  for (int nt = 0; nt < 4; nt++)
#pragma unroll
    for (int r = 0; r < 4; r++) t4acc[nt][r] = 0.f;

  // prologue: load + store chunk 0
  bf16x8 pw3[4];
  bf16x8 pw4;
#pragma unroll
  for (int q = 0; q < 4; q++) {
    int flat = q * 2048 + tid * 8;
    pw3[q] = *(const bf16x8*)(W3c + flat);
  }
  pw4 = *(const bf16x8*)(W4c + (size_t)w4row * 512 + w4seg);
#pragma unroll
  for (int q = 0; q < 4; q++) {
    int flat = q * 2048 + tid * 8;
    *(bf16x8*)&Bs[0][flat >> 8][flat & 255] = pw3[q];
  }
  *(bf16x8*)&Ws4[0][w4row][w4seg] = pw4;
  __syncthreads();

  for (int c = 0; c < 16; c++) {
    int cur = c & 1, nxt = cur ^ 1;
    // issue next chunk's global loads (latency overlapped with MFMA below)
    if (c < 15) {
#pragma unroll
      for (int q = 0; q < 4; q++) {
        int flat = q * 2048 + tid * 8;
        pw3[q] = *(const bf16x8*)(W3c + (size_t)(c + 1) * 32 * 256 + flat);
      }
      pw4 = *(const bf16x8*)(W4c + (size_t)w4row * 512 + (c + 1) * 32 + w4seg);
    }

    // stage-1: h3 chunk (2 nt tiles), 16 MFMA
    f32x4 acc1[2];
#pragma unroll
    for (int nt = 0; nt < 2; nt++)
#pragma unroll
      for (int r = 0; r < 4; r++) acc1[nt][r] = 0.f;
#pragma unroll
    for (int k0 = 0; k0 < 8; k0++) {
      bf16x8 bb[2];
#pragma unroll
      for (int nt = 0; nt < 2; nt++) bb[nt] = *(const bf16x8*)&Bs[cur][nt * 16 + lm][k0 * 32 + lk];
#pragma unroll
      for (int nt = 0; nt < 2; nt++)
        acc1[nt] = __builtin_amdgcn_mfma_f32_16x16x32_bf16(afr[k0], bb[nt], acc1[nt], 0, 0, 0);
    }
    // bias + leaky -> bf16 -> Hs (C->A layout, wave-private rows)
#pragma unroll
    for (int nt = 0; nt < 2; nt++) {
      float bv = b3[c * 32 + nt * 16 + lm];
#pragma unroll
      for (int r = 0; r < 4; r++) {
        float v = acc1[nt][r] + bv;
        v = (v >= 0.f) ? v : 0.01f * v;
        Hs[w * 16 + rquad + r][nt * 16 + lm] = (short)f2bf(v);
      }
    }
    // stage-2: t4 += h3_chunk @ W4_chunk (k=32, 4 MFMA)
    {
      bf16x8 ah2 = *(const bf16x8*)&Hs[w * 16 + lm][lk];
      bf16x8 bb2[4];
#pragma unroll
      for (int nt = 0; nt < 4; nt++) bb2[nt] = *(const bf16x8*)&Ws4[cur][nt * 16 + lm][lk];
#pragma unroll
      for (int nt = 0; nt < 4; nt++)
        t4acc[nt] = __builtin_amdgcn_mfma_f32_16x16x32_bf16(ah2, bb2[nt], t4acc[nt], 0, 0, 0);
    }
    // store prefetched chunk into the other buffer (disjoint from cur)
    if (c < 15) {
#pragma unroll
      for (int q = 0; q < 4; q++) {
        int flat = q * 2048 + tid * 8;
        *(bf16x8*)&Bs[nxt][flat >> 8][flat & 255] = pw3[q];
      }
      *(bf16x8*)&Ws4[nxt][w4row][w4seg] = pw4;
    }
    __syncthreads();
  }
  // epilogue: t4 fp32, pre-scaled by dis[row]
#pragma unroll
  for (int r = 0; r < 4; r++) {
    int gr = row0 + w * 16 + rquad + r;
    float sc = (gr < M) ? dis[gr] : 0.f;
#pragma unroll
    for (int nt = 0; nt < 4; nt++) {
      int gc = nt * 16 + lm;
      if (gr < M) T4[(size_t)gr * 64 + gc] = t4acc[nt][r] * sc;
    }
  }
}

// ---------------- Aggregation (dis-free; rows pre-scaled by dis) ----------------

template<int BR, int OSCL>
__global__ __launch_bounds__(256) void aggb64_k(const short* __restrict__ T, const float* __restrict__ dis,
                                                const int* __restrict__ off, const int* __restrict__ csr,
                                                const float* __restrict__ bias, short* __restrict__ Out, int n) {
  int wid = (blockIdx.x * 256 + threadIdx.x) >> 6;
  int lane = threadIdx.x & 63;
  if (wid >= n) return;
  float di = dis[wid];
  int e0 = off[wid], e1 = off[wid + 1];
  float acc = bf2f((unsigned short)T[(size_t)wid * 64 + lane]);
  int e = e0;
  for (; e + 8 <= e1; e += 8) {
    int j0 = csr[e], j1 = csr[e + 1], j2 = csr[e + 2], j3 = csr[e + 3];
    int j4 = csr[e + 4], j5 = csr[e + 5], j6 = csr[e + 6], j7 = csr[e + 7];
    float v0 = bf2f((unsigned short)T[(size_t)j0 * 64 + lane]);
    float v1 = bf2f((unsigned short)T[(size_t)j1 * 64 + lane]);
    float v2 = bf2f((unsigned short)T[(size_t)j2 * 64 + lane]);
    float v3 = bf2f((unsigned short)T[(size_t)j3 * 64 + lane]);
    float v4 = bf2f((unsigned short)T[(size_t)j4 * 64 + lane]);
    float v5 = bf2f((unsigned short)T[(size_t)j5 * 64 + lane]);
    float v6 = bf2f((unsigned short)T[(size_t)j6 * 64 + lane]);
    float v7 = bf2f((unsigned short)T[(size_t)j7 * 64 + lane]);
    acc += ((v0 + v1) + (v2 + v3)) + ((v4 + v5) + (v6 + v7));
  }
  for (; e + 4 <= e1; e += 4) {
    int j0 = csr[e], j1 = csr[e + 1], j2 = csr[e + 2], j3 = csr[e + 3];
    float v0 = bf2f((unsigned short)T[(size_t)j0 * 64 + lane]);
    float v1 = bf2f((unsigned short)T[(size_t)j1 * 64 + lane]);
    float v2 = bf2f((unsigned short)T[(size_t)j2 * 64 + lane]);
    float v3 = bf2f((unsigned short)T[(size_t)j3 * 64 + lane]);
    acc += (v0 + v1) + (v2 + v3);
  }
  for (; e < e1; e++) acc += bf2f((unsigned short)T[(size_t)csr[e] * 64 + lane]);
  float v = di * acc;
  if (BR) {
    v += bias[lane];
    v = (v >= 0.f) ? v : 0.01f * v;
  }
  if (OSCL) v *= di;
  Out[(size_t)wid * 64 + lane] = (short)f2bf(v);
}

// layer-4 tail fused: hn = LN( leaky(di*sum(t4) + b4) + resid )
__global__ __launch_bounds__(256) void agg64_ln_k(const float* __restrict__ T, const float* __restrict__ dis,
                                                  const int* __restrict__ off, const int* __restrict__ csr,
                                                  const float* __restrict__ bias, const float* __restrict__ resid,
                                                  const float* __restrict__ g, const float* __restrict__ b,
                                                  float* __restrict__ outh, int n) {
  int wid = (blockIdx.x * 256 + threadIdx.x) >> 6;
  int lane = threadIdx.x & 63;
  if (wid >= n) return;
  float di = dis[wid];
  int e0 = off[wid], e1 = off[wid + 1];
  float acc = T[(size_t)wid * 64 + lane];
  int e = e0;
  for (; e + 8 <= e1; e += 8) {
    int j0 = csr[e], j1 = csr[e + 1], j2 = csr[e + 2], j3 = csr[e + 3];
    int j4 = csr[e + 4], j5 = csr[e + 5], j6 = csr[e + 6], j7 = csr[e + 7];
    float v0 = T[(size_t)j0 * 64 + lane];
    float v1 = T[(size_t)j1 * 64 + lane];
    float v2 = T[(size_t)j2 * 64 + lane];
    float v3 = T[(size_t)j3 * 64 + lane];
    float v4 = T[(size_t)j4 * 64 + lane];
    float v5 = T[(size_t)j5 * 64 + lane];
    float v6 = T[(size_t)j6 * 64 + lane];
    float v7 = T[(size_t)j7 * 64 + lane];
    acc += ((v0 + v1) + (v2 + v3)) + ((v4 + v5) + (v6 + v7));
  }
  for (; e + 4 <= e1; e += 4) {
    int j0 = csr[e], j1 = csr[e + 1], j2 = csr[e + 2], j3 = csr[e + 3];
    float v0 = T[(size_t)j0 * 64 + lane];
    float v1 = T[(size_t)j1 * 64 + lane];
    float v2 = T[(size_t)j2 * 64 + lane];
    float v3 = T[(size_t)j3 * 64 + lane];
    acc += (v0 + v1) + (v2 + v3);
  }
  for (; e < e1; e++) acc += T[(size_t)csr[e] * 64 + lane];
  float v = di * acc + bias[lane];
  v = (v >= 0.f) ? v : 0.01f * v;
  v += resid[(size_t)wid * 64 + lane];
  float s = v, ss = v * v;
#pragma unroll
  for (int o = 32; o > 0; o >>= 1) {
    s += __shfl_xor(s, o);
    ss += __shfl_xor(ss, o);
  }
  float m = s * (1.f / 64.f);
  float var = ss * (1.f / 64.f) - m * m;
  float y = (v - m) * rsqrtf(var + 1e-5f) * g[lane] + b[lane];
  outh[(size_t)wid * 64 + lane] = y;
}

// bf16 gather for the 256-dim layer: z3 = di*(sum + self)
__global__ __launch_bounds__(256) void agg256b_k(const short* __restrict__ T, const float* __restrict__ dis,
                                                 const int* __restrict__ off, const int* __restrict__ csr,
                                                 short* __restrict__ Out, int n) {
  int wid = (blockIdx.x * 256 + threadIdx.x) >> 6;
  int lane = threadIdx.x & 63;
  if (wid >= n) return;
  float di = dis[wid];
  int e0 = off[wid], e1 = off[wid + 1];
  bf16x4 sf = *(const bf16x4*)&T[(size_t)wid * 256 + lane * 4];
  float a0 = bf2f((unsigned short)sf[0]);
  float a1 = bf2f((unsigned short)sf[1]);
  float a2 = bf2f((unsigned short)sf[2]);
  float a3 = bf2f((unsigned short)sf[3]);
  int e = e0;
  for (; e + 8 <= e1; e += 8) {
    bf16x4 t[8];
#pragma unroll
    for (int q = 0; q < 8; q++) t[q] = *(const bf16x4*)&T[(size_t)csr[e + q] * 256 + lane * 4];
#pragma unroll
    for (int q = 0; q < 8; q++) {
      a0 += bf2f((unsigned short)t[q][0]);
      a1 += bf2f((unsigned short)t[q][1]);
      a2 += bf2f((unsigned short)t[q][2]);
      a3 += bf2f((unsigned short)t[q][3]);
    }
  }
  for (; e + 4 <= e1; e += 4) {
    bf16x4 t[4];
#pragma unroll
    for (int q = 0; q < 4; q++) t[q] = *(const bf16x4*)&T[(size_t)csr[e + q] * 256 + lane * 4];
#pragma unroll
    for (int q = 0; q < 4; q++) {
      a0 += bf2f((unsigned short)t[q][0]);
      a1 += bf2f((unsigned short)t[q][1]);
      a2 += bf2f((unsigned short)t[q][2]);
      a3 += bf2f((unsigned short)t[q][3]);
    }
  }
  for (; e < e1; e++) {
    bf16x4 t = *(const bf16x4*)&T[(size_t)csr[e] * 256 + lane * 4];
    a0 += bf2f((unsigned short)t[0]);
    a1 += bf2f((unsigned short)t[1]);
    a2 += bf2f((unsigned short)t[2]);
    a3 += bf2f((unsigned short)t[3]);
  }
  bf16x4 o;
  o[0] = (short)f2bf(di * a0);
  o[1] = (short)f2bf(di * a1);
  o[2] = (short)f2bf(di * a2);
  o[3] = (short)f2bf(di * a3);
  *(bf16x4*)&Out[(size_t)wid * 256 + lane * 4] = o;
}

// ---------------- per-graph max pool + final MLP (fused, one block per graph) ----------------

__global__ __launch_bounds__(256) void pool_mlp_k(const float* __restrict__ hn,
                                                  const float* __restrict__ fc1W, const float* __restrict__ fc1b,
                                                  const float* __restrict__ fng, const float* __restrict__ fnb,
                                                  const float* __restrict__ fc2W, const float* __restrict__ fc2b,
                                                  float* __restrict__ out, int n) {
  const int G = 64;
  int g = blockIdx.x;
  int f = threadIdx.x & 63, c = threadIdx.x >> 6;
  long long s0 = ((long long)g * n + G - 1) / G;
  long long e0 = ((long long)(g + 1) * n + G - 1) / G;
  float m = -INFINITY;
  for (long long i = s0 + c; i < e0; i += 4) m = fmaxf(m, hn[(size_t)i * 64 + f]);
  __shared__ float red[4][64];
  __shared__ float ps[64], qs[64];
  red[c][f] = m;
  __syncthreads();
  if (c == 0) ps[f] = fmaxf(fmaxf(red[0][f], red[1][f]), fmaxf(red[2][f], red[3][f]));
  __syncthreads();
  if (threadIdx.x < 64) {
    int lane = threadIdx.x;
    float q = fc1b[lane];
#pragma unroll 8
    for (int k = 0; k < 64; k++) q = fmaf(ps[k], fc1W[k * 64 + lane], q);
    float s = q, ss = q * q;
#pragma unroll
    for (int o = 32; o > 0; o >>= 1) {
      s += __shfl_xor(s, o);
      ss += __shfl_xor(ss, o);
    }
    float mm = s * (1.f / 64.f);
    float var = ss * (1.f / 64.f) - mm * mm;
    float y = (q - mm) * rsqrtf(var + 1e-5f) * fng[lane] + fnb[lane];
    y = (y >= 0.f) ? y : 0.01f * y;
    qs[lane] = y;
    __builtin_amdgcn_wave_barrier();
    if (lane < 16) {
      float o = fc2b[lane];
#pragma unroll 8
      for (int k = 0; k < 64; k++) o = fmaf(qs[k], fc2W[k * 16 + lane], o);
      out[g * 16 + lane] = o;
    }
  }
}

// ---------------- launch ----------------

extern "C" void kernel_launch(void* const* d_in, const int* in_sizes, int n_in,
                              void* d_out, int out_size, void* d_ws, size_t ws_size,
                              hipStream_t stream) {
  const float* x   = (const float*)d_in[0];
  const int*   ei  = (const int*)d_in[1];
  const float* W1  = (const float*)d_in[3];
  const float* b1  = (const float*)d_in[4];
  const float* W2  = (const float*)d_in[5];
  const float* b2  = (const float*)d_in[6];
  const float* W3  = (const float*)d_in[7];
  const float* b3  = (const float*)d_in[8];
  const float* W4  = (const float*)d_in[9];
  const float* b4  = (const float*)d_in[10];
  const float* Wr  = (const float*)d_in[11];
  const float* br  = (const float*)d_in[12];
  const float* lng = (const float*)d_in[13];
  const float* lnb = (const float*)d_in[14];
  const float* f1W = (const float*)d_in[15];
  const float* f1b = (const float*)d_in[16];
  const float* fng = (const float*)d_in[17];
  const float* fnb = (const float*)d_in[18];
  const float* f2W = (const float*)d_in[19];
  const float* f2b = (const float*)d_in[20];

  int n = in_sizes[0] / 128;   // 50000
  int e = in_sizes[1] / 2;     // 400000
  const int* src = ei;
  const int* dst = ei + e;

  float* arena = (float*)d_ws;
  float* resid = arena;
  short* h2b   = (short*)(arena + (size_t)64 * n);
  float* t4    = arena + (size_t)64 * n;
  short* z3b   = (short*)(arena + (size_t)192 * n);
  float* hn    = arena + (size_t)192 * n;
  short* t1b   = (short*)(arena + (size_t)320 * n);
  short* h1b   = (short*)(arena + (size_t)352 * n);
  short* z2b   = (short*)(arena + (size_t)384 * n);
  float* dis   = arena + (size_t)448 * n;  // n
  int* cnt    = (int*)(dis + n);           // n
  int* off    = cnt + n;                   // n+1
  int* cursor = off + n + 1;               // n
  int* csr    = cursor + n;                // e
  int* bsum   = csr + e;                   // 256
  int* bpre   = bsum + 256;                // 256
  float* pool = (float*)(bpre + 256);      // 64*64 (unused now, kept for layout)
  size_t wq = (((size_t)(pool + 4096)) + 15) & ~(size_t)15;
  short* wc1 = (short*)wq;                 // 64 x 128   (wc1||wcR = fused 128 x 128)
  short* wcR = wc1 + 8192;                 // 64 x 128
  short* wc2 = wcR + 8192;                 // 256 x 64
  short* wc3 = wc2 + 16384;                // 512 x 256
  short* wc4 = wc3 + 131072;               // 64 x 512
  size_t need = ((char*)(wc4 + 32768) - (char*)d_ws) + 64;
  if (ws_size < need) return;

  int nb_n = (n + 255) / 256;     // 196
  int nb_e = (e + 255) / 256;
  int nb_w = (n + 3) / 4;         // one wave per node
  int g_wide = (n + 63) / 64;     // 782
  int g_fused = (n + 127) / 128;  // 391

  // weights -> bf16 [N][K]
  wconv_k<<<960, 256, 0, stream>>>(W1, Wr, W2, W3, W4, wc1, wcR, wc2, wc3, wc4);

  // degree + CSR (hierarchical scan; dis fused into scan_c)
  zero_i32<<<nb_n, 256, 0, stream>>>(cnt, n);
  count_k<<<nb_e, 256, 0, stream>>>(dst, cnt, e);
  scan_a<<<nb_n, 256, 0, stream>>>(cnt, bsum, n);
  scan_b<<<1, 256, 0, stream>>>(bsum, bpre, off + n, nb_n);
  scan_c<<<nb_n, 256, 0, stream>>>(cnt, bpre, off, cursor, dis, n);
  scatter_k<<<nb_e, 256, 0, stream>>>(src, dst, cursor, csr, e);

  // fused L1 + residual: t1b = bf16(dis*(x@W1)); resid = x@Wr + br
  mgemm<128, 128, 2, 2, 1, 0, 0, 0, 1, 1, 4><<<dim3(g_fused, 1), 256, 0, stream>>>(x, wc1, br, t1b, resid, dis, n);
  // h1b = bf16( dis * leaky(di*sum(t1) + b1) )
  aggb64_k<1, 1><<<nb_w, 256, 0, stream>>>(t1b, dis, off, csr, b1, h1b, n);
  // z2b = bf16( di * sum(h1) )
  aggb64_k<0, 0><<<nb_w, 256, 0, stream>>>(h1b, dis, off, csr, nullptr, z2b, n);
  // h2b = bf16( dis * leaky(z2@W2 + b2) )
  mgemm<64, 256, 1, 4, 1, 1, 1, 1, 0, 1, 5><<<dim3(g_wide, 1), 256, 0, stream>>>(z2b, wc2, b2, h2b, nullptr, dis, n);
  // z3b = bf16( di * sum(h2b) )
  agg256b_k<<<nb_w, 256, 0, stream>>>(h2b, dis, off, csr, z3b, n);
  // t4 = dis * (leaky(z3@W3+b3) @ W4)   (h3 on-chip, ping-pong pipeline)
  fused34_k<<<g_wide, 256, 0, stream>>>(z3b, wc3, b3, wc4, dis, t4, n);
  // hn = LN( leaky(di*sum(t4) + b4) + resid )
  agg64_ln_k<<<nb_w, 256, 0, stream>>>(t4, dis, off, csr, b4, resid, lng, lnb, hn, n);
  // pool + MLP fused
  pool_mlp_k<<<64, 256, 0, stream>>>(hn, f1W, f1b, fng, fnb, f2W, f2b, (float*)d_out, n);
}